// Round 2
// baseline (19389.130 us; speedup 1.0000x reference)
//
#include <hip/hip_runtime.h>
#include <hip/hip_bf16.h>
#include <math.h>

#define V_N    100000
#define E_N    400000
#define NFEAT  74
#define NEFEAT 12
#define G_DIM  200
#define L_N    2
#define NG_N   4000

static inline int cdiv(int a, int b) { return (a + b - 1) / b; }

__device__ __forceinline__ float lrelu_f(float x) { return x > 0.f ? x : 0.01f * x; }
__device__ __forceinline__ float sigmoid_f(float x) { return 1.f / (1.f + expf(-x)); }
__device__ __forceinline__ float elu_f(float x) { return x > 0.f ? x : expm1f(x); }

__device__ __forceinline__ void atomicMaxFloat(float* addr, float value) {
    if (value >= 0.f)
        atomicMax((int*)addr, __float_as_int(value));
    else
        atomicMin((unsigned int*)addr, __float_as_uint(value));
}

__device__ __forceinline__ float ld_f(const float* p) { return *p; }
__device__ __forceinline__ float to_f(float x) { return x; }
__device__ __forceinline__ float to_f(__hip_bfloat16 x) { return __bfloat162float(x); }

// ---------------------------------------------------------------------------
// fill kernel (replaces hipMemsetAsync; graph-capture-safe by construction)
// ---------------------------------------------------------------------------
__global__ __launch_bounds__(256)
void fill_kernel(float* __restrict__ p, float v, int n)
{
    int i = blockIdx.x * blockDim.x + threadIdx.x;
    if (i < n) p[i] = v;
}

// ---------------------------------------------------------------------------
// Plain tiled GEMM, C(bf16) = act(A[M,K] @ B[K,N] + bias). A is f32 or bf16.
// 64x64 tile, 256 threads, 4x4 acc per thread.
// ---------------------------------------------------------------------------
template<typename AT, int ACT>
__global__ __launch_bounds__(256)
void gemm_bf16out_kernel(const AT* __restrict__ A, int lda,
                         const float* __restrict__ B, int ldb,
                         const float* __restrict__ bias,
                         __hip_bfloat16* __restrict__ C, int ldc,
                         int M, int N, int K)
{
    __shared__ float As[16][65];
    __shared__ float Bs[16][65];
    const int tid = threadIdx.x;
    const int rowBase = blockIdx.y * 64;
    const int colBase = blockIdx.x * 64;
    const int tx = tid & 15, ty = tid >> 4;
    float acc[4][4] = {};

    for (int k0 = 0; k0 < K; k0 += 16) {
        for (int t = tid; t < 1024; t += 256) {
            int m = t & 63, kk = t >> 6;
            int row = rowBase + m, kg = k0 + kk;
            As[kk][m] = (row < M && kg < K) ? to_f(A[(long)row * lda + kg]) : 0.f;
        }
        for (int t = tid; t < 1024; t += 256) {
            int n = t & 63, kk = t >> 6;
            int col = colBase + n, kg = k0 + kk;
            Bs[kk][n] = (col < N && kg < K) ? B[(long)kg * ldb + col] : 0.f;
        }
        __syncthreads();
        #pragma unroll
        for (int kk = 0; kk < 16; kk++) {
            float a[4], b[4];
            #pragma unroll
            for (int i = 0; i < 4; i++) a[i] = As[kk][ty * 4 + i];
            #pragma unroll
            for (int j = 0; j < 4; j++) b[j] = Bs[kk][tx * 4 + j];
            #pragma unroll
            for (int i = 0; i < 4; i++)
                #pragma unroll
                for (int j = 0; j < 4; j++)
                    acc[i][j] += a[i] * b[j];
        }
        __syncthreads();
    }
    #pragma unroll
    for (int i = 0; i < 4; i++) {
        int row = rowBase + ty * 4 + i;
        if (row >= M) continue;
        #pragma unroll
        for (int j = 0; j < 4; j++) {
            int col = colBase + tx * 4 + j;
            if (col >= N) continue;
            float v = acc[i][j] + (bias ? bias[col] : 0.f);
            if (ACT == 1) v = lrelu_f(v);
            C[(long)row * ldc + col] = __float2bfloat16(v);
        }
    }
}

// ---------------------------------------------------------------------------
// Shared phase-1: compute he1 tile (64 edges x 200) into LDS.
// he1[e] = lrelu(concat(node_feats[src[e]], edge_feats[e]) @ pe1_W + pe1_b)
// he1s is [64][209]; cols 200..208 zeroed (pad so K-loop reads past 200 are 0-safe).
// ---------------------------------------------------------------------------
__device__ __forceinline__ void compute_he1_tile(
    int eBase, int tid,
    const float* __restrict__ nfeat, const float* __restrict__ efeat,
    const int* __restrict__ src,
    const float* __restrict__ pe1W, const float* __restrict__ pe1b,
    float (*he1s)[209], float (*As)[65], float (*Bs)[65])
{
    const int tx = tid & 15, ty = tid >> 4;
    for (int cb = 0; cb < 200; cb += 64) {
        float acc[4][4] = {};
        for (int k0 = 0; k0 < 86; k0 += 16) {
            for (int t = tid; t < 1024; t += 256) {
                int m = t & 63, kk = t >> 6;
                int kg = k0 + kk, e = eBase + m;
                float v = 0.f;
                if (kg < NFEAT) v = nfeat[(long)src[e] * NFEAT + kg];
                else if (kg < NFEAT + NEFEAT) v = efeat[(long)e * NEFEAT + (kg - NFEAT)];
                As[kk][m] = v;
            }
            for (int t = tid; t < 1024; t += 256) {
                int n = t & 63, kk = t >> 6;
                int kg = k0 + kk, col = cb + n;
                Bs[kk][n] = (kg < NFEAT + NEFEAT && col < G_DIM)
                          ? pe1W[(long)kg * G_DIM + col] : 0.f;
            }
            __syncthreads();
            #pragma unroll
            for (int kk = 0; kk < 16; kk++) {
                float a[4], b[4];
                #pragma unroll
                for (int i = 0; i < 4; i++) a[i] = As[kk][ty * 4 + i];
                #pragma unroll
                for (int j = 0; j < 4; j++) b[j] = Bs[kk][tx * 4 + j];
                #pragma unroll
                for (int i = 0; i < 4; i++)
                    #pragma unroll
                    for (int j = 0; j < 4; j++)
                        acc[i][j] += a[i] * b[j];
            }
            __syncthreads();
        }
        #pragma unroll
        for (int i = 0; i < 4; i++) {
            #pragma unroll
            for (int j = 0; j < 4; j++) {
                int col = cb + tx * 4 + j;
                if (col < 209) {
                    float v = (col < G_DIM) ? lrelu_f(acc[i][j] + pe1b[col]) : 0.f;
                    he1s[ty * 4 + i][col] = v;
                }
            }
        }
    }
    __syncthreads();
}

// ---------------------------------------------------------------------------
// GetContext logits: logits[e] = lrelu(hv[dst[e]]·pe2W[0:200] + he1[e]·pe2W[200:400] + pe2b)
// ---------------------------------------------------------------------------
__global__ __launch_bounds__(256)
void ctx_logits_kernel(const float* __restrict__ nfeat, const float* __restrict__ efeat,
                       const int* __restrict__ src, const int* __restrict__ dst,
                       const float* __restrict__ pe1W, const float* __restrict__ pe1b,
                       const __hip_bfloat16* __restrict__ hv,
                       const float* __restrict__ pe2W, const float* __restrict__ pe2b,
                       float* __restrict__ logits)
{
    __shared__ float he1s[64][209];
    __shared__ float As[16][65];
    __shared__ float Bs[16][65];
    __shared__ float red[256];
    const int tid = threadIdx.x;
    const int eBase = blockIdx.x * 64;

    compute_he1_tile(eBase, tid, nfeat, efeat, src, pe1W, pe1b, he1s, As, Bs);

    const int r = tid & 63, part = tid >> 6;
    const int e = eBase + r;
    const int d = dst[e];
    float s = 0.f;
    const int c0 = part * 50;
    for (int c = c0; c < c0 + 50; c++) {
        s += __bfloat162float(hv[(long)d * G_DIM + c]) * pe2W[c];
        s += he1s[r][c] * pe2W[G_DIM + c];
    }
    red[tid] = s;
    __syncthreads();
    if (tid < 64) {
        float sum = red[tid] + red[tid + 64] + red[tid + 128] + red[tid + 192];
        logits[eBase + tid] = lrelu_f(sum + pe2b[0]);
    }
}

// ---------------------------------------------------------------------------
// GetContext et + scatter: c[dst[e]] += aw[e] * (he1[e] @ et_W + et_b)
// ---------------------------------------------------------------------------
__global__ __launch_bounds__(256)
void ctx_et_kernel(const float* __restrict__ nfeat, const float* __restrict__ efeat,
                   const int* __restrict__ src, const int* __restrict__ dst,
                   const float* __restrict__ pe1W, const float* __restrict__ pe1b,
                   const float* __restrict__ etW, const float* __restrict__ etb,
                   const float* __restrict__ aw, float* __restrict__ c)
{
    __shared__ float he1s[64][209];
    __shared__ float As[16][65];
    __shared__ float Bs[16][65];
    const int tid = threadIdx.x;
    const int tx = tid & 15, ty = tid >> 4;
    const int eBase = blockIdx.x * 64;

    compute_he1_tile(eBase, tid, nfeat, efeat, src, pe1W, pe1b, he1s, As, Bs);

    for (int cb = 0; cb < 200; cb += 64) {
        float acc[4][4] = {};
        for (int k0 = 0; k0 < 200; k0 += 16) {
            for (int t = tid; t < 1024; t += 256) {
                int n = t & 63, kk = t >> 6;
                int kg = k0 + kk, col = cb + n;
                Bs[kk][n] = (kg < G_DIM && col < G_DIM) ? etW[(long)kg * G_DIM + col] : 0.f;
            }
            __syncthreads();
            #pragma unroll
            for (int kk = 0; kk < 16; kk++) {
                float a[4], b[4];
                #pragma unroll
                for (int i = 0; i < 4; i++) a[i] = he1s[ty * 4 + i][k0 + kk];
                #pragma unroll
                for (int j = 0; j < 4; j++) b[j] = Bs[kk][tx * 4 + j];
                #pragma unroll
                for (int i = 0; i < 4; i++)
                    #pragma unroll
                    for (int j = 0; j < 4; j++)
                        acc[i][j] += a[i] * b[j];
            }
            __syncthreads();
        }
        #pragma unroll
        for (int i = 0; i < 4; i++) {
            int e = eBase + ty * 4 + i;
            int d = dst[e];
            float w = aw[e];
            #pragma unroll
            for (int j = 0; j < 4; j++) {
                int col = cb + tx * 4 + j;
                if (col < G_DIM) {
                    float v = acc[i][j] + etb[col];
                    atomicAdd(&c[(long)d * G_DIM + col], w * v);
                }
            }
        }
    }
}

// ---------------------------------------------------------------------------
// Fused GRU: out = relu(gru_cell(elu(xc), h)).  Computes all 6 gate sub-GEMMs
// (x@Wih_r/z/n, h@Whh_r/z/n) for a 64x64 (row x gate-col) tile; no gi/gh in HBM.
// ---------------------------------------------------------------------------
__global__ __launch_bounds__(256)
void gru_fused_kernel(const float* __restrict__ xc,
                      const __hip_bfloat16* __restrict__ h,
                      const float* __restrict__ Wih, const float* __restrict__ Whh,
                      const float* __restrict__ bih, const float* __restrict__ bhh,
                      __hip_bfloat16* __restrict__ out)
{
    __shared__ float Ax[16][65];
    __shared__ float Ah[16][65];
    __shared__ float Bsh[6][16][65];
    const int tid = threadIdx.x;
    const int tx = tid & 15, ty = tid >> 4;
    const int rowBase = blockIdx.y * 64;
    const int j0 = blockIdx.x * 64;
    float acc[6][4][4] = {};

    for (int k0 = 0; k0 < G_DIM; k0 += 16) {
        for (int t = tid; t < 2048; t += 256) {
            int sel = t >> 10, rem = t & 1023;
            int m = rem & 63, kk = rem >> 6;
            int row = rowBase + m, kg = k0 + kk;
            float v = 0.f;
            if (row < V_N && kg < G_DIM) {
                if (sel == 0) v = elu_f(xc[(long)row * G_DIM + kg]);
                else v = __bfloat162float(h[(long)row * G_DIM + kg]);
            }
            if (sel == 0) Ax[kk][m] = v; else Ah[kk][m] = v;
        }
        for (int t = tid; t < 6144; t += 256) {
            int mat = t >> 10, rem = t & 1023;
            int n = rem & 63, kk = rem >> 6;
            int kg = k0 + kk, jc = j0 + n;
            int gate = mat % 3;
            const float* W = (mat < 3) ? Wih : Whh;
            float v = (kg < G_DIM && jc < G_DIM)
                    ? W[(long)kg * (3 * G_DIM) + gate * G_DIM + jc] : 0.f;
            Bsh[mat][kk][n] = v;
        }
        __syncthreads();
        #pragma unroll
        for (int kk = 0; kk < 16; kk++) {
            float ax[4], ah[4], bb[4];
            #pragma unroll
            for (int i = 0; i < 4; i++) { ax[i] = Ax[kk][ty * 4 + i]; ah[i] = Ah[kk][ty * 4 + i]; }
            #pragma unroll
            for (int mat = 0; mat < 6; mat++) {
                #pragma unroll
                for (int j = 0; j < 4; j++) bb[j] = Bsh[mat][kk][tx * 4 + j];
                #pragma unroll
                for (int i = 0; i < 4; i++) {
                    float av = (mat < 3) ? ax[i] : ah[i];
                    #pragma unroll
                    for (int j = 0; j < 4; j++) acc[mat][i][j] += av * bb[j];
                }
            }
        }
        __syncthreads();
    }

    #pragma unroll
    for (int i = 0; i < 4; i++) {
        int row = rowBase + ty * 4 + i;
        if (row >= V_N) continue;
        #pragma unroll
        for (int j = 0; j < 4; j++) {
            int col = j0 + tx * 4 + j;
            if (col >= G_DIM) continue;
            float gir = acc[0][i][j] + bih[col];
            float giz = acc[1][i][j] + bih[G_DIM + col];
            float gin = acc[2][i][j] + bih[2 * G_DIM + col];
            float ghr = acc[3][i][j] + bhh[col];
            float ghz = acc[4][i][j] + bhh[G_DIM + col];
            float ghn = acc[5][i][j] + bhh[2 * G_DIM + col];
            float r = sigmoid_f(gir + ghr);
            float z = sigmoid_f(giz + ghz);
            float n = tanhf(gin + r * ghn);
            float hval = __bfloat162float(h[(long)row * G_DIM + col]);
            float o = (1.f - z) * n + z * hval;
            out[(long)row * G_DIM + col] = __float2bfloat16(o > 0.f ? o : 0.f);
        }
    }
}

// ---------------------------------------------------------------------------
// edge softmax pieces
// ---------------------------------------------------------------------------
__global__ __launch_bounds__(256)
void edge_max_kernel(const float* __restrict__ logits, const int* __restrict__ dst,
                     float* __restrict__ nmax)
{
    int e = blockIdx.x * blockDim.x + threadIdx.x;
    if (e >= E_N) return;
    atomicMaxFloat(&nmax[dst[e]], logits[e]);
}

__global__ __launch_bounds__(256)
void edge_expsum_kernel(const float* __restrict__ logits, const int* __restrict__ dst,
                        const float* __restrict__ nmax, float* __restrict__ aw,
                        float* __restrict__ nsum)
{
    int e = blockIdx.x * blockDim.x + threadIdx.x;
    if (e >= E_N) return;
    int d = dst[e];
    float ex = expf(logits[e] - nmax[d]);
    aw[e] = ex;
    atomicAdd(&nsum[d], ex);
}

__global__ __launch_bounds__(256)
void edge_norm_kernel(float* __restrict__ aw, const int* __restrict__ dst,
                      const float* __restrict__ nsum)
{
    int e = blockIdx.x * blockDim.x + threadIdx.x;
    if (e >= E_N) return;
    aw[e] = aw[e] / nsum[dst[e]];
}

// ---------------------------------------------------------------------------
// GNN edge logits: lrelu(nf[dst]·w[0:200] + nf[src]·w[200:400] + b), wave/edge
// ---------------------------------------------------------------------------
__global__ __launch_bounds__(256)
void gnn_edge_logits_kernel(const __hip_bfloat16* __restrict__ nf,
                            const int* __restrict__ src, const int* __restrict__ dst,
                            const float* __restrict__ w, const float* __restrict__ b,
                            float* __restrict__ out)
{
    int gtid = blockIdx.x * blockDim.x + threadIdx.x;
    int e = gtid >> 6, lane = gtid & 63;
    if (e >= E_N) return;
    int d = dst[e], s = src[e];
    float acc = 0.f;
    for (int k = lane; k < G_DIM; k += 64) {
        acc += __bfloat162float(nf[(long)d * G_DIM + k]) * w[k];
        acc += __bfloat162float(nf[(long)s * G_DIM + k]) * w[G_DIM + k];
    }
    for (int off = 32; off > 0; off >>= 1) acc += __shfl_down(acc, off, 64);
    if (lane == 0) out[e] = lrelu_f(acc + b[0]);
}

// c[dst[e]] += aw[e] * hvp[src[e]], wave per edge
__global__ __launch_bounds__(256)
void gnn_scatter_kernel(const __hip_bfloat16* __restrict__ hvp,
                        const int* __restrict__ src, const int* __restrict__ dst,
                        const float* __restrict__ aw, float* __restrict__ c)
{
    int gtid = blockIdx.x * blockDim.x + threadIdx.x;
    int e = gtid >> 6, lane = gtid & 63;
    if (e >= E_N) return;
    int s = src[e], d = dst[e];
    float w = aw[e];
    for (int k = lane; k < G_DIM; k += 64)
        atomicAdd(&c[(long)d * G_DIM + k], w * __bfloat162float(hvp[(long)s * G_DIM + k]));
}

// ---------------------------------------------------------------------------
// readout
// ---------------------------------------------------------------------------
__global__ __launch_bounds__(256)
void mask_kernel(const float* __restrict__ nfeat, float* __restrict__ mask)
{
    int v = blockIdx.x * blockDim.x + threadIdx.x;
    if (v >= V_N) return;
    const float* row = nfeat + (long)v * NFEAT;
    float s = row[NFEAT - 4] + row[NFEAT - 3] + row[NFEAT - 2] + row[NFEAT - 1];
    float m = s * (1.f - row[0]);
    mask[v] = 1.f / m - 1.f;
}

__global__ __launch_bounds__(256)
void readout_kernel(const __hip_bfloat16* __restrict__ nf, const float* __restrict__ predW,
                    const float* __restrict__ predb, const float* __restrict__ mask,
                    const int* __restrict__ gid, float* __restrict__ out_atom,
                    float* __restrict__ gsum)
{
    int gtid = blockIdx.x * blockDim.x + threadIdx.x;
    int v = gtid >> 6, lane = gtid & 63;
    if (v >= V_N) return;
    float acc = 0.f;
    for (int k = lane; k < G_DIM; k += 64)
        acc += __bfloat162float(nf[(long)v * G_DIM + k]) * predW[k];
    for (int off = 32; off > 0; off >>= 1) acc += __shfl_down(acc, off, 64);
    if (lane == 0) {
        float p = acc + predb[0] + mask[v];
        out_atom[v] = p;
        atomicAdd(&gsum[gid[v]], exp10f(-p));
    }
}

__global__ __launch_bounds__(256)
void graph_out_kernel(const float* __restrict__ gsum, float* __restrict__ out_g)
{
    int g = blockIdx.x * blockDim.x + threadIdx.x;
    if (g >= NG_N) return;
    out_g[g] = -log10f(gsum[g]);
}

// ---------------------------------------------------------------------------
extern "C" void kernel_launch(void* const* d_in, const int* in_sizes, int n_in,
                              void* d_out, int out_size, void* d_ws, size_t ws_size,
                              hipStream_t stream)
{
    const float* node_feats = (const float*)d_in[0];
    const float* edge_feats = (const float*)d_in[1];
    const float* pn_W  = (const float*)d_in[2];
    const float* pn_b  = (const float*)d_in[3];
    const float* pe1_W = (const float*)d_in[4];
    const float* pe1_b = (const float*)d_in[5];
    const float* pe2_W = (const float*)d_in[6];
    const float* pe2_b = (const float*)d_in[7];
    const float* et_W  = (const float*)d_in[8];
    const float* et_b  = (const float*)d_in[9];
    const float* gru0_Wih = (const float*)d_in[10];
    const float* gru0_Whh = (const float*)d_in[11];
    const float* gru0_bih = (const float*)d_in[12];
    const float* gru0_bhh = (const float*)d_in[13];
    const float* gnn_pe_W = (const float*)d_in[14];
    const float* gnn_pe_b = (const float*)d_in[15];
    const float* gnn_pn_W = (const float*)d_in[16];
    const float* gnn_pn_b = (const float*)d_in[17];
    const float* gnn_gru_Wih = (const float*)d_in[18];
    const float* gnn_gru_Whh = (const float*)d_in[19];
    const float* gnn_gru_bih = (const float*)d_in[20];
    const float* gnn_gru_bhh = (const float*)d_in[21];
    const float* pred_W = (const float*)d_in[22];
    const float* pred_b = (const float*)d_in[23];
    const int* src = (const int*)d_in[24];
    const int* dst = (const int*)d_in[25];
    const int* gid = (const int*)d_in[26];

    float* out_g = (float*)d_out;
    float* out_atom = out_g + NG_N;

    // ---- workspace layout (256B-aligned segments) ----
    char* base = (char*)d_ws;
    size_t off = 0;
    auto take = [&](size_t bytes) -> void* {
        void* p = base + off;
        off += (bytes + 255) & ~(size_t)255;
        return p;
    };
    const size_t VG = (size_t)V_N * G_DIM;
    float* mask   = (float*)take((size_t)V_N * 4);
    float* logits = (float*)take((size_t)E_N * 4);
    float* aw     = (float*)take((size_t)E_N * 4);
    float* nmax   = (float*)take((size_t)V_N * 4);
    float* nsum   = (float*)take((size_t)V_N * 4);
    float* gsum   = (float*)take((size_t)NG_N * 4);
    float* c      = (float*)take(VG * 4);
    __hip_bfloat16* hv   = (__hip_bfloat16*)take(VG * 2);  // later reused as hvp
    __hip_bfloat16* nf_a = (__hip_bfloat16*)take(VG * 2);
    __hip_bfloat16* nf_b = (__hip_bfloat16*)take(VG * 2);
    __hip_bfloat16* hvp  = hv;   // alias: hv dead after GRU0

    if (off > ws_size) {
        // workspace too small: emit sentinel so the failure mode is diagnosable
        fill_kernel<<<cdiv(out_size, 256), 256, 0, stream>>>((float*)d_out, -12345.f, out_size);
        return;
    }

    const int BLK = 256;
    const dim3 gNode(4, cdiv(V_N, 64));         // 64x64 tiles over (V,200)
    const int gEdgeTiles = E_N / 64;            // 6250, exact
    const dim3 gGru(4, cdiv(V_N, 64));

    mask_kernel<<<cdiv(V_N, BLK), BLK, 0, stream>>>(node_feats, mask);

    // ---- GetContext ----
    gemm_bf16out_kernel<float, 1><<<gNode, BLK, 0, stream>>>(
        node_feats, NFEAT, pn_W, G_DIM, pn_b, hv, G_DIM, V_N, G_DIM, NFEAT);

    ctx_logits_kernel<<<gEdgeTiles, BLK, 0, stream>>>(
        node_feats, edge_feats, src, dst, pe1_W, pe1_b, hv, pe2_W, pe2_b, logits);

    fill_kernel<<<cdiv(V_N, BLK), BLK, 0, stream>>>(nmax, -INFINITY, V_N);
    fill_kernel<<<cdiv(V_N, BLK), BLK, 0, stream>>>(nsum, 0.f, V_N);
    edge_max_kernel<<<cdiv(E_N, BLK), BLK, 0, stream>>>(logits, dst, nmax);
    edge_expsum_kernel<<<cdiv(E_N, BLK), BLK, 0, stream>>>(logits, dst, nmax, aw, nsum);
    edge_norm_kernel<<<cdiv(E_N, BLK), BLK, 0, stream>>>(aw, dst, nsum);

    fill_kernel<<<cdiv((int)VG, BLK), BLK, 0, stream>>>(c, 0.f, (int)VG);
    ctx_et_kernel<<<gEdgeTiles, BLK, 0, stream>>>(
        node_feats, edge_feats, src, dst, pe1_W, pe1_b, et_W, et_b, aw, c);

    gru_fused_kernel<<<gGru, BLK, 0, stream>>>(
        c, hv, gru0_Wih, gru0_Whh, gru0_bih, gru0_bhh, nf_a);

    // ---- GNN layers ----
    __hip_bfloat16* cur = nf_a;
    __hip_bfloat16* nxt = nf_b;
    for (int l = 0; l < L_N; l++) {
        const float* pe_W = gnn_pe_W + (size_t)l * 2 * G_DIM;
        const float* pe_b = gnn_pe_b + l;
        const float* pnW  = gnn_pn_W + (size_t)l * G_DIM * G_DIM;
        const float* pnB  = gnn_pn_b + (size_t)l * G_DIM;
        const float* Wih  = gnn_gru_Wih + (size_t)l * G_DIM * 3 * G_DIM;
        const float* Whh  = gnn_gru_Whh + (size_t)l * G_DIM * 3 * G_DIM;
        const float* bih  = gnn_gru_bih + (size_t)l * 3 * G_DIM;
        const float* bhh  = gnn_gru_bhh + (size_t)l * 3 * G_DIM;

        gnn_edge_logits_kernel<<<cdiv(E_N * 64, BLK), BLK, 0, stream>>>(
            cur, src, dst, pe_W, pe_b, logits);

        fill_kernel<<<cdiv(V_N, BLK), BLK, 0, stream>>>(nmax, -INFINITY, V_N);
        fill_kernel<<<cdiv(V_N, BLK), BLK, 0, stream>>>(nsum, 0.f, V_N);
        edge_max_kernel<<<cdiv(E_N, BLK), BLK, 0, stream>>>(logits, dst, nmax);
        edge_expsum_kernel<<<cdiv(E_N, BLK), BLK, 0, stream>>>(logits, dst, nmax, aw, nsum);
        edge_norm_kernel<<<cdiv(E_N, BLK), BLK, 0, stream>>>(aw, dst, nsum);

        gemm_bf16out_kernel<__hip_bfloat16, 0><<<gNode, BLK, 0, stream>>>(
            cur, G_DIM, pnW, G_DIM, pnB, hvp, G_DIM, V_N, G_DIM, G_DIM);

        fill_kernel<<<cdiv((int)VG, BLK), BLK, 0, stream>>>(c, 0.f, (int)VG);
        gnn_scatter_kernel<<<cdiv(E_N * 64, BLK), BLK, 0, stream>>>(hvp, src, dst, aw, c);

        gru_fused_kernel<<<gGru, BLK, 0, stream>>>(c, cur, Wih, Whh, bih, bhh, nxt);

        __hip_bfloat16* tmp = cur; cur = nxt; nxt = tmp;
    }

    // ---- readout ----
    fill_kernel<<<cdiv(NG_N, BLK), BLK, 0, stream>>>(gsum, 0.f, NG_N);
    readout_kernel<<<cdiv(V_N * 64, BLK), BLK, 0, stream>>>(
        cur, pred_W, pred_b, mask, gid, out_atom, gsum);
    graph_out_kernel<<<cdiv(NG_N, BLK), BLK, 0, stream>>>(gsum, out_g);
}

// Round 3
// 7498.579 us; speedup vs baseline: 2.5857x; 2.5857x over previous
//
#include <hip/hip_runtime.h>
#include <hip/hip_bf16.h>
#include <math.h>

#define V_N    100000
#define E_N    400000
#define NFEAT  74
#define NEFEAT 12
#define G_DIM  200
#define L_N    2
#define NG_N   4000

static inline int cdiv(int a, int b) { return (a + b - 1) / b; }

__device__ __forceinline__ float lrelu_f(float x) { return x > 0.f ? x : 0.01f * x; }
__device__ __forceinline__ float sigmoid_f(float x) { return 1.f / (1.f + expf(-x)); }
__device__ __forceinline__ float elu_f(float x) { return x > 0.f ? x : expm1f(x); }

__device__ __forceinline__ void atomicMaxFloat(float* addr, float value) {
    if (value >= 0.f)
        atomicMax((int*)addr, __float_as_int(value));
    else
        atomicMin((unsigned int*)addr, __float_as_uint(value));
}

__device__ __forceinline__ float to_f(float x) { return x; }
__device__ __forceinline__ float to_f(__hip_bfloat16 x) { return __bfloat162float(x); }

__device__ __forceinline__ short f2bf(float f) {
    __hip_bfloat16 b = __float2bfloat16(f);
    short s;
    __builtin_memcpy(&s, &b, 2);
    return s;
}

typedef short short8 __attribute__((ext_vector_type(8)));
typedef float f32x4 __attribute__((ext_vector_type(4)));

// ---------------------------------------------------------------------------
__global__ __launch_bounds__(256)
void fill_kernel(float* __restrict__ p, float v, int n)
{
    int i = blockIdx.x * blockDim.x + threadIdx.x;
    if (i < n) p[i] = v;
}

// ---------------------------------------------------------------------------
// GRU weight prep: Wp[g][j][k] (bf16 bits), g<3, j<256, k<448.
//   k<200        -> Wih[k][g*200+j]
//   224<=k<424   -> Whh[k-224][g*200+j]
//   else / j>=200 -> 0
// ---------------------------------------------------------------------------
__global__ __launch_bounds__(256)
void gru_wprep_kernel(const float* __restrict__ Wih, const float* __restrict__ Whh,
                      short* __restrict__ Wp)
{
    int idx = blockIdx.x * 256 + threadIdx.x;
    if (idx >= 3 * 256 * 448) return;
    int g = idx / (256 * 448);
    int rem = idx % (256 * 448);
    int j = rem / 448, k = rem % 448;
    float v = 0.f;
    if (j < G_DIM) {
        if (k < G_DIM) v = Wih[(long)k * (3 * G_DIM) + g * G_DIM + j];
        else if (k >= 224 && k < 224 + G_DIM) v = Whh[(long)(k - 224) * (3 * G_DIM) + g * G_DIM + j];
    }
    Wp[idx] = f2bf(v);
}

// ---------------------------------------------------------------------------
// Fused MFMA GRU: out = relu(gru_cell(elu(xc), h))
// A = [elu(xc) pad224 | h pad224]  (K=448), B = Wp (3 gates, K-minor bf16)
// accums: r, z, n_lo (x phase), n_hi (h phase)
// block: 256 thr = 4 waves; tile 64 rows x 64 cols; grid (4, cdiv(V,64))
// ---------------------------------------------------------------------------
__global__ __launch_bounds__(256)
void gru_mfma_kernel(const float* __restrict__ xc,
                     const __hip_bfloat16* __restrict__ h,
                     const short* __restrict__ Wp,
                     const float* __restrict__ bih, const float* __restrict__ bhh,
                     __hip_bfloat16* __restrict__ out)
{
    __shared__ short As[64 * 40];      // row stride 40 (bank rotation)
    __shared__ short Bs[3 * 64 * 40];  // [gate][col][k], stride 40
    const int tid = threadIdx.x;
    const int lane = tid & 63;
    const int w = tid >> 6;
    const int quad = lane >> 4;
    const int lm = lane & 15;
    const int rowBase = blockIdx.y * 64;
    const int j0 = blockIdx.x * 64;

    const int arow = tid >> 2;            // A staging: row 0..63
    const int akc = (tid & 3) * 8;        // k chunk 0/8/16/24
    const int agrow = rowBase + arow;

    f32x4 accR = {}, accZ = {};
    f32x4 accNlo[4] = {}, accNhi[4] = {};
    f32x4 accRt[4] = {}, accZt[4] = {};

    // ---- phase 0: k0 = 0..224 (x = elu(c)), phase 1: k0 = 224..448 (h) ----
    #pragma unroll 1
    for (int phase = 0; phase < 2; phase++) {
        for (int k0 = phase * 224; k0 < (phase + 1) * 224; k0 += 32) {
            // stage A (64x32 bf16)
            {
                short8 v = {};
                if (phase == 0) {
                    int gk = k0 + akc;
                    if (agrow < V_N && gk < G_DIM) {
                        const float* p = xc + (long)agrow * G_DIM + gk;
                        #pragma unroll
                        for (int i = 0; i < 8; i++) v[i] = f2bf(elu_f(p[i]));
                    }
                } else {
                    int hk = k0 - 224 + akc;
                    if (agrow < V_N && hk < G_DIM)
                        v = *(const short8*)((const short*)h + (long)agrow * G_DIM + hk);
                }
                *(short8*)&As[arow * 40 + akc] = v;
            }
            // stage B (3 x 64 x 32 bf16) : 768 short8, 3 per thread
            {
                #pragma unroll
                for (int i = 0; i < 3; i++) {
                    int idx8 = tid + i * 256;
                    int base = idx8 * 8;
                    int g = base >> 11;
                    int rem = base & 2047;
                    int jrow = rem >> 5, kc = rem & 31;
                    long goff = ((long)g * 256 + (j0 + jrow)) * 448 + (k0 + kc);
                    *(short8*)&Bs[(g * 64 + jrow) * 40 + kc] = *(const short8*)(Wp + goff);
                }
            }
            __syncthreads();
            short8 a = *(short8*)&As[(w * 16 + lm) * 40 + quad * 8];
            #pragma unroll
            for (int nt = 0; nt < 4; nt++) {
                int coll = nt * 16 + lm;
                short8 br = *(short8*)&Bs[(0 * 64 + coll) * 40 + quad * 8];
                short8 bz = *(short8*)&Bs[(1 * 64 + coll) * 40 + quad * 8];
                short8 bn = *(short8*)&Bs[(2 * 64 + coll) * 40 + quad * 8];
                accRt[nt] = __builtin_amdgcn_mfma_f32_16x16x32_bf16(a, br, accRt[nt], 0, 0, 0);
                accZt[nt] = __builtin_amdgcn_mfma_f32_16x16x32_bf16(a, bz, accZt[nt], 0, 0, 0);
                if (phase == 0)
                    accNlo[nt] = __builtin_amdgcn_mfma_f32_16x16x32_bf16(a, bn, accNlo[nt], 0, 0, 0);
                else
                    accNhi[nt] = __builtin_amdgcn_mfma_f32_16x16x32_bf16(a, bn, accNhi[nt], 0, 0, 0);
            }
            __syncthreads();
        }
    }
    (void)accR; (void)accZ;

    // ---- epilogue: GRU gate math ----
    #pragma unroll
    for (int nt = 0; nt < 4; nt++) {
        int col = j0 + nt * 16 + lm;
        if (col >= G_DIM) continue;
        float b_ir = bih[col], b_iz = bih[G_DIM + col], b_in = bih[2 * G_DIM + col];
        float b_hr = bhh[col], b_hz = bhh[G_DIM + col], b_hn = bhh[2 * G_DIM + col];
        #pragma unroll
        for (int r = 0; r < 4; r++) {
            int grow = rowBase + w * 16 + quad * 4 + r;
            if (grow >= V_N) continue;
            float sr = accRt[nt][r] + b_ir + b_hr;
            float sz = accZt[nt][r] + b_iz + b_hz;
            float gin = accNlo[nt][r] + b_in;
            float ghn = accNhi[nt][r] + b_hn;
            float rr = sigmoid_f(sr);
            float zz = sigmoid_f(sz);
            float nn = tanhf(gin + rr * ghn);
            float hval = __bfloat162float(h[(long)grow * G_DIM + col]);
            float o = (1.f - zz) * nn + zz * hval;
            out[(long)grow * G_DIM + col] = __float2bfloat16(o > 0.f ? o : 0.f);
        }
    }
}

// ---------------------------------------------------------------------------
// Plain tiled GEMM, C(bf16) = act(A[M,K] @ B[K,N] + bias). A is f32 or bf16.
// ---------------------------------------------------------------------------
template<typename AT, int ACT>
__global__ __launch_bounds__(256)
void gemm_bf16out_kernel(const AT* __restrict__ A, int lda,
                         const float* __restrict__ B, int ldb,
                         const float* __restrict__ bias,
                         __hip_bfloat16* __restrict__ C, int ldc,
                         int M, int N, int K)
{
    __shared__ float As[16][65];
    __shared__ float Bs[16][65];
    const int tid = threadIdx.x;
    const int rowBase = blockIdx.y * 64;
    const int colBase = blockIdx.x * 64;
    const int tx = tid & 15, ty = tid >> 4;
    float acc[4][4] = {};

    for (int k0 = 0; k0 < K; k0 += 16) {
        for (int t = tid; t < 1024; t += 256) {
            int m = t & 63, kk = t >> 6;
            int row = rowBase + m, kg = k0 + kk;
            As[kk][m] = (row < M && kg < K) ? to_f(A[(long)row * lda + kg]) : 0.f;
        }
        for (int t = tid; t < 1024; t += 256) {
            int n = t & 63, kk = t >> 6;
            int col = colBase + n, kg = k0 + kk;
            Bs[kk][n] = (col < N && kg < K) ? B[(long)kg * ldb + col] : 0.f;
        }
        __syncthreads();
        #pragma unroll
        for (int kk = 0; kk < 16; kk++) {
            float a[4], b[4];
            #pragma unroll
            for (int i = 0; i < 4; i++) a[i] = As[kk][ty * 4 + i];
            #pragma unroll
            for (int j = 0; j < 4; j++) b[j] = Bs[kk][tx * 4 + j];
            #pragma unroll
            for (int i = 0; i < 4; i++)
                #pragma unroll
                for (int j = 0; j < 4; j++)
                    acc[i][j] += a[i] * b[j];
        }
        __syncthreads();
    }
    #pragma unroll
    for (int i = 0; i < 4; i++) {
        int row = rowBase + ty * 4 + i;
        if (row >= M) continue;
        #pragma unroll
        for (int j = 0; j < 4; j++) {
            int col = colBase + tx * 4 + j;
            if (col >= N) continue;
            float v = acc[i][j] + (bias ? bias[col] : 0.f);
            if (ACT == 1) v = lrelu_f(v);
            C[(long)row * ldc + col] = __float2bfloat16(v);
        }
    }
}

// ---------------------------------------------------------------------------
// he1 tile (64 edges x 200) into LDS (fp32 VALU GEMM, K=86)
// ---------------------------------------------------------------------------
__device__ __forceinline__ void compute_he1_tile(
    int eBase, int tid,
    const float* __restrict__ nfeat, const float* __restrict__ efeat,
    const int* __restrict__ src,
    const float* __restrict__ pe1W, const float* __restrict__ pe1b,
    float (*he1s)[209], float (*As)[65], float (*Bs)[65])
{
    const int tx = tid & 15, ty = tid >> 4;
    for (int cb = 0; cb < 200; cb += 64) {
        float acc[4][4] = {};
        for (int k0 = 0; k0 < 86; k0 += 16) {
            for (int t = tid; t < 1024; t += 256) {
                int m = t & 63, kk = t >> 6;
                int kg = k0 + kk, e = eBase + m;
                float v = 0.f;
                if (kg < NFEAT) v = nfeat[(long)src[e] * NFEAT + kg];
                else if (kg < NFEAT + NEFEAT) v = efeat[(long)e * NEFEAT + (kg - NFEAT)];
                As[kk][m] = v;
            }
            for (int t = tid; t < 1024; t += 256) {
                int n = t & 63, kk = t >> 6;
                int kg = k0 + kk, col = cb + n;
                Bs[kk][n] = (kg < NFEAT + NEFEAT && col < G_DIM)
                          ? pe1W[(long)kg * G_DIM + col] : 0.f;
            }
            __syncthreads();
            #pragma unroll
            for (int kk = 0; kk < 16; kk++) {
                float a[4], b[4];
                #pragma unroll
                for (int i = 0; i < 4; i++) a[i] = As[kk][ty * 4 + i];
                #pragma unroll
                for (int j = 0; j < 4; j++) b[j] = Bs[kk][tx * 4 + j];
                #pragma unroll
                for (int i = 0; i < 4; i++)
                    #pragma unroll
                    for (int j = 0; j < 4; j++)
                        acc[i][j] += a[i] * b[j];
            }
            __syncthreads();
        }
        #pragma unroll
        for (int i = 0; i < 4; i++) {
            #pragma unroll
            for (int j = 0; j < 4; j++) {
                int col = cb + tx * 4 + j;
                if (col < 209) {
                    float v = (col < G_DIM) ? lrelu_f(acc[i][j] + pe1b[col]) : 0.f;
                    he1s[ty * 4 + i][col] = v;
                }
            }
        }
    }
    __syncthreads();
}

__global__ __launch_bounds__(256)
void ctx_logits_kernel(const float* __restrict__ nfeat, const float* __restrict__ efeat,
                       const int* __restrict__ src, const int* __restrict__ dst,
                       const float* __restrict__ pe1W, const float* __restrict__ pe1b,
                       const __hip_bfloat16* __restrict__ hv,
                       const float* __restrict__ pe2W, const float* __restrict__ pe2b,
                       float* __restrict__ logits)
{
    __shared__ float he1s[64][209];
    __shared__ float As[16][65];
    __shared__ float Bs[16][65];
    __shared__ float red[256];
    const int tid = threadIdx.x;
    const int eBase = blockIdx.x * 64;

    compute_he1_tile(eBase, tid, nfeat, efeat, src, pe1W, pe1b, he1s, As, Bs);

    const int r = tid & 63, part = tid >> 6;
    const int e = eBase + r;
    const int d = dst[e];
    float s = 0.f;
    const int c0 = part * 50;
    for (int c = c0; c < c0 + 50; c++) {
        s += __bfloat162float(hv[(long)d * G_DIM + c]) * pe2W[c];
        s += he1s[r][c] * pe2W[G_DIM + c];
    }
    red[tid] = s;
    __syncthreads();
    if (tid < 64) {
        float sum = red[tid] + red[tid + 64] + red[tid + 128] + red[tid + 192];
        logits[eBase + tid] = lrelu_f(sum + pe2b[0]);
    }
}

__global__ __launch_bounds__(256)
void ctx_et_kernel(const float* __restrict__ nfeat, const float* __restrict__ efeat,
                   const int* __restrict__ src, const int* __restrict__ dst,
                   const float* __restrict__ pe1W, const float* __restrict__ pe1b,
                   const float* __restrict__ etW, const float* __restrict__ etb,
                   const float* __restrict__ aw, float* __restrict__ c)
{
    __shared__ float he1s[64][209];
    __shared__ float As[16][65];
    __shared__ float Bs[16][65];
    const int tid = threadIdx.x;
    const int tx = tid & 15, ty = tid >> 4;
    const int eBase = blockIdx.x * 64;

    compute_he1_tile(eBase, tid, nfeat, efeat, src, pe1W, pe1b, he1s, As, Bs);

    for (int cb = 0; cb < 200; cb += 64) {
        float acc[4][4] = {};
        for (int k0 = 0; k0 < 200; k0 += 16) {
            for (int t = tid; t < 1024; t += 256) {
                int n = t & 63, kk = t >> 6;
                int kg = k0 + kk, col = cb + n;
                Bs[kk][n] = (kg < G_DIM && col < G_DIM) ? etW[(long)kg * G_DIM + col] : 0.f;
            }
            __syncthreads();
            #pragma unroll
            for (int kk = 0; kk < 16; kk++) {
                float a[4], b[4];
                #pragma unroll
                for (int i = 0; i < 4; i++) a[i] = he1s[ty * 4 + i][k0 + kk];
                #pragma unroll
                for (int j = 0; j < 4; j++) b[j] = Bs[kk][tx * 4 + j];
                #pragma unroll
                for (int i = 0; i < 4; i++)
                    #pragma unroll
                    for (int j = 0; j < 4; j++)
                        acc[i][j] += a[i] * b[j];
            }
            __syncthreads();
        }
        #pragma unroll
        for (int i = 0; i < 4; i++) {
            int e = eBase + ty * 4 + i;
            int d = dst[e];
            float w = aw[e];
            #pragma unroll
            for (int j = 0; j < 4; j++) {
                int col = cb + tx * 4 + j;
                if (col < G_DIM) {
                    float v = acc[i][j] + etb[col];
                    atomicAdd(&c[(long)d * G_DIM + col], w * v);
                }
            }
        }
    }
}

// ---------------------------------------------------------------------------
// edge softmax pieces
// ---------------------------------------------------------------------------
__global__ __launch_bounds__(256)
void edge_max_kernel(const float* __restrict__ logits, const int* __restrict__ dst,
                     float* __restrict__ nmax)
{
    int e = blockIdx.x * blockDim.x + threadIdx.x;
    if (e >= E_N) return;
    atomicMaxFloat(&nmax[dst[e]], logits[e]);
}

__global__ __launch_bounds__(256)
void edge_expsum_kernel(const float* __restrict__ logits, const int* __restrict__ dst,
                        const float* __restrict__ nmax, float* __restrict__ aw,
                        float* __restrict__ nsum)
{
    int e = blockIdx.x * blockDim.x + threadIdx.x;
    if (e >= E_N) return;
    int d = dst[e];
    float ex = expf(logits[e] - nmax[d]);
    aw[e] = ex;
    atomicAdd(&nsum[d], ex);
}

__global__ __launch_bounds__(256)
void edge_norm_kernel(float* __restrict__ aw, const int* __restrict__ dst,
                      const float* __restrict__ nsum)
{
    int e = blockIdx.x * blockDim.x + threadIdx.x;
    if (e >= E_N) return;
    aw[e] = aw[e] / nsum[dst[e]];
}

__global__ __launch_bounds__(256)
void gnn_edge_logits_kernel(const __hip_bfloat16* __restrict__ nf,
                            const int* __restrict__ src, const int* __restrict__ dst,
                            const float* __restrict__ w, const float* __restrict__ b,
                            float* __restrict__ out)
{
    int gtid = blockIdx.x * blockDim.x + threadIdx.x;
    int e = gtid >> 6, lane = gtid & 63;
    if (e >= E_N) return;
    int d = dst[e], s = src[e];
    float acc = 0.f;
    for (int k = lane; k < G_DIM; k += 64) {
        acc += __bfloat162float(nf[(long)d * G_DIM + k]) * w[k];
        acc += __bfloat162float(nf[(long)s * G_DIM + k]) * w[G_DIM + k];
    }
    for (int off = 32; off > 0; off >>= 1) acc += __shfl_down(acc, off, 64);
    if (lane == 0) out[e] = lrelu_f(acc + b[0]);
}

__global__ __launch_bounds__(256)
void gnn_scatter_kernel(const __hip_bfloat16* __restrict__ hvp,
                        const int* __restrict__ src, const int* __restrict__ dst,
                        const float* __restrict__ aw, float* __restrict__ c)
{
    int gtid = blockIdx.x * blockDim.x + threadIdx.x;
    int e = gtid >> 6, lane = gtid & 63;
    if (e >= E_N) return;
    int s = src[e], d = dst[e];
    float w = aw[e];
    for (int k = lane; k < G_DIM; k += 64)
        atomicAdd(&c[(long)d * G_DIM + k], w * __bfloat162float(hvp[(long)s * G_DIM + k]));
}

// ---------------------------------------------------------------------------
// readout
// ---------------------------------------------------------------------------
__global__ __launch_bounds__(256)
void mask_kernel(const float* __restrict__ nfeat, float* __restrict__ mask)
{
    int v = blockIdx.x * blockDim.x + threadIdx.x;
    if (v >= V_N) return;
    const float* row = nfeat + (long)v * NFEAT;
    float s = row[NFEAT - 4] + row[NFEAT - 3] + row[NFEAT - 2] + row[NFEAT - 1];
    float m = s * (1.f - row[0]);
    mask[v] = 1.f / m - 1.f;
}

__global__ __launch_bounds__(256)
void readout_kernel(const __hip_bfloat16* __restrict__ nf, const float* __restrict__ predW,
                    const float* __restrict__ predb, const float* __restrict__ mask,
                    const int* __restrict__ gid, float* __restrict__ out_atom,
                    float* __restrict__ gsum)
{
    int gtid = blockIdx.x * blockDim.x + threadIdx.x;
    int v = gtid >> 6, lane = gtid & 63;
    if (v >= V_N) return;
    float acc = 0.f;
    for (int k = lane; k < G_DIM; k += 64)
        acc += __bfloat162float(nf[(long)v * G_DIM + k]) * predW[k];
    for (int off = 32; off > 0; off >>= 1) acc += __shfl_down(acc, off, 64);
    if (lane == 0) {
        float p = acc + predb[0] + mask[v];
        out_atom[v] = p;
        atomicAdd(&gsum[gid[v]], exp10f(-p));
    }
}

__global__ __launch_bounds__(256)
void graph_out_kernel(const float* __restrict__ gsum, float* __restrict__ out_g)
{
    int g = blockIdx.x * blockDim.x + threadIdx.x;
    if (g >= NG_N) return;
    out_g[g] = -log10f(gsum[g]);
}

// ---------------------------------------------------------------------------
extern "C" void kernel_launch(void* const* d_in, const int* in_sizes, int n_in,
                              void* d_out, int out_size, void* d_ws, size_t ws_size,
                              hipStream_t stream)
{
    const float* node_feats = (const float*)d_in[0];
    const float* edge_feats = (const float*)d_in[1];
    const float* pn_W  = (const float*)d_in[2];
    const float* pn_b  = (const float*)d_in[3];
    const float* pe1_W = (const float*)d_in[4];
    const float* pe1_b = (const float*)d_in[5];
    const float* pe2_W = (const float*)d_in[6];
    const float* pe2_b = (const float*)d_in[7];
    const float* et_W  = (const float*)d_in[8];
    const float* et_b  = (const float*)d_in[9];
    const float* gru0_Wih = (const float*)d_in[10];
    const float* gru0_Whh = (const float*)d_in[11];
    const float* gru0_bih = (const float*)d_in[12];
    const float* gru0_bhh = (const float*)d_in[13];
    const float* gnn_pe_W = (const float*)d_in[14];
    const float* gnn_pe_b = (const float*)d_in[15];
    const float* gnn_pn_W = (const float*)d_in[16];
    const float* gnn_pn_b = (const float*)d_in[17];
    const float* gnn_gru_Wih = (const float*)d_in[18];
    const float* gnn_gru_Whh = (const float*)d_in[19];
    const float* gnn_gru_bih = (const float*)d_in[20];
    const float* gnn_gru_bhh = (const float*)d_in[21];
    const float* pred_W = (const float*)d_in[22];
    const float* pred_b = (const float*)d_in[23];
    const int* src = (const int*)d_in[24];
    const int* dst = (const int*)d_in[25];
    const int* gid = (const int*)d_in[26];

    float* out_g = (float*)d_out;
    float* out_atom = out_g + NG_N;

    char* base = (char*)d_ws;
    size_t off = 0;
    auto take = [&](size_t bytes) -> void* {
        void* p = base + off;
        off += (bytes + 255) & ~(size_t)255;
        return p;
    };
    const size_t VG = (size_t)V_N * G_DIM;
    const size_t WPL = 3 * 256 * 448;   // per-layer prepped GRU weight elems
    float* mask   = (float*)take((size_t)V_N * 4);
    float* logits = (float*)take((size_t)E_N * 4);
    float* aw     = (float*)take((size_t)E_N * 4);
    float* nmax   = (float*)take((size_t)V_N * 4);
    float* nsum   = (float*)take((size_t)V_N * 4);
    float* gsum   = (float*)take((size_t)NG_N * 4);
    float* c      = (float*)take(VG * 4);
    __hip_bfloat16* hv   = (__hip_bfloat16*)take(VG * 2);
    __hip_bfloat16* nf_a = (__hip_bfloat16*)take(VG * 2);
    __hip_bfloat16* nf_b = (__hip_bfloat16*)take(VG * 2);
    short* Wp = (short*)take(3 * WPL * 2);
    __hip_bfloat16* hvp  = hv;   // alias: hv dead after GRU0

    if (off > ws_size) {
        fill_kernel<<<cdiv(out_size, 256), 256, 0, stream>>>((float*)d_out, -12345.f, out_size);
        return;
    }

    const int BLK = 256;
    const dim3 gNode(4, cdiv(V_N, 64));
    const int gEdgeTiles = E_N / 64;
    const dim3 gGru(4, cdiv(V_N, 64));
    const int wprepBlocks = cdiv(3 * 256 * 448, 256);

    // GRU weight prep (GetContext + 2 GNN layers)
    gru_wprep_kernel<<<wprepBlocks, BLK, 0, stream>>>(gru0_Wih, gru0_Whh, Wp);
    for (int l = 0; l < L_N; l++) {
        gru_wprep_kernel<<<wprepBlocks, BLK, 0, stream>>>(
            gnn_gru_Wih + (size_t)l * G_DIM * 3 * G_DIM,
            gnn_gru_Whh + (size_t)l * G_DIM * 3 * G_DIM,
            Wp + (size_t)(l + 1) * WPL);
    }

    mask_kernel<<<cdiv(V_N, BLK), BLK, 0, stream>>>(node_feats, mask);

    // ---- GetContext ----
    gemm_bf16out_kernel<float, 1><<<gNode, BLK, 0, stream>>>(
        node_feats, NFEAT, pn_W, G_DIM, pn_b, hv, G_DIM, V_N, G_DIM, NFEAT);

    ctx_logits_kernel<<<gEdgeTiles, BLK, 0, stream>>>(
        node_feats, edge_feats, src, dst, pe1_W, pe1_b, hv, pe2_W, pe2_b, logits);

    fill_kernel<<<cdiv(V_N, BLK), BLK, 0, stream>>>(nmax, -INFINITY, V_N);
    fill_kernel<<<cdiv(V_N, BLK), BLK, 0, stream>>>(nsum, 0.f, V_N);
    edge_max_kernel<<<cdiv(E_N, BLK), BLK, 0, stream>>>(logits, dst, nmax);
    edge_expsum_kernel<<<cdiv(E_N, BLK), BLK, 0, stream>>>(logits, dst, nmax, aw, nsum);
    edge_norm_kernel<<<cdiv(E_N, BLK), BLK, 0, stream>>>(aw, dst, nsum);

    fill_kernel<<<cdiv((int)VG, BLK), BLK, 0, stream>>>(c, 0.f, (int)VG);
    ctx_et_kernel<<<gEdgeTiles, BLK, 0, stream>>>(
        node_feats, edge_feats, src, dst, pe1_W, pe1_b, et_W, et_b, aw, c);

    gru_mfma_kernel<<<gGru, BLK, 0, stream>>>(
        c, hv, Wp, gru0_bih, gru0_bhh, nf_a);

    // ---- GNN layers ----
    __hip_bfloat16* cur = nf_a;
    __hip_bfloat16* nxt = nf_b;
    for (int l = 0; l < L_N; l++) {
        const float* pe_W = gnn_pe_W + (size_t)l * 2 * G_DIM;
        const float* pe_b = gnn_pe_b + l;
        const float* pnW  = gnn_pn_W + (size_t)l * G_DIM * G_DIM;
        const float* pnB  = gnn_pn_b + (size_t)l * G_DIM;
        const float* bih  = gnn_gru_bih + (size_t)l * 3 * G_DIM;
        const float* bhh  = gnn_gru_bhh + (size_t)l * 3 * G_DIM;

        gnn_edge_logits_kernel<<<cdiv(E_N * 64, BLK), BLK, 0, stream>>>(
            cur, src, dst, pe_W, pe_b, logits);

        fill_kernel<<<cdiv(V_N, BLK), BLK, 0, stream>>>(nmax, -INFINITY, V_N);
        fill_kernel<<<cdiv(V_N, BLK), BLK, 0, stream>>>(nsum, 0.f, V_N);
        edge_max_kernel<<<cdiv(E_N, BLK), BLK, 0, stream>>>(logits, dst, nmax);
        edge_expsum_kernel<<<cdiv(E_N, BLK), BLK, 0, stream>>>(logits, dst, nmax, aw, nsum);
        edge_norm_kernel<<<cdiv(E_N, BLK), BLK, 0, stream>>>(aw, dst, nsum);

        gemm_bf16out_kernel<__hip_bfloat16, 0><<<gNode, BLK, 0, stream>>>(
            cur, G_DIM, pnW, G_DIM, pnB, hvp, G_DIM, V_N, G_DIM, G_DIM);

        fill_kernel<<<cdiv((int)VG, BLK), BLK, 0, stream>>>(c, 0.f, (int)VG);
        gnn_scatter_kernel<<<cdiv(E_N * 64, BLK), BLK, 0, stream>>>(hvp, src, dst, aw, c);

        gru_mfma_kernel<<<gGru, BLK, 0, stream>>>(
            c, cur, Wp + (size_t)(l + 1) * WPL, bih, bhh, nxt);

        __hip_bfloat16* tmp = cur; cur = nxt; nxt = tmp;
    }

    // ---- readout ----
    fill_kernel<<<cdiv(NG_N, BLK), BLK, 0, stream>>>(gsum, 0.f, NG_N);
    readout_kernel<<<cdiv(V_N * 64, BLK), BLK, 0, stream>>>(
        cur, pred_W, pred_b, mask, gid, out_atom, gsum);
    graph_out_kernel<<<cdiv(NG_N, BLK), BLK, 0, stream>>>(gsum, out_g);
}

// Round 5
// 3196.948 us; speedup vs baseline: 6.0649x; 2.3455x over previous
//
#include <hip/hip_runtime.h>
#include <hip/hip_bf16.h>
#include <math.h>

#define V_N    100000
#define E_N    400000
#define NFEAT  74
#define NEFEAT 12
#define G_DIM  200
#define L_N    2
#define NG_N   4000

static inline int cdiv(int a, int b) { return (a + b - 1) / b; }

__device__ __forceinline__ float lrelu_f(float x) { return x > 0.f ? x : 0.01f * x; }
__device__ __forceinline__ float sigmoid_f(float x) { return 1.f / (1.f + expf(-x)); }
__device__ __forceinline__ float elu_f(float x) { return x > 0.f ? x : expm1f(x); }
__device__ __forceinline__ float bf2f(__hip_bfloat16 x) { return __bfloat162float(x); }

__device__ __forceinline__ short f2bf(float f) {
    __hip_bfloat16 b = __float2bfloat16(f);
    short s;
    __builtin_memcpy(&s, &b, 2);
    return s;
}

typedef short short8 __attribute__((ext_vector_type(8)));
typedef float f32x4 __attribute__((ext_vector_type(4)));

// ---------------------------------------------------------------------------
__global__ __launch_bounds__(256)
void fill_kernel(float* __restrict__ p, float v, int n)
{
    int i = blockIdx.x * blockDim.x + threadIdx.x;
    if (i < n) p[i] = v;
}

__global__ __launch_bounds__(256)
void fill_int_kernel(int* __restrict__ p, int v, int n)
{
    int i = blockIdx.x * blockDim.x + threadIdx.x;
    if (i < n) p[i] = v;
}

// ---------------------------------------------------------------------------
// Weight prep: Wp[j][k] bf16, j<256, k<Kpad; W is [K, 200] row-major fp32.
// ---------------------------------------------------------------------------
__global__ __launch_bounds__(256)
void wprep_kernel(const float* __restrict__ W, short* __restrict__ Wp, int K, int Kpad)
{
    int idx = blockIdx.x * 256 + threadIdx.x;
    if (idx >= 256 * Kpad) return;
    int j = idx / Kpad, k = idx % Kpad;
    float v = (j < G_DIM && k < K) ? W[(long)k * G_DIM + j] : 0.f;
    Wp[idx] = f2bf(v);
}

// GRU weight prep: Wp[g][j][k], g<3, j<256, k<448 (x at k<200, h at 224..424)
__global__ __launch_bounds__(256)
void gru_wprep_kernel(const float* __restrict__ Wih, const float* __restrict__ Whh,
                      short* __restrict__ Wp)
{
    int idx = blockIdx.x * 256 + threadIdx.x;
    if (idx >= 3 * 256 * 448) return;
    int g = idx / (256 * 448);
    int rem = idx % (256 * 448);
    int j = rem / 448, k = rem % 448;
    float v = 0.f;
    if (j < G_DIM) {
        if (k < G_DIM) v = Wih[(long)k * (3 * G_DIM) + g * G_DIM + j];
        else if (k >= 224 && k < 224 + G_DIM) v = Whh[(long)(k - 224) * (3 * G_DIM) + g * G_DIM + j];
    }
    Wp[idx] = f2bf(v);
}

// ---------------------------------------------------------------------------
// CSR build: deg histogram -> exclusive scan -> fill perm
// ---------------------------------------------------------------------------
__global__ __launch_bounds__(256)
void hist_kernel(const int* __restrict__ dst, int* __restrict__ deg)
{
    int e = blockIdx.x * blockDim.x + threadIdx.x;
    if (e >= E_N) return;
    atomicAdd(&deg[dst[e]], 1);
}

__global__ __launch_bounds__(256)
void scan1_kernel(const int* __restrict__ deg, int* __restrict__ rp, int* __restrict__ bsum)
{
    __shared__ int s[256];
    int tid = threadIdx.x;
    int v = blockIdx.x * 256 + tid;
    int x = (v < V_N) ? deg[v] : 0;
    s[tid] = x;
    __syncthreads();
    for (int off = 1; off < 256; off <<= 1) {
        int t = (tid >= off) ? s[tid - off] : 0;
        __syncthreads();
        s[tid] += t;
        __syncthreads();
    }
    if (v < V_N) rp[v] = s[tid] - x;
    if (tid == 255) bsum[blockIdx.x] = s[255];
}

__global__ void scan2_kernel(int* __restrict__ bsum, int* __restrict__ rp, int nb)
{
    if (threadIdx.x != 0 || blockIdx.x != 0) return;
    int acc = 0;
    for (int b = 0; b < nb; b++) { int t = bsum[b]; bsum[b] = acc; acc += t; }
    rp[V_N] = acc;
}

__global__ __launch_bounds__(256)
void scan3_kernel(int* __restrict__ rp, const int* __restrict__ bsum)
{
    int v = blockIdx.x * 256 + threadIdx.x;
    if (v < V_N) rp[v] += bsum[v >> 8];
}

__global__ __launch_bounds__(256)
void csr_fill_kernel(const int* __restrict__ dst, const int* __restrict__ rp,
                     int* __restrict__ cnt, int* __restrict__ perm)
{
    int e = blockIdx.x * blockDim.x + threadIdx.x;
    if (e >= E_N) return;
    int d = dst[e];
    int pos = rp[d] + atomicAdd(&cnt[d], 1);
    perm[pos] = e;
}

// ---------------------------------------------------------------------------
// Unified MFMA GEMM: C = epi(A[M,K] @ Wp^T + bias), tile 64x64, 4 waves.
// Wp: [256 cols][KPAD] bf16 (pre-transposed, padded). grid (4, cdiv(M,64)).
// ---------------------------------------------------------------------------
#define A_F32    0
#define A_BF16   1
#define EPI_LRELU_BF16 0
#define EPI_BIAS_BF16  1
#define EPI_ELU_BF16   3

template<int AV, int EPI, int K, int KPAD>
__global__ __launch_bounds__(256)
void mfma_gemm_kernel(const float* __restrict__ Af32,
                      const __hip_bfloat16* __restrict__ Abf,
                      const short* __restrict__ Wp,
                      const float* __restrict__ bias,
                      __hip_bfloat16* __restrict__ Cbf,
                      int M)
{
    __shared__ short As[64 * 40];
    __shared__ short Bs[64 * 40];
    const int tid = threadIdx.x;
    const int lane = tid & 63;
    const int w = tid >> 6;
    const int quad = lane >> 4;
    const int lm = lane & 15;
    const int rowBase = blockIdx.y * 64;
    const int j0 = blockIdx.x * 64;
    const int arow = tid >> 2;
    const int akc = (tid & 3) * 8;
    const int agrow = rowBase + arow;

    f32x4 acc[4] = {};

    for (int k0 = 0; k0 < KPAD; k0 += 32) {
        short8 av = {};
        if (agrow < M) {
            int gk = k0 + akc;
            if (AV == A_F32) {
                if (gk + 8 <= K) {
                    const float* p = Af32 + (long)agrow * K + gk;
                    #pragma unroll
                    for (int i = 0; i < 8; i++) av[i] = f2bf(p[i]);
                } else {
                    #pragma unroll
                    for (int i = 0; i < 8; i++) {
                        int kg = gk + i;
                        av[i] = (kg < K) ? f2bf(Af32[(long)agrow * K + kg]) : (short)0;
                    }
                }
            } else {
                if (gk + 8 <= K) {
                    av = *(const short8*)((const short*)Abf + (long)agrow * K + gk);
                } else {
                    #pragma unroll
                    for (int i = 0; i < 8; i++) {
                        int kg = gk + i;
                        av[i] = (kg < K) ? ((const short*)Abf)[(long)agrow * K + kg] : (short)0;
                    }
                }
            }
        }
        *(short8*)&As[arow * 40 + akc] = av;
        {
            int col = tid >> 2;
            *(short8*)&Bs[col * 40 + akc] =
                *(const short8*)(Wp + (long)(j0 + col) * KPAD + k0 + akc);
        }
        __syncthreads();
        short8 a = *(short8*)&As[(w * 16 + lm) * 40 + quad * 8];
        #pragma unroll
        for (int nt = 0; nt < 4; nt++) {
            short8 b = *(short8*)&Bs[(nt * 16 + lm) * 40 + quad * 8];
            acc[nt] = __builtin_amdgcn_mfma_f32_16x16x32_bf16(a, b, acc[nt], 0, 0, 0);
        }
        __syncthreads();
    }

    #pragma unroll
    for (int nt = 0; nt < 4; nt++) {
        int col = j0 + nt * 16 + lm;
        if (col >= G_DIM) continue;
        float bv = bias ? bias[col] : 0.f;
        #pragma unroll
        for (int r = 0; r < 4; r++) {
            int grow = rowBase + w * 16 + quad * 4 + r;
            if (grow >= M) continue;
            float v = acc[nt][r] + bv;
            if (EPI == EPI_LRELU_BF16) v = lrelu_f(v);
            else if (EPI == EPI_ELU_BF16) v = elu_f(v);
            Cbf[(long)grow * G_DIM + col] = __float2bfloat16(v);
        }
    }
}

// ---------------------------------------------------------------------------
// Fused MFMA GRU: out = relu(gru_cell(xc, h))   (xc already elu'd, bf16)
// ---------------------------------------------------------------------------
__global__ __launch_bounds__(256)
void gru_mfma_kernel(const __hip_bfloat16* __restrict__ xc,
                     const __hip_bfloat16* __restrict__ h,
                     const short* __restrict__ Wp,
                     const float* __restrict__ bih, const float* __restrict__ bhh,
                     __hip_bfloat16* __restrict__ out)
{
    __shared__ short As[64 * 40];
    __shared__ short Bs[3 * 64 * 40];
    const int tid = threadIdx.x;
    const int lane = tid & 63;
    const int w = tid >> 6;
    const int quad = lane >> 4;
    const int lm = lane & 15;
    const int rowBase = blockIdx.y * 64;
    const int j0 = blockIdx.x * 64;

    const int arow = tid >> 2;
    const int akc = (tid & 3) * 8;
    const int agrow = rowBase + arow;

    f32x4 accNlo[4] = {}, accNhi[4] = {};
    f32x4 accRt[4] = {}, accZt[4] = {};

    #pragma unroll 1
    for (int phase = 0; phase < 2; phase++) {
        const short* Aptr = (phase == 0) ? (const short*)xc : (const short*)h;
        for (int k0 = phase * 224; k0 < (phase + 1) * 224; k0 += 32) {
            {
                short8 v = {};
                int lk = k0 - phase * 224 + akc;
                if (agrow < V_N && lk < G_DIM)
                    v = *(const short8*)(Aptr + (long)agrow * G_DIM + lk);
                *(short8*)&As[arow * 40 + akc] = v;
            }
            {
                #pragma unroll
                for (int i = 0; i < 3; i++) {
                    int idx8 = tid + i * 256;
                    int base = idx8 * 8;
                    int g = base >> 11;
                    int rem = base & 2047;
                    int jrow = rem >> 5, kc = rem & 31;
                    long goff = ((long)g * 256 + (j0 + jrow)) * 448 + (k0 + kc);
                    *(short8*)&Bs[(g * 64 + jrow) * 40 + kc] = *(const short8*)(Wp + goff);
                }
            }
            __syncthreads();
            short8 a = *(short8*)&As[(w * 16 + lm) * 40 + quad * 8];
            #pragma unroll
            for (int nt = 0; nt < 4; nt++) {
                int coll = nt * 16 + lm;
                short8 br = *(short8*)&Bs[(0 * 64 + coll) * 40 + quad * 8];
                short8 bz = *(short8*)&Bs[(1 * 64 + coll) * 40 + quad * 8];
                short8 bn = *(short8*)&Bs[(2 * 64 + coll) * 40 + quad * 8];
                accRt[nt] = __builtin_amdgcn_mfma_f32_16x16x32_bf16(a, br, accRt[nt], 0, 0, 0);
                accZt[nt] = __builtin_amdgcn_mfma_f32_16x16x32_bf16(a, bz, accZt[nt], 0, 0, 0);
                if (phase == 0)
                    accNlo[nt] = __builtin_amdgcn_mfma_f32_16x16x32_bf16(a, bn, accNlo[nt], 0, 0, 0);
                else
                    accNhi[nt] = __builtin_amdgcn_mfma_f32_16x16x32_bf16(a, bn, accNhi[nt], 0, 0, 0);
            }
            __syncthreads();
        }
    }

    #pragma unroll
    for (int nt = 0; nt < 4; nt++) {
        int col = j0 + nt * 16 + lm;
        if (col >= G_DIM) continue;
        float b_ir = bih[col], b_iz = bih[G_DIM + col], b_in = bih[2 * G_DIM + col];
        float b_hr = bhh[col], b_hz = bhh[G_DIM + col], b_hn = bhh[2 * G_DIM + col];
        #pragma unroll
        for (int r = 0; r < 4; r++) {
            int grow = rowBase + w * 16 + quad * 4 + r;
            if (grow >= V_N) continue;
            float sr = accRt[nt][r] + b_ir + b_hr;
            float sz = accZt[nt][r] + b_iz + b_hz;
            float gin = accNlo[nt][r] + b_in;
            float ghn = accNhi[nt][r] + b_hn;
            float rr = sigmoid_f(sr);
            float zz = sigmoid_f(sz);
            float nn = tanhf(gin + rr * ghn);
            float hval = bf2f(h[(long)grow * G_DIM + col]);
            float o = (1.f - zz) * nn + zz * hval;
            out[(long)grow * G_DIM + col] = __float2bfloat16(o > 0.f ? o : 0.f);
        }
    }
}

// ---------------------------------------------------------------------------
// Ctx edge logits, he1 on the fly:
//   he1[e][k] = lrelu(P[src[e]][k] + sum_j ef[e][j]*Wef[j][k])
//   logits[e] = lrelu( hv[dst[e]]·w1 + he1[e]·w2 + b )
// wave per edge, 4 edges/block.
// ---------------------------------------------------------------------------
__global__ __launch_bounds__(256)
void ctx_edge_logits_kernel(const __hip_bfloat16* __restrict__ P,
                            const __hip_bfloat16* __restrict__ hv,
                            const float* __restrict__ efeat,
                            const int* __restrict__ src, const int* __restrict__ dst,
                            const float* __restrict__ pe1W,
                            const float* __restrict__ pe2W, const float* __restrict__ pe2b,
                            float* __restrict__ logits)
{
    __shared__ float Wef[NEFEAT * G_DIM];
    __shared__ float w1s[G_DIM], w2s[G_DIM];
    const int tid = threadIdx.x;
    for (int i = tid; i < NEFEAT * G_DIM; i += 256) {
        int j = i / G_DIM, k = i % G_DIM;
        Wef[i] = pe1W[(long)(NFEAT + j) * G_DIM + k];
    }
    for (int i = tid; i < G_DIM; i += 256) { w1s[i] = pe2W[i]; w2s[i] = pe2W[G_DIM + i]; }
    __syncthreads();
    const int w = tid >> 6, lane = tid & 63;
    int e = blockIdx.x * 4 + w;
    if (e >= E_N) return;
    int s = src[e], d = dst[e];
    float efj = (lane < NEFEAT) ? efeat[(long)e * NEFEAT + lane] : 0.f;
    float ef[NEFEAT];
    #pragma unroll
    for (int j = 0; j < NEFEAT; j++) ef[j] = __shfl(efj, j, 64);
    float acc = 0.f;
    #pragma unroll
    for (int c = 0; c < 4; c++) {
        int k = c * 64 + lane;
        if (k < G_DIM) {
            float q = 0.f;
            #pragma unroll
            for (int j = 0; j < NEFEAT; j++) q += ef[j] * Wef[j * G_DIM + k];
            float he1k = lrelu_f(bf2f(P[(long)s * G_DIM + k]) + q);
            acc += he1k * w2s[k] + bf2f(hv[(long)d * G_DIM + k]) * w1s[k];
        }
    }
    for (int off = 32; off > 0; off >>= 1) acc += __shfl_down(acc, off, 64);
    if (lane == 0) logits[e] = lrelu_f(acc + pe2b[0]);
}

// ---------------------------------------------------------------------------
// Ctx aggregation: hbar[v] = sum_{e in(v)} aw[e] * he1[e]  (he1 on the fly)
// wave per node, 4 nodes/block.
// ---------------------------------------------------------------------------
__global__ __launch_bounds__(256)
void ctx_agg_kernel(const __hip_bfloat16* __restrict__ P,
                    const float* __restrict__ efeat,
                    const int* __restrict__ src,
                    const int* __restrict__ rp, const int* __restrict__ perm,
                    const float* __restrict__ aw,
                    const float* __restrict__ pe1W,
                    __hip_bfloat16* __restrict__ hbar)
{
    __shared__ float Wef[NEFEAT * G_DIM];
    const int tid = threadIdx.x;
    for (int i = tid; i < NEFEAT * G_DIM; i += 256) {
        int j = i / G_DIM, k = i % G_DIM;
        Wef[i] = pe1W[(long)(NFEAT + j) * G_DIM + k];
    }
    __syncthreads();
    const int w = tid >> 6, lane = tid & 63;
    int v = blockIdx.x * 4 + w;
    if (v >= V_N) return;
    float a[4] = {};
    int b = rp[v], en = rp[v + 1];
    for (int i = b; i < en; i++) {
        int e = perm[i];
        float we = aw[e];
        int s = src[e];
        float efj = (lane < NEFEAT) ? efeat[(long)e * NEFEAT + lane] : 0.f;
        float ef[NEFEAT];
        #pragma unroll
        for (int j = 0; j < NEFEAT; j++) ef[j] = __shfl(efj, j, 64);
        #pragma unroll
        for (int c = 0; c < 4; c++) {
            int k = c * 64 + lane;
            if (k < G_DIM) {
                float q = 0.f;
                #pragma unroll
                for (int j = 0; j < NEFEAT; j++) q += ef[j] * Wef[j * G_DIM + k];
                a[c] += we * lrelu_f(bf2f(P[(long)s * G_DIM + k]) + q);
            }
        }
    }
    #pragma unroll
    for (int c = 0; c < 4; c++) {
        int k = c * 64 + lane;
        if (k < G_DIM) hbar[(long)v * G_DIM + k] = __float2bfloat16(a[c]);
    }
}

// ---------------------------------------------------------------------------
// GNN edge logits: lrelu(nf[dst]·w[0:200] + nf[src]·w[200:400] + b)
// ---------------------------------------------------------------------------
__global__ __launch_bounds__(256)
void gnn_edge_logits_kernel(const __hip_bfloat16* __restrict__ nf,
                            const int* __restrict__ src, const int* __restrict__ dst,
                            const float* __restrict__ w, const float* __restrict__ b,
                            float* __restrict__ out)
{
    int gtid = blockIdx.x * blockDim.x + threadIdx.x;
    int e = gtid >> 6, lane = gtid & 63;
    if (e >= E_N) return;
    int d = dst[e], s = src[e];
    float acc = 0.f;
    for (int k = lane; k < G_DIM; k += 64) {
        acc += bf2f(nf[(long)d * G_DIM + k]) * w[k];
        acc += bf2f(nf[(long)s * G_DIM + k]) * w[G_DIM + k];
    }
    for (int off = 32; off > 0; off >>= 1) acc += __shfl_down(acc, off, 64);
    if (lane == 0) out[e] = lrelu_f(acc + b[0]);
}

// ---------------------------------------------------------------------------
// CSR softmax over incoming edges (thread per node)
// ---------------------------------------------------------------------------
__global__ __launch_bounds__(256)
void softmax_csr_kernel(const float* __restrict__ logits, const int* __restrict__ rp,
                        const int* __restrict__ perm, float* __restrict__ aw)
{
    int v = blockIdx.x * blockDim.x + threadIdx.x;
    if (v >= V_N) return;
    int b = rp[v], en = rp[v + 1];
    if (en == b) return;
    float m = -INFINITY;
    for (int i = b; i < en; i++) m = fmaxf(m, logits[perm[i]]);
    float s = 0.f;
    for (int i = b; i < en; i++) s += expf(logits[perm[i]] - m);
    float inv = 1.f / s;
    for (int i = b; i < en; i++) {
        int e = perm[i];
        aw[e] = expf(logits[e] - m) * inv;
    }
}

// ---------------------------------------------------------------------------
// GNN aggregate: c[v] = elu( sum_{e in(v)} aw[e] * hvp[src[e]] )  -> bf16
// ---------------------------------------------------------------------------
__global__ __launch_bounds__(256)
void gnn_agg_kernel(const __hip_bfloat16* __restrict__ X, const int* __restrict__ src,
                    const int* __restrict__ rp, const int* __restrict__ perm,
                    const float* __restrict__ aw, __hip_bfloat16* __restrict__ out)
{
    int w = threadIdx.x >> 6, lane = threadIdx.x & 63;
    int v = blockIdx.x * 4 + w;
    if (v >= V_N) return;
    float a[4] = {};
    int b = rp[v], en = rp[v + 1];
    for (int i = b; i < en; i++) {
        int e = perm[i];
        float we = aw[e];
        long basep = (long)src[e] * G_DIM;
        a[0] += we * bf2f(X[basep + lane]);
        a[1] += we * bf2f(X[basep + 64 + lane]);
        a[2] += we * bf2f(X[basep + 128 + lane]);
        if (lane < 8) a[3] += we * bf2f(X[basep + 192 + lane]);
    }
    out[(long)v * G_DIM + lane] = __float2bfloat16(elu_f(a[0]));
    out[(long)v * G_DIM + 64 + lane] = __float2bfloat16(elu_f(a[1]));
    out[(long)v * G_DIM + 128 + lane] = __float2bfloat16(elu_f(a[2]));
    if (lane < 8) out[(long)v * G_DIM + 192 + lane] = __float2bfloat16(elu_f(a[3]));
}

// ---------------------------------------------------------------------------
// readout
// ---------------------------------------------------------------------------
__global__ __launch_bounds__(256)
void mask_kernel(const float* __restrict__ nfeat, float* __restrict__ mask)
{
    int v = blockIdx.x * blockDim.x + threadIdx.x;
    if (v >= V_N) return;
    const float* row = nfeat + (long)v * NFEAT;
    float s = row[NFEAT - 4] + row[NFEAT - 3] + row[NFEAT - 2] + row[NFEAT - 1];
    float m = s * (1.f - row[0]);
    mask[v] = 1.f / m - 1.f;
}

__global__ __launch_bounds__(256)
void readout_kernel(const __hip_bfloat16* __restrict__ nf, const float* __restrict__ predW,
                    const float* __restrict__ predb, const float* __restrict__ mask,
                    const int* __restrict__ gid, float* __restrict__ out_atom,
                    float* __restrict__ gsum)
{
    int gtid = blockIdx.x * blockDim.x + threadIdx.x;
    int v = gtid >> 6, lane = gtid & 63;
    if (v >= V_N) return;
    float acc = 0.f;
    for (int k = lane; k < G_DIM; k += 64)
        acc += bf2f(nf[(long)v * G_DIM + k]) * predW[k];
    for (int off = 32; off > 0; off >>= 1) acc += __shfl_down(acc, off, 64);
    if (lane == 0) {
        float p = acc + predb[0] + mask[v];
        out_atom[v] = p;
        atomicAdd(&gsum[gid[v]], exp10f(-p));
    }
}

__global__ __launch_bounds__(256)
void graph_out_kernel(const float* __restrict__ gsum, float* __restrict__ out_g)
{
    int g = blockIdx.x * blockDim.x + threadIdx.x;
    if (g >= NG_N) return;
    out_g[g] = -log10f(gsum[g]);
}

// ---------------------------------------------------------------------------
extern "C" void kernel_launch(void* const* d_in, const int* in_sizes, int n_in,
                              void* d_out, int out_size, void* d_ws, size_t ws_size,
                              hipStream_t stream)
{
    const float* node_feats = (const float*)d_in[0];
    const float* edge_feats = (const float*)d_in[1];
    const float* pn_W  = (const float*)d_in[2];
    const float* pn_b  = (const float*)d_in[3];
    const float* pe1_W = (const float*)d_in[4];
    const float* pe1_b = (const float*)d_in[5];
    const float* pe2_W = (const float*)d_in[6];
    const float* pe2_b = (const float*)d_in[7];
    const float* et_W  = (const float*)d_in[8];
    const float* et_b  = (const float*)d_in[9];
    const float* gru0_Wih = (const float*)d_in[10];
    const float* gru0_Whh = (const float*)d_in[11];
    const float* gru0_bih = (const float*)d_in[12];
    const float* gru0_bhh = (const float*)d_in[13];
    const float* gnn_pe_W = (const float*)d_in[14];
    const float* gnn_pe_b = (const float*)d_in[15];
    const float* gnn_pn_W = (const float*)d_in[16];
    const float* gnn_pn_b = (const float*)d_in[17];
    const float* gnn_gru_Wih = (const float*)d_in[18];
    const float* gnn_gru_Whh = (const float*)d_in[19];
    const float* gnn_gru_bih = (const float*)d_in[20];
    const float* gnn_gru_bhh = (const float*)d_in[21];
    const float* pred_W = (const float*)d_in[22];
    const float* pred_b = (const float*)d_in[23];
    const int* src = (const int*)d_in[24];
    const int* dst = (const int*)d_in[25];
    const int* gid = (const int*)d_in[26];

    float* out_g = (float*)d_out;
    float* out_atom = out_g + NG_N;

    char* base = (char*)d_ws;
    size_t off = 0;
    auto take = [&](size_t bytes) -> void* {
        void* p = base + off;
        off += (bytes + 255) & ~(size_t)255;
        return p;
    };
    const size_t VG = (size_t)V_N * G_DIM;
    const size_t WPL = 3 * 256 * 448;
    float* mask   = (float*)take((size_t)V_N * 4);
    float* logits = (float*)take((size_t)E_N * 4);
    float* aw     = (float*)take((size_t)E_N * 4);
    float* gsum   = (float*)take((size_t)NG_N * 4);
    __hip_bfloat16* c    = (__hip_bfloat16*)take(VG * 2);
    __hip_bfloat16* hv   = (__hip_bfloat16*)take(VG * 2);
    __hip_bfloat16* nf_a = (__hip_bfloat16*)take(VG * 2);
    __hip_bfloat16* nf_b = (__hip_bfloat16*)take(VG * 2);
    short* WpGru = (short*)take(3 * WPL * 2);
    short* Wp_pn0 = (short*)take((size_t)256 * 96 * 2);
    short* Wp_pe1 = (short*)take((size_t)256 * 96 * 2);
    short* Wp_et  = (short*)take((size_t)256 * 224 * 2);
    short* Wp_pn1 = (short*)take((size_t)256 * 224 * 2);
    short* Wp_pn2 = (short*)take((size_t)256 * 224 * 2);
    int* deg  = (int*)take((size_t)V_N * 4);
    int* cnt  = (int*)take((size_t)V_N * 4);
    int* rp   = (int*)take((size_t)(V_N + 1) * 4);
    int* perm = (int*)take((size_t)E_N * 4);
    int* bsum = (int*)take((size_t)512 * 4);
    __hip_bfloat16* P    = nf_a;  // alias: nf_a written only at GRU0 (P dead by then)
    __hip_bfloat16* hbar = nf_b;  // alias: nf_b first written as layer-0 GRU output
    __hip_bfloat16* hvp  = hv;    // alias: hv dead after GRU0

    if (off > ws_size) {
        fill_kernel<<<cdiv(out_size, 256), 256, 0, stream>>>((float*)d_out, -12345.f, out_size);
        return;
    }

    const int BLK = 256;
    const int nScanBlocks = cdiv(V_N, 256);
    const dim3 gNode(4, cdiv(V_N, 64));
    const int gEdge4 = cdiv(E_N, 4);
    const int gAgg = cdiv(V_N, 4);

    // ---- weight prep ----
    gru_wprep_kernel<<<cdiv(3 * 256 * 448, 256), BLK, 0, stream>>>(gru0_Wih, gru0_Whh, WpGru);
    for (int l = 0; l < L_N; l++)
        gru_wprep_kernel<<<cdiv(3 * 256 * 448, 256), BLK, 0, stream>>>(
            gnn_gru_Wih + (size_t)l * G_DIM * 3 * G_DIM,
            gnn_gru_Whh + (size_t)l * G_DIM * 3 * G_DIM,
            WpGru + (size_t)(l + 1) * WPL);
    wprep_kernel<<<cdiv(256 * 96, 256), BLK, 0, stream>>>(pn_W, Wp_pn0, NFEAT, 96);
    wprep_kernel<<<cdiv(256 * 96, 256), BLK, 0, stream>>>(pe1_W, Wp_pe1, NFEAT, 96); // node rows only
    wprep_kernel<<<cdiv(256 * 224, 256), BLK, 0, stream>>>(et_W, Wp_et, G_DIM, 224);
    wprep_kernel<<<cdiv(256 * 224, 256), BLK, 0, stream>>>(gnn_pn_W, Wp_pn1, G_DIM, 224);
    wprep_kernel<<<cdiv(256 * 224, 256), BLK, 0, stream>>>(gnn_pn_W + (size_t)G_DIM * G_DIM,
                                                           Wp_pn2, G_DIM, 224);

    mask_kernel<<<cdiv(V_N, BLK), BLK, 0, stream>>>(node_feats, mask);

    // ---- CSR build (by dst) ----
    fill_int_kernel<<<cdiv(V_N, BLK), BLK, 0, stream>>>(deg, 0, V_N);
    hist_kernel<<<cdiv(E_N, BLK), BLK, 0, stream>>>(dst, deg);
    scan1_kernel<<<nScanBlocks, BLK, 0, stream>>>(deg, rp, bsum);
    scan2_kernel<<<1, 1, 0, stream>>>(bsum, rp, nScanBlocks);
    scan3_kernel<<<nScanBlocks, BLK, 0, stream>>>(rp, bsum);
    fill_int_kernel<<<cdiv(V_N, BLK), BLK, 0, stream>>>(cnt, 0, V_N);
    csr_fill_kernel<<<cdiv(E_N, BLK), BLK, 0, stream>>>(dst, rp, cnt, perm);

    // ---- GetContext ----
    // hv = lrelu(node_feats @ pn_W + pn_b)
    mfma_gemm_kernel<A_F32, EPI_LRELU_BF16, NFEAT, 96><<<gNode, BLK, 0, stream>>>(
        node_feats, nullptr, Wp_pn0, pn_b, hv, V_N);
    // P = node_feats @ pe1_W[0:74] + pe1_b   (no lrelu; he1 = lrelu(P[src]+Q) later)
    mfma_gemm_kernel<A_F32, EPI_BIAS_BF16, NFEAT, 96><<<gNode, BLK, 0, stream>>>(
        node_feats, nullptr, Wp_pe1, pe1_b, P, V_N);
    // logits / softmax
    ctx_edge_logits_kernel<<<gEdge4, BLK, 0, stream>>>(
        P, hv, edge_feats, src, dst, pe1_W, pe2_W, pe2_b, logits);
    softmax_csr_kernel<<<cdiv(V_N, BLK), BLK, 0, stream>>>(logits, rp, perm, aw);
    // hbar[v] = sum aw_e * he1_e
    ctx_agg_kernel<<<gAgg, BLK, 0, stream>>>(P, edge_feats, src, rp, perm, aw, pe1_W, hbar);
    // c = elu(hbar @ et_W + et_b)
    mfma_gemm_kernel<A_BF16, EPI_ELU_BF16, G_DIM, 224><<<gNode, BLK, 0, stream>>>(
        nullptr, hbar, Wp_et, et_b, c, V_N);
    // nf = relu(gru(c, hv))
    gru_mfma_kernel<<<gNode, BLK, 0, stream>>>(c, hv, WpGru, gru0_bih, gru0_bhh, nf_a);

    // ---- GNN layers ----
    __hip_bfloat16* cur = nf_a;
    __hip_bfloat16* nxt = nf_b;
    for (int l = 0; l < L_N; l++) {
        const float* pe_W = gnn_pe_W + (size_t)l * 2 * G_DIM;
        const float* pe_b = gnn_pe_b + l;
        const float* pnB  = gnn_pn_b + (size_t)l * G_DIM;
        const float* bih  = gnn_gru_bih + (size_t)l * 3 * G_DIM;
        const float* bhh  = gnn_gru_bhh + (size_t)l * 3 * G_DIM;
        const short* WpPn = (l == 0) ? Wp_pn1 : Wp_pn2;

        gnn_edge_logits_kernel<<<cdiv(E_N * 64, BLK), BLK, 0, stream>>>(
            cur, src, dst, pe_W, pe_b, logits);
        softmax_csr_kernel<<<cdiv(V_N, BLK), BLK, 0, stream>>>(logits, rp, perm, aw);

        // hvp = cur @ pnW + pnB
        mfma_gemm_kernel<A_BF16, EPI_BIAS_BF16, G_DIM, 224><<<gNode, BLK, 0, stream>>>(
            nullptr, cur, WpPn, pnB, hvp, V_N);
        // c[v] = elu(sum aw_e * hvp[src[e]])
        gnn_agg_kernel<<<gAgg, BLK, 0, stream>>>(hvp, src, rp, perm, aw, c);
        gru_mfma_kernel<<<gNode, BLK, 0, stream>>>(
            c, cur, WpGru + (size_t)(l + 1) * WPL, bih, bhh, nxt);

        __hip_bfloat16* tmp = cur; cur = nxt; nxt = tmp;
    }

    // ---- readout ----
    fill_kernel<<<cdiv(NG_N, BLK), BLK, 0, stream>>>(gsum, 0.f, NG_N);
    readout_kernel<<<cdiv(V_N * 64, BLK), BLK, 0, stream>>>(
        cur, pred_W, pred_b, mask, gid, out_atom, gsum);
    graph_out_kernel<<<cdiv(NG_N, BLK), BLK, 0, stream>>>(gsum, out_g);
}

// Round 6
// 2627.580 us; speedup vs baseline: 7.3791x; 1.2167x over previous
//
#include <hip/hip_runtime.h>
#include <hip/hip_bf16.h>
#include <math.h>

#define V_N    100000
#define E_N    400000
#define NFEAT  74
#define NEFEAT 12
#define G_DIM  200
#define LDA    224          // padded leading dim for all bf16 node matrices
#define L_N    2
#define NG_N   4000

static inline int cdiv(int a, int b) { return (a + b - 1) / b; }

__device__ __forceinline__ float lrelu_f(float x) { return x > 0.f ? x : 0.01f * x; }
__device__ __forceinline__ float sigmoid_f(float x) { return 1.f / (1.f + expf(-x)); }
__device__ __forceinline__ float elu_f(float x) { return x > 0.f ? x : expm1f(x); }
__device__ __forceinline__ float bf2f(__hip_bfloat16 x) { return __bfloat162float(x); }

__device__ __forceinline__ short f2bf(float f) {
    __hip_bfloat16 b = __float2bfloat16(f);
    short s;
    __builtin_memcpy(&s, &b, 2);
    return s;
}

typedef short short8 __attribute__((ext_vector_type(8)));
typedef float f32x4 __attribute__((ext_vector_type(4)));

#define MFMA16(a, b, c) __builtin_amdgcn_mfma_f32_16x16x32_bf16((a), (b), (c), 0, 0, 0)

// ---------------------------------------------------------------------------
__global__ __launch_bounds__(256)
void fill_kernel(float* __restrict__ p, float v, int n)
{
    int i = blockIdx.x * blockDim.x + threadIdx.x;
    if (i < n) p[i] = v;
}

__global__ __launch_bounds__(256)
void fill_int_kernel(int* __restrict__ p, int v, int n)
{
    int i = blockIdx.x * blockDim.x + threadIdx.x;
    if (i < n) p[i] = v;
}

// ---------------------------------------------------------------------------
// Weight preps
// ---------------------------------------------------------------------------
// Old-style (64x64 GEMM): Wp[j<256][k<Kpad], W is [K,200] fp32
__global__ __launch_bounds__(256)
void wprep_kernel(const float* __restrict__ W, short* __restrict__ Wp, int K, int Kpad)
{
    int idx = blockIdx.x * 256 + threadIdx.x;
    if (idx >= 256 * Kpad) return;
    int j = idx / Kpad, k = idx % Kpad;
    float v = (j < G_DIM && k < K) ? W[(long)k * G_DIM + j] : 0.f;
    Wp[idx] = f2bf(v);
}

// Tiled for K=224 GEMM: Wp[cb<7][st<7][cc<32][kk<32]; col=cb*32+cc, k=st*32+kk
__global__ __launch_bounds__(256)
void wprep_tiled_kernel(const float* __restrict__ W, short* __restrict__ Wp)
{
    int idx = blockIdx.x * 256 + threadIdx.x;
    if (idx >= 7 * 7 * 1024) return;
    int cb = idx / (7 * 1024);
    int r = idx % (7 * 1024);
    int st = r / 1024;
    int r2 = r % 1024;
    int cc = r2 / 32, kk = r2 % 32;
    int col = cb * 32 + cc, k = st * 32 + kk;
    float v = (col < G_DIM && k < G_DIM) ? W[(long)k * G_DIM + col] : 0.f;
    Wp[idx] = f2bf(v);
}

// GRU tiled: Wp[cb<7][st<14][g<3][cc<32][kk<32]; st<7 -> Wih, st>=7 -> Whh
__global__ __launch_bounds__(256)
void gru_wprep_kernel(const float* __restrict__ Wih, const float* __restrict__ Whh,
                      short* __restrict__ Wp)
{
    int idx = blockIdx.x * 256 + threadIdx.x;
    if (idx >= 7 * 14 * 3072) return;
    int cb = idx / (14 * 3072);
    int r = idx % (14 * 3072);
    int st = r / 3072;
    int r2 = r % 3072;
    int g = r2 / 1024;
    int r3 = r2 % 1024;
    int cc = r3 / 32, kk = r3 % 32;
    int col = cb * 32 + cc;
    float v = 0.f;
    if (col < G_DIM) {
        if (st < 7) {
            int k = st * 32 + kk;
            if (k < G_DIM) v = Wih[(long)k * (3 * G_DIM) + g * G_DIM + col];
        } else {
            int k = (st - 7) * 32 + kk;
            if (k < G_DIM) v = Whh[(long)k * (3 * G_DIM) + g * G_DIM + col];
        }
    }
    Wp[idx] = f2bf(v);
}

// ---------------------------------------------------------------------------
// CSR build
// ---------------------------------------------------------------------------
__global__ __launch_bounds__(256)
void hist_kernel(const int* __restrict__ dst, int* __restrict__ deg)
{
    int e = blockIdx.x * blockDim.x + threadIdx.x;
    if (e >= E_N) return;
    atomicAdd(&deg[dst[e]], 1);
}

__global__ __launch_bounds__(256)
void scan1_kernel(const int* __restrict__ deg, int* __restrict__ rp, int* __restrict__ bsum)
{
    __shared__ int s[256];
    int tid = threadIdx.x;
    int v = blockIdx.x * 256 + tid;
    int x = (v < V_N) ? deg[v] : 0;
    s[tid] = x;
    __syncthreads();
    for (int off = 1; off < 256; off <<= 1) {
        int t = (tid >= off) ? s[tid - off] : 0;
        __syncthreads();
        s[tid] += t;
        __syncthreads();
    }
    if (v < V_N) rp[v] = s[tid] - x;
    if (tid == 255) bsum[blockIdx.x] = s[255];
}

__global__ void scan2_kernel(int* __restrict__ bsum, int* __restrict__ rp, int nb)
{
    if (threadIdx.x != 0 || blockIdx.x != 0) return;
    int acc = 0;
    for (int b = 0; b < nb; b++) { int t = bsum[b]; bsum[b] = acc; acc += t; }
    rp[V_N] = acc;
}

__global__ __launch_bounds__(256)
void scan3_kernel(int* __restrict__ rp, const int* __restrict__ bsum)
{
    int v = blockIdx.x * 256 + threadIdx.x;
    if (v < V_N) rp[v] += bsum[v >> 8];
}

__global__ __launch_bounds__(256)
void csr_fill_kernel(const int* __restrict__ dst, const int* __restrict__ rp,
                     int* __restrict__ cnt, int* __restrict__ perm)
{
    int e = blockIdx.x * blockDim.x + threadIdx.x;
    if (e >= E_N) return;
    int d = dst[e];
    int pos = rp[d] + atomicAdd(&cnt[d], 1);
    perm[pos] = e;
}

// ---------------------------------------------------------------------------
// Old 64x64 MFMA GEMM for fp32-A inputs (K=74 pad 96): hv, P
// Wp old layout [256][96]; out bf16 stride LDA.
// ---------------------------------------------------------------------------
template<int EPI>   // 0 = lrelu, 1 = bias only
__global__ __launch_bounds__(256)
void gemm_f32a_kernel(const float* __restrict__ Af32,
                      const short* __restrict__ Wp,
                      const float* __restrict__ bias,
                      __hip_bfloat16* __restrict__ Cbf)
{
    __shared__ short As[64 * 40];
    __shared__ short Bs[64 * 40];
    const int tid = threadIdx.x;
    const int lane = tid & 63;
    const int w = tid >> 6;
    const int quad = lane >> 4;
    const int lm = lane & 15;
    const int rowBase = blockIdx.y * 64;
    const int j0 = blockIdx.x * 64;
    const int arow = tid >> 2;
    const int akc = (tid & 3) * 8;
    const int agrow = rowBase + arow;

    f32x4 acc[4] = {};

    for (int k0 = 0; k0 < 96; k0 += 32) {
        short8 av = {};
        if (agrow < V_N) {
            int gk = k0 + akc;
            #pragma unroll
            for (int i = 0; i < 8; i++) {
                int kg = gk + i;
                av[i] = (kg < NFEAT) ? f2bf(Af32[(long)agrow * NFEAT + kg]) : (short)0;
            }
        }
        *(short8*)&As[arow * 40 + akc] = av;
        {
            int col = tid >> 2;
            *(short8*)&Bs[col * 40 + akc] =
                *(const short8*)(Wp + (long)(j0 + col) * 96 + k0 + akc);
        }
        __syncthreads();
        short8 a = *(short8*)&As[(w * 16 + lm) * 40 + quad * 8];
        #pragma unroll
        for (int nt = 0; nt < 4; nt++) {
            short8 b = *(short8*)&Bs[(nt * 16 + lm) * 40 + quad * 8];
            acc[nt] = MFMA16(a, b, acc[nt]);
        }
        __syncthreads();
    }

    #pragma unroll
    for (int nt = 0; nt < 4; nt++) {
        int col = j0 + nt * 16 + lm;
        if (col >= G_DIM) continue;
        float bv = bias[col];
        #pragma unroll
        for (int r = 0; r < 4; r++) {
            int grow = rowBase + w * 16 + quad * 4 + r;
            if (grow >= V_N) continue;
            float v = acc[nt][r] + bv;
            if (EPI == 0) v = lrelu_f(v);
            Cbf[(long)grow * LDA + col] = __float2bfloat16(v);
        }
    }
}

// ---------------------------------------------------------------------------
// New 256x32 MFMA GEMM, bf16 A [V][LDA], K=224, Wp tiled [7][7][32][32].
// 4 waves; wave w covers rows w*64..w*64+63 (4 rt), cols cb*32..+31 (2 nt).
// ---------------------------------------------------------------------------
template<int EPI>   // 1 = bias only, 3 = elu
__global__ __launch_bounds__(256)
void gemm_bf16a_kernel(const __hip_bfloat16* __restrict__ Abf,
                       const short* __restrict__ Wp,
                       const float* __restrict__ bias,
                       __hip_bfloat16* __restrict__ Cbf)
{
    __shared__ short As[256 * 32];
    __shared__ short Bs[32 * 32];
    const int tid = threadIdx.x;
    const int lane = tid & 63;
    const int w = tid >> 6;
    const int quad = lane >> 4;
    const int lm = lane & 15;
    const int cb = blockIdx.x;            // 0..6
    const int j0 = cb * 32;
    const int rowBase = blockIdx.y * 256;
    const int sRow = tid >> 2;
    const int sChunk = (tid & 3) * 8;

    const short* WpB = Wp + (long)cb * (7 * 1024);
    f32x4 acc[4][2] = {};

    #pragma unroll 1
    for (int st = 0; st < 7; st++) {
        int kl = st * 32;
        #pragma unroll
        for (int p = 0; p < 4; p++) {
            int r = sRow + p * 64;
            int gr = rowBase + r;
            short8 v = {};
            if (gr < V_N) v = *(const short8*)((const short*)Abf + (long)gr * LDA + kl + sChunk);
            *(short8*)&As[r * 32 + sChunk] = v;
        }
        if (tid < 128)
            *(short8*)&Bs[tid * 8] = *(const short8*)(WpB + st * 1024 + tid * 8);
        __syncthreads();
        short8 b0 = *(short8*)&Bs[(0 * 16 + lm) * 32 + quad * 8];
        short8 b1 = *(short8*)&Bs[(1 * 16 + lm) * 32 + quad * 8];
        #pragma unroll
        for (int rt = 0; rt < 4; rt++) {
            short8 a = *(short8*)&As[(w * 64 + rt * 16 + lm) * 32 + quad * 8];
            acc[rt][0] = MFMA16(a, b0, acc[rt][0]);
            acc[rt][1] = MFMA16(a, b1, acc[rt][1]);
        }
        __syncthreads();
    }

    #pragma unroll
    for (int nt = 0; nt < 2; nt++) {
        int col = j0 + nt * 16 + lm;
        if (col >= G_DIM) continue;
        float bv = bias[col];
        #pragma unroll
        for (int rt = 0; rt < 4; rt++) {
            #pragma unroll
            for (int r = 0; r < 4; r++) {
                int grow = rowBase + w * 64 + rt * 16 + quad * 4 + r;
                if (grow >= V_N) continue;
                float v = acc[rt][nt][r] + bv;
                if (EPI == 3) v = elu_f(v);
                Cbf[(long)grow * LDA + col] = __float2bfloat16(v);
            }
        }
    }
}

// ---------------------------------------------------------------------------
// Fused MFMA GRU: out = relu(gru_cell(xc, h)); xc,h bf16 [V][LDA] (pads zero)
// block 256x32 tile, Wp [7][14][3][32][32]; steps 0..6 = x, 7..13 = h.
// ---------------------------------------------------------------------------
__global__ __launch_bounds__(256)
void gru_mfma_kernel(const __hip_bfloat16* __restrict__ xc,
                     const __hip_bfloat16* __restrict__ h,
                     const short* __restrict__ Wp,
                     const float* __restrict__ bih, const float* __restrict__ bhh,
                     __hip_bfloat16* __restrict__ out)
{
    __shared__ short As[256 * 32];
    __shared__ short Bs[3 * 32 * 32];
    const int tid = threadIdx.x;
    const int lane = tid & 63;
    const int w = tid >> 6;
    const int quad = lane >> 4;
    const int lm = lane & 15;
    const int cb = blockIdx.x;            // 0..6
    const int j0 = cb * 32;
    const int rowBase = blockIdx.y * 256;
    const int sRow = tid >> 2;
    const int sChunk = (tid & 3) * 8;

    const short* WpB = Wp + (long)cb * (14 * 3072);

    f32x4 aR[4][2] = {}, aZ[4][2] = {}, aNl[4][2] = {}, aNh[4][2] = {};

    #pragma unroll 1
    for (int st = 0; st < 14; st++) {
        const short* Aptr = (st < 7) ? (const short*)xc : (const short*)h;
        int kl = (st < 7 ? st : st - 7) * 32;
        #pragma unroll
        for (int p = 0; p < 4; p++) {
            int r = sRow + p * 64;
            int gr = rowBase + r;
            short8 v = {};
            if (gr < V_N) v = *(const short8*)(Aptr + (long)gr * LDA + kl + sChunk);
            *(short8*)&As[r * 32 + sChunk] = v;
        }
        {
            const short* bs = WpB + st * 3072;
            *(short8*)&Bs[tid * 8] = *(const short8*)(bs + tid * 8);
            if (tid < 128)
                *(short8*)&Bs[(tid + 256) * 8] = *(const short8*)(bs + (tid + 256) * 8);
        }
        __syncthreads();
        short8 br[2], bz[2], bn[2];
        #pragma unroll
        for (int nt = 0; nt < 2; nt++) {
            br[nt] = *(short8*)&Bs[(0 * 32 + nt * 16 + lm) * 32 + quad * 8];
            bz[nt] = *(short8*)&Bs[(1 * 32 + nt * 16 + lm) * 32 + quad * 8];
            bn[nt] = *(short8*)&Bs[(2 * 32 + nt * 16 + lm) * 32 + quad * 8];
        }
        #pragma unroll
        for (int rt = 0; rt < 4; rt++) {
            short8 a = *(short8*)&As[(w * 64 + rt * 16 + lm) * 32 + quad * 8];
            #pragma unroll
            for (int nt = 0; nt < 2; nt++) {
                aR[rt][nt] = MFMA16(a, br[nt], aR[rt][nt]);
                aZ[rt][nt] = MFMA16(a, bz[nt], aZ[rt][nt]);
                if (st < 7) aNl[rt][nt] = MFMA16(a, bn[nt], aNl[rt][nt]);
                else        aNh[rt][nt] = MFMA16(a, bn[nt], aNh[rt][nt]);
            }
        }
        __syncthreads();
    }

    #pragma unroll
    for (int nt = 0; nt < 2; nt++) {
        int col = j0 + nt * 16 + lm;
        if (col >= G_DIM) continue;
        float b_ir = bih[col], b_iz = bih[G_DIM + col], b_in = bih[2 * G_DIM + col];
        float b_hr = bhh[col], b_hz = bhh[G_DIM + col], b_hn = bhh[2 * G_DIM + col];
        #pragma unroll
        for (int rt = 0; rt < 4; rt++) {
            #pragma unroll
            for (int r = 0; r < 4; r++) {
                int grow = rowBase + w * 64 + rt * 16 + quad * 4 + r;
                if (grow >= V_N) continue;
                float sr = aR[rt][nt][r] + b_ir + b_hr;
                float sz = aZ[rt][nt][r] + b_iz + b_hz;
                float gin = aNl[rt][nt][r] + b_in;
                float ghn = aNh[rt][nt][r] + b_hn;
                float rr = sigmoid_f(sr);
                float zz = sigmoid_f(sz);
                float nn = tanhf(gin + rr * ghn);
                float hval = bf2f(h[(long)grow * LDA + col]);
                float o = (1.f - zz) * nn + zz * hval;
                out[(long)grow * LDA + col] = __float2bfloat16(o > 0.f ? o : 0.f);
            }
        }
    }
}

// ---------------------------------------------------------------------------
// Ctx edge logits (he1 on the fly): wave per edge, 4 edges/block.
// ---------------------------------------------------------------------------
__global__ __launch_bounds__(256)
void ctx_edge_logits_kernel(const __hip_bfloat16* __restrict__ P,
                            const __hip_bfloat16* __restrict__ hv,
                            const float* __restrict__ efeat,
                            const int* __restrict__ src, const int* __restrict__ dst,
                            const float* __restrict__ pe1W,
                            const float* __restrict__ pe2W, const float* __restrict__ pe2b,
                            float* __restrict__ logits)
{
    __shared__ float Wef[NEFEAT * G_DIM];
    __shared__ float w1s[G_DIM], w2s[G_DIM];
    const int tid = threadIdx.x;
    for (int i = tid; i < NEFEAT * G_DIM; i += 256) {
        int j = i / G_DIM, k = i % G_DIM;
        Wef[i] = pe1W[(long)(NFEAT + j) * G_DIM + k];
    }
    for (int i = tid; i < G_DIM; i += 256) { w1s[i] = pe2W[i]; w2s[i] = pe2W[G_DIM + i]; }
    __syncthreads();
    const int w = tid >> 6, lane = tid & 63;
    int e = blockIdx.x * 4 + w;
    if (e >= E_N) return;
    int s = src[e], d = dst[e];
    float efj = (lane < NEFEAT) ? efeat[(long)e * NEFEAT + lane] : 0.f;
    float ef[NEFEAT];
    #pragma unroll
    for (int j = 0; j < NEFEAT; j++) ef[j] = __shfl(efj, j, 64);
    float acc = 0.f;
    #pragma unroll
    for (int c = 0; c < 4; c++) {
        int k = c * 64 + lane;
        if (k < G_DIM) {
            float q = 0.f;
            #pragma unroll
            for (int j = 0; j < NEFEAT; j++) q += ef[j] * Wef[j * G_DIM + k];
            float he1k = lrelu_f(bf2f(P[(long)s * LDA + k]) + q);
            acc += he1k * w2s[k] + bf2f(hv[(long)d * LDA + k]) * w1s[k];
        }
    }
    for (int off = 32; off > 0; off >>= 1) acc += __shfl_down(acc, off, 64);
    if (lane == 0) logits[e] = lrelu_f(acc + pe2b[0]);
}

// ---------------------------------------------------------------------------
// Ctx aggregation: hbar[v] = sum aw[e]*he1[e] (on the fly), wave per node
// ---------------------------------------------------------------------------
__global__ __launch_bounds__(256)
void ctx_agg_kernel(const __hip_bfloat16* __restrict__ P,
                    const float* __restrict__ efeat,
                    const int* __restrict__ src,
                    const int* __restrict__ rp, const int* __restrict__ perm,
                    const float* __restrict__ aw,
                    const float* __restrict__ pe1W,
                    __hip_bfloat16* __restrict__ hbar)
{
    __shared__ float Wef[NEFEAT * G_DIM];
    const int tid = threadIdx.x;
    for (int i = tid; i < NEFEAT * G_DIM; i += 256) {
        int j = i / G_DIM, k = i % G_DIM;
        Wef[i] = pe1W[(long)(NFEAT + j) * G_DIM + k];
    }
    __syncthreads();
    const int w = tid >> 6, lane = tid & 63;
    int v = blockIdx.x * 4 + w;
    if (v >= V_N) return;
    float a[4] = {};
    int b = rp[v], en = rp[v + 1];
    for (int i = b; i < en; i++) {
        int e = perm[i];
        float we = aw[e];
        int s = src[e];
        float efj = (lane < NEFEAT) ? efeat[(long)e * NEFEAT + lane] : 0.f;
        float ef[NEFEAT];
        #pragma unroll
        for (int j = 0; j < NEFEAT; j++) ef[j] = __shfl(efj, j, 64);
        #pragma unroll
        for (int c = 0; c < 4; c++) {
            int k = c * 64 + lane;
            if (k < G_DIM) {
                float q = 0.f;
                #pragma unroll
                for (int j = 0; j < NEFEAT; j++) q += ef[j] * Wef[j * G_DIM + k];
                a[c] += we * lrelu_f(bf2f(P[(long)s * LDA + k]) + q);
            }
        }
    }
    #pragma unroll
    for (int c = 0; c < 4; c++) {
        int k = c * 64 + lane;
        if (k < G_DIM) hbar[(long)v * LDA + k] = __float2bfloat16(a[c]);
    }
}

// ---------------------------------------------------------------------------
// GNN edge logits: wave per edge
// ---------------------------------------------------------------------------
__global__ __launch_bounds__(256)
void gnn_edge_logits_kernel(const __hip_bfloat16* __restrict__ nf,
                            const int* __restrict__ src, const int* __restrict__ dst,
                            const float* __restrict__ w, const float* __restrict__ b,
                            float* __restrict__ out)
{
    int gtid = blockIdx.x * blockDim.x + threadIdx.x;
    int e = gtid >> 6, lane = gtid & 63;
    if (e >= E_N) return;
    int d = dst[e], s = src[e];
    float acc = 0.f;
    for (int k = lane; k < G_DIM; k += 64) {
        acc += bf2f(nf[(long)d * LDA + k]) * w[k];
        acc += bf2f(nf[(long)s * LDA + k]) * w[G_DIM + k];
    }
    for (int off = 32; off > 0; off >>= 1) acc += __shfl_down(acc, off, 64);
    if (lane == 0) out[e] = lrelu_f(acc + b[0]);
}

// ---------------------------------------------------------------------------
// CSR softmax (thread per node)
// ---------------------------------------------------------------------------
__global__ __launch_bounds__(256)
void softmax_csr_kernel(const float* __restrict__ logits, const int* __restrict__ rp,
                        const int* __restrict__ perm, float* __restrict__ aw)
{
    int v = blockIdx.x * blockDim.x + threadIdx.x;
    if (v >= V_N) return;
    int b = rp[v], en = rp[v + 1];
    if (en == b) return;
    float m = -INFINITY;
    for (int i = b; i < en; i++) m = fmaxf(m, logits[perm[i]]);
    float s = 0.f;
    for (int i = b; i < en; i++) s += expf(logits[perm[i]] - m);
    float inv = 1.f / s;
    for (int i = b; i < en; i++) {
        int e = perm[i];
        aw[e] = expf(logits[e] - m) * inv;
    }
}

// ---------------------------------------------------------------------------
// GNN aggregate: c[v] = elu(sum aw[e]*hvp[src[e]]), wave per node
// ---------------------------------------------------------------------------
__global__ __launch_bounds__(256)
void gnn_agg_kernel(const __hip_bfloat16* __restrict__ X, const int* __restrict__ src,
                    const int* __restrict__ rp, const int* __restrict__ perm,
                    const float* __restrict__ aw, __hip_bfloat16* __restrict__ out)
{
    int w = threadIdx.x >> 6, lane = threadIdx.x & 63;
    int v = blockIdx.x * 4 + w;
    if (v >= V_N) return;
    float a[4] = {};
    int b = rp[v], en = rp[v + 1];
    for (int i = b; i < en; i++) {
        int e = perm[i];
        float we = aw[e];
        long basep = (long)src[e] * LDA;
        a[0] += we * bf2f(X[basep + lane]);
        a[1] += we * bf2f(X[basep + 64 + lane]);
        a[2] += we * bf2f(X[basep + 128 + lane]);
        if (lane < 8) a[3] += we * bf2f(X[basep + 192 + lane]);
    }
    out[(long)v * LDA + lane] = __float2bfloat16(elu_f(a[0]));
    out[(long)v * LDA + 64 + lane] = __float2bfloat16(elu_f(a[1]));
    out[(long)v * LDA + 128 + lane] = __float2bfloat16(elu_f(a[2]));
    if (lane < 8) out[(long)v * LDA + 192 + lane] = __float2bfloat16(elu_f(a[3]));
}

// ---------------------------------------------------------------------------
// readout
// ---------------------------------------------------------------------------
__global__ __launch_bounds__(256)
void mask_kernel(const float* __restrict__ nfeat, float* __restrict__ mask)
{
    int v = blockIdx.x * blockDim.x + threadIdx.x;
    if (v >= V_N) return;
    const float* row = nfeat + (long)v * NFEAT;
    float s = row[NFEAT - 4] + row[NFEAT - 3] + row[NFEAT - 2] + row[NFEAT - 1];
    float m = s * (1.f - row[0]);
    mask[v] = 1.f / m - 1.f;
}

__global__ __launch_bounds__(256)
void readout_kernel(const __hip_bfloat16* __restrict__ nf, const float* __restrict__ predW,
                    const float* __restrict__ predb, const float* __restrict__ mask,
                    const int* __restrict__ gid, float* __restrict__ out_atom,
                    float* __restrict__ gsum)
{
    int gtid = blockIdx.x * blockDim.x + threadIdx.x;
    int v = gtid >> 6, lane = gtid & 63;
    if (v >= V_N) return;
    float acc = 0.f;
    for (int k = lane; k < G_DIM; k += 64)
        acc += bf2f(nf[(long)v * LDA + k]) * predW[k];
    for (int off = 32; off > 0; off >>= 1) acc += __shfl_down(acc, off, 64);
    if (lane == 0) {
        float p = acc + predb[0] + mask[v];
        out_atom[v] = p;
        atomicAdd(&gsum[gid[v]], exp10f(-p));
    }
}

__global__ __launch_bounds__(256)
void graph_out_kernel(const float* __restrict__ gsum, float* __restrict__ out_g)
{
    int g = blockIdx.x * blockDim.x + threadIdx.x;
    if (g >= NG_N) return;
    out_g[g] = -log10f(gsum[g]);
}

// ---------------------------------------------------------------------------
extern "C" void kernel_launch(void* const* d_in, const int* in_sizes, int n_in,
                              void* d_out, int out_size, void* d_ws, size_t ws_size,
                              hipStream_t stream)
{
    const float* node_feats = (const float*)d_in[0];
    const float* edge_feats = (const float*)d_in[1];
    const float* pn_W  = (const float*)d_in[2];
    const float* pn_b  = (const float*)d_in[3];
    const float* pe1_W = (const float*)d_in[4];
    const float* pe1_b = (const float*)d_in[5];
    const float* pe2_W = (const float*)d_in[6];
    const float* pe2_b = (const float*)d_in[7];
    const float* et_W  = (const float*)d_in[8];
    const float* et_b  = (const float*)d_in[9];
    const float* gru0_Wih = (const float*)d_in[10];
    const float* gru0_Whh = (const float*)d_in[11];
    const float* gru0_bih = (const float*)d_in[12];
    const float* gru0_bhh = (const float*)d_in[13];
    const float* gnn_pe_W = (const float*)d_in[14];
    const float* gnn_pe_b = (const float*)d_in[15];
    const float* gnn_pn_W = (const float*)d_in[16];
    const float* gnn_pn_b = (const float*)d_in[17];
    const float* gnn_gru_Wih = (const float*)d_in[18];
    const float* gnn_gru_Whh = (const float*)d_in[19];
    const float* gnn_gru_bih = (const float*)d_in[20];
    const float* gnn_gru_bhh = (const float*)d_in[21];
    const float* pred_W = (const float*)d_in[22];
    const float* pred_b = (const float*)d_in[23];
    const int* src = (const int*)d_in[24];
    const int* dst = (const int*)d_in[25];
    const int* gid = (const int*)d_in[26];

    float* out_g = (float*)d_out;
    float* out_atom = out_g + NG_N;

    char* base = (char*)d_ws;
    size_t off = 0;
    auto take = [&](size_t bytes) -> void* {
        void* p = base + off;
        off += (bytes + 255) & ~(size_t)255;
        return p;
    };
    const size_t VP = (size_t)V_N * LDA;       // padded node-matrix elems
    const size_t WPL = (size_t)7 * 14 * 3072;  // per-layer GRU Wp elems
    float* mask   = (float*)take((size_t)V_N * 4);
    float* logits = (float*)take((size_t)E_N * 4);
    float* aw     = (float*)take((size_t)E_N * 4);
    float* gsum   = (float*)take((size_t)NG_N * 4);
    // 4 contiguous padded bf16 node matrices (zero-filled as one region)
    __hip_bfloat16* c    = (__hip_bfloat16*)take(VP * 2);
    __hip_bfloat16* hv   = (__hip_bfloat16*)take(VP * 2);
    __hip_bfloat16* nf_a = (__hip_bfloat16*)take(VP * 2);
    __hip_bfloat16* nf_b = (__hip_bfloat16*)take(VP * 2);
    short* WpGru = (short*)take(3 * WPL * 2);
    short* Wp_pn0 = (short*)take((size_t)256 * 96 * 2);
    short* Wp_pe1 = (short*)take((size_t)256 * 96 * 2);
    short* Wp_et  = (short*)take((size_t)7 * 7 * 1024 * 2);
    short* Wp_pn1 = (short*)take((size_t)7 * 7 * 1024 * 2);
    short* Wp_pn2 = (short*)take((size_t)7 * 7 * 1024 * 2);
    int* deg  = (int*)take((size_t)V_N * 4);
    int* cnt  = (int*)take((size_t)V_N * 4);
    int* rp   = (int*)take((size_t)(V_N + 1) * 4);
    int* perm = (int*)take((size_t)E_N * 4);
    int* bsum = (int*)take((size_t)512 * 4);
    __hip_bfloat16* P    = nf_a;  // alias: nf_a written only at GRU0
    __hip_bfloat16* hbar = nf_b;  // alias: nf_b first written as layer-0 GRU output
    __hip_bfloat16* hvp  = hv;    // alias: hv dead after GRU0

    if (off > ws_size) {
        fill_kernel<<<cdiv(out_size, 256), 256, 0, stream>>>((float*)d_out, -12345.f, out_size);
        return;
    }

    const int BLK = 256;
    const int nScanBlocks = cdiv(V_N, 256);
    const dim3 gOld(4, cdiv(V_N, 64));
    const dim3 gNew(7, cdiv(V_N, 256));
    const int gEdge4 = cdiv(E_N, 4);
    const int gAgg = cdiv(V_N, 4);

    // zero-fill the 4 padded node matrices (pads must be 0 for GEMM/GRU K-loops)
    {
        int nFloats = (int)(4 * VP * 2 / 4);
        fill_kernel<<<cdiv(nFloats, BLK), BLK, 0, stream>>>((float*)c, 0.f, nFloats);
    }

    // ---- weight prep ----
    gru_wprep_kernel<<<cdiv(7 * 14 * 3072, 256), BLK, 0, stream>>>(gru0_Wih, gru0_Whh, WpGru);
    for (int l = 0; l < L_N; l++)
        gru_wprep_kernel<<<cdiv(7 * 14 * 3072, 256), BLK, 0, stream>>>(
            gnn_gru_Wih + (size_t)l * G_DIM * 3 * G_DIM,
            gnn_gru_Whh + (size_t)l * G_DIM * 3 * G_DIM,
            WpGru + (size_t)(l + 1) * WPL);
    wprep_kernel<<<cdiv(256 * 96, 256), BLK, 0, stream>>>(pn_W, Wp_pn0, NFEAT, 96);
    wprep_kernel<<<cdiv(256 * 96, 256), BLK, 0, stream>>>(pe1_W, Wp_pe1, NFEAT, 96);
    wprep_tiled_kernel<<<cdiv(7 * 7 * 1024, 256), BLK, 0, stream>>>(et_W, Wp_et);
    wprep_tiled_kernel<<<cdiv(7 * 7 * 1024, 256), BLK, 0, stream>>>(gnn_pn_W, Wp_pn1);
    wprep_tiled_kernel<<<cdiv(7 * 7 * 1024, 256), BLK, 0, stream>>>(
        gnn_pn_W + (size_t)G_DIM * G_DIM, Wp_pn2);

    mask_kernel<<<cdiv(V_N, BLK), BLK, 0, stream>>>(node_feats, mask);

    // ---- CSR build (by dst) ----
    fill_int_kernel<<<cdiv(V_N, BLK), BLK, 0, stream>>>(deg, 0, V_N);
    hist_kernel<<<cdiv(E_N, BLK), BLK, 0, stream>>>(dst, deg);
    scan1_kernel<<<nScanBlocks, BLK, 0, stream>>>(deg, rp, bsum);
    scan2_kernel<<<1, 1, 0, stream>>>(bsum, rp, nScanBlocks);
    scan3_kernel<<<nScanBlocks, BLK, 0, stream>>>(rp, bsum);
    fill_int_kernel<<<cdiv(V_N, BLK), BLK, 0, stream>>>(cnt, 0, V_N);
    csr_fill_kernel<<<cdiv(E_N, BLK), BLK, 0, stream>>>(dst, rp, cnt, perm);

    // ---- GetContext ----
    gemm_f32a_kernel<0><<<gOld, BLK, 0, stream>>>(node_feats, Wp_pn0, pn_b, hv);
    gemm_f32a_kernel<1><<<gOld, BLK, 0, stream>>>(node_feats, Wp_pe1, pe1_b, P);
    ctx_edge_logits_kernel<<<gEdge4, BLK, 0, stream>>>(
        P, hv, edge_feats, src, dst, pe1_W, pe2_W, pe2_b, logits);
    softmax_csr_kernel<<<cdiv(V_N, BLK), BLK, 0, stream>>>(logits, rp, perm, aw);
    ctx_agg_kernel<<<gAgg, BLK, 0, stream>>>(P, edge_feats, src, rp, perm, aw, pe1_W, hbar);
    gemm_bf16a_kernel<3><<<gNew, BLK, 0, stream>>>(hbar, Wp_et, et_b, c);
    gru_mfma_kernel<<<gNew, BLK, 0, stream>>>(c, hv, WpGru, gru0_bih, gru0_bhh, nf_a);

    // ---- GNN layers ----
    __hip_bfloat16* cur = nf_a;
    __hip_bfloat16* nxt = nf_b;
    for (int l = 0; l < L_N; l++) {
        const float* pe_W = gnn_pe_W + (size_t)l * 2 * G_DIM;
        const float* pe_b = gnn_pe_b + l;
        const float* pnB  = gnn_pn_b + (size_t)l * G_DIM;
        const float* bih  = gnn_gru_bih + (size_t)l * 3 * G_DIM;
        const float* bhh  = gnn_gru_bhh + (size_t)l * 3 * G_DIM;
        const short* WpPn = (l == 0) ? Wp_pn1 : Wp_pn2;

        gnn_edge_logits_kernel<<<cdiv(E_N * 64, BLK), BLK, 0, stream>>>(
            cur, src, dst, pe_W, pe_b, logits);
        softmax_csr_kernel<<<cdiv(V_N, BLK), BLK, 0, stream>>>(logits, rp, perm, aw);

        gemm_bf16a_kernel<1><<<gNew, BLK, 0, stream>>>(cur, WpPn, pnB, hvp);
        gnn_agg_kernel<<<gAgg, BLK, 0, stream>>>(hvp, src, rp, perm, aw, c);
        gru_mfma_kernel<<<gNew, BLK, 0, stream>>>(
            c, cur, WpGru + (size_t)(l + 1) * WPL, bih, bhh, nxt);

        __hip_bfloat16* tmp = cur; cur = nxt; nxt = tmp;
    }

    // ---- readout ----
    fill_kernel<<<cdiv(NG_N, BLK), BLK, 0, stream>>>(gsum, 0.f, NG_N);
    readout_kernel<<<cdiv(V_N * 64, BLK), BLK, 0, stream>>>(
        cur, pred_W, pred_b, mask, gid, out_atom, gsum);
    graph_out_kernel<<<cdiv(NG_N, BLK), BLK, 0, stream>>>(gsum, out_g);
}

// Round 7
// 2404.486 us; speedup vs baseline: 8.0637x; 1.0928x over previous
//
#include <hip/hip_runtime.h>
#include <hip/hip_bf16.h>
#include <math.h>

#define V_N    100000
#define E_N    400000
#define NFEAT  74
#define NEFEAT 12
#define G_DIM  200
#define LDA    224          // padded leading dim for all bf16 node matrices
#define L_N    2
#define NG_N   4000

static inline int cdiv(int a, int b) { return (a + b - 1) / b; }

__device__ __forceinline__ float lrelu_f(float x) { return x > 0.f ? x : 0.01f * x; }
__device__ __forceinline__ float sigmoid_f(float x) { return 1.f / (1.f + expf(-x)); }
__device__ __forceinline__ float elu_f(float x) { return x > 0.f ? x : expm1f(x); }
__device__ __forceinline__ float bf2f(__hip_bfloat16 x) { return __bfloat162float(x); }

__device__ __forceinline__ short f2bf(float f) {
    __hip_bfloat16 b = __float2bfloat16(f);
    short s;
    __builtin_memcpy(&s, &b, 2);
    return s;
}

typedef short short8 __attribute__((ext_vector_type(8)));
typedef float f32x4 __attribute__((ext_vector_type(4)));

#define MFMA16(a, b, c) __builtin_amdgcn_mfma_f32_16x16x32_bf16((a), (b), (c), 0, 0, 0)

// ---------------------------------------------------------------------------
__global__ __launch_bounds__(256)
void fill_kernel(float* __restrict__ p, float v, int n)
{
    int i = blockIdx.x * blockDim.x + threadIdx.x;
    if (i < n) p[i] = v;
}

__global__ __launch_bounds__(256)
void fill_int_kernel(int* __restrict__ p, int v, int n)
{
    int i = blockIdx.x * blockDim.x + threadIdx.x;
    if (i < n) p[i] = v;
}

// ---------------------------------------------------------------------------
// Weight preps
// ---------------------------------------------------------------------------
__global__ __launch_bounds__(256)
void wprep_kernel(const float* __restrict__ W, short* __restrict__ Wp, int K, int Kpad)
{
    int idx = blockIdx.x * 256 + threadIdx.x;
    if (idx >= 256 * Kpad) return;
    int j = idx / Kpad, k = idx % Kpad;
    float v = (j < G_DIM && k < K) ? W[(long)k * G_DIM + j] : 0.f;
    Wp[idx] = f2bf(v);
}

// Tiled for K=224 GEMM: Wp[cb<7][st<7][cc<32][kk<32]
__global__ __launch_bounds__(256)
void wprep_tiled_kernel(const float* __restrict__ W, short* __restrict__ Wp)
{
    int idx = blockIdx.x * 256 + threadIdx.x;
    if (idx >= 7 * 7 * 1024) return;
    int cb = idx / (7 * 1024);
    int r = idx % (7 * 1024);
    int st = r / 1024;
    int r2 = r % 1024;
    int cc = r2 / 32, kk = r2 % 32;
    int col = cb * 32 + cc, k = st * 32 + kk;
    float v = (col < G_DIM && k < G_DIM) ? W[(long)k * G_DIM + col] : 0.f;
    Wp[idx] = f2bf(v);
}

// GRU tiled: Wp[cb<7][st<14][g<3][cc<32][kk<32]; st<7 -> Wih, st>=7 -> Whh
__global__ __launch_bounds__(256)
void gru_wprep_kernel(const float* __restrict__ Wih, const float* __restrict__ Whh,
                      short* __restrict__ Wp)
{
    int idx = blockIdx.x * 256 + threadIdx.x;
    if (idx >= 7 * 14 * 3072) return;
    int cb = idx / (14 * 3072);
    int r = idx % (14 * 3072);
    int st = r / 3072;
    int r2 = r % 3072;
    int g = r2 / 1024;
    int r3 = r2 % 1024;
    int cc = r3 / 32, kk = r3 % 32;
    int col = cb * 32 + cc;
    float v = 0.f;
    if (col < G_DIM) {
        if (st < 7) {
            int k = st * 32 + kk;
            if (k < G_DIM) v = Wih[(long)k * (3 * G_DIM) + g * G_DIM + col];
        } else {
            int k = (st - 7) * 32 + kk;
            if (k < G_DIM) v = Whh[(long)k * (3 * G_DIM) + g * G_DIM + col];
        }
    }
    Wp[idx] = f2bf(v);
}

// ---------------------------------------------------------------------------
// CSR build
// ---------------------------------------------------------------------------
__global__ __launch_bounds__(256)
void hist_kernel(const int* __restrict__ dst, int* __restrict__ deg)
{
    int e = blockIdx.x * blockDim.x + threadIdx.x;
    if (e >= E_N) return;
    atomicAdd(&deg[dst[e]], 1);
}

__global__ __launch_bounds__(256)
void scan1_kernel(const int* __restrict__ deg, int* __restrict__ rp, int* __restrict__ bsum)
{
    __shared__ int s[256];
    int tid = threadIdx.x;
    int v = blockIdx.x * 256 + tid;
    int x = (v < V_N) ? deg[v] : 0;
    s[tid] = x;
    __syncthreads();
    for (int off = 1; off < 256; off <<= 1) {
        int t = (tid >= off) ? s[tid - off] : 0;
        __syncthreads();
        s[tid] += t;
        __syncthreads();
    }
    if (v < V_N) rp[v] = s[tid] - x;
    if (tid == 255) bsum[blockIdx.x] = s[255];
}

__global__ void scan2_kernel(int* __restrict__ bsum, int* __restrict__ rp, int nb)
{
    if (threadIdx.x != 0 || blockIdx.x != 0) return;
    int acc = 0;
    for (int b = 0; b < nb; b++) { int t = bsum[b]; bsum[b] = acc; acc += t; }
    rp[V_N] = acc;
}

__global__ __launch_bounds__(256)
void scan3_kernel(int* __restrict__ rp, const int* __restrict__ bsum)
{
    int v = blockIdx.x * 256 + threadIdx.x;
    if (v < V_N) rp[v] += bsum[v >> 8];
}

__global__ __launch_bounds__(256)
void csr_fill_kernel(const int* __restrict__ dst, const int* __restrict__ rp,
                     int* __restrict__ cnt, int* __restrict__ perm)
{
    int e = blockIdx.x * blockDim.x + threadIdx.x;
    if (e >= E_N) return;
    int d = dst[e];
    int pos = rp[d] + atomicAdd(&cnt[d], 1);
    perm[pos] = e;
}

// ---------------------------------------------------------------------------
// 64x64 MFMA GEMM for fp32-A (K=74 pad 96): hv, P
// ---------------------------------------------------------------------------
template<int EPI>   // 0 = lrelu, 1 = bias only
__global__ __launch_bounds__(256)
void gemm_f32a_kernel(const float* __restrict__ Af32,
                      const short* __restrict__ Wp,
                      const float* __restrict__ bias,
                      __hip_bfloat16* __restrict__ Cbf)
{
    __shared__ short As[64 * 40];
    __shared__ short Bs[64 * 40];
    const int tid = threadIdx.x;
    const int lane = tid & 63;
    const int w = tid >> 6;
    const int quad = lane >> 4;
    const int lm = lane & 15;
    const int rowBase = blockIdx.y * 64;
    const int j0 = blockIdx.x * 64;
    const int arow = tid >> 2;
    const int akc = (tid & 3) * 8;
    const int agrow = rowBase + arow;

    f32x4 acc[4] = {};

    for (int k0 = 0; k0 < 96; k0 += 32) {
        short8 av = {};
        if (agrow < V_N) {
            int gk = k0 + akc;
            #pragma unroll
            for (int i = 0; i < 8; i++) {
                int kg = gk + i;
                av[i] = (kg < NFEAT) ? f2bf(Af32[(long)agrow * NFEAT + kg]) : (short)0;
            }
        }
        *(short8*)&As[arow * 40 + akc] = av;
        {
            int col = tid >> 2;
            *(short8*)&Bs[col * 40 + akc] =
                *(const short8*)(Wp + (long)(j0 + col) * 96 + k0 + akc);
        }
        __syncthreads();
        short8 a = *(short8*)&As[(w * 16 + lm) * 40 + quad * 8];
        #pragma unroll
        for (int nt = 0; nt < 4; nt++) {
            short8 b = *(short8*)&Bs[(nt * 16 + lm) * 40 + quad * 8];
            acc[nt] = MFMA16(a, b, acc[nt]);
        }
        __syncthreads();
    }

    #pragma unroll
    for (int nt = 0; nt < 4; nt++) {
        int col = j0 + nt * 16 + lm;
        if (col >= G_DIM) continue;
        float bv = bias[col];
        #pragma unroll
        for (int r = 0; r < 4; r++) {
            int grow = rowBase + w * 16 + quad * 4 + r;
            if (grow >= V_N) continue;
            float v = acc[nt][r] + bv;
            if (EPI == 0) v = lrelu_f(v);
            Cbf[(long)grow * LDA + col] = __float2bfloat16(v);
        }
    }
}

// ---------------------------------------------------------------------------
// 256x32 MFMA GEMM, bf16 A [V][LDA], K=224, Wp tiled [7][7][32][32]
// ---------------------------------------------------------------------------
template<int EPI>   // 1 = bias only, 3 = elu
__global__ __launch_bounds__(256)
void gemm_bf16a_kernel(const __hip_bfloat16* __restrict__ Abf,
                       const short* __restrict__ Wp,
                       const float* __restrict__ bias,
                       __hip_bfloat16* __restrict__ Cbf)
{
    __shared__ short As[256 * 32];
    __shared__ short Bs[32 * 32];
    const int tid = threadIdx.x;
    const int lane = tid & 63;
    const int w = tid >> 6;
    const int quad = lane >> 4;
    const int lm = lane & 15;
    const int cb = blockIdx.x;
    const int j0 = cb * 32;
    const int rowBase = blockIdx.y * 256;
    const int sRow = tid >> 2;
    const int sChunk = (tid & 3) * 8;

    const short* WpB = Wp + (long)cb * (7 * 1024);
    f32x4 acc[4][2] = {};

    #pragma unroll 1
    for (int st = 0; st < 7; st++) {
        int kl = st * 32;
        #pragma unroll
        for (int p = 0; p < 4; p++) {
            int r = sRow + p * 64;
            int gr = rowBase + r;
            short8 v = {};
            if (gr < V_N) v = *(const short8*)((const short*)Abf + (long)gr * LDA + kl + sChunk);
            *(short8*)&As[r * 32 + sChunk] = v;
        }
        if (tid < 128)
            *(short8*)&Bs[tid * 8] = *(const short8*)(WpB + st * 1024 + tid * 8);
        __syncthreads();
        short8 b0 = *(short8*)&Bs[(0 * 16 + lm) * 32 + quad * 8];
        short8 b1 = *(short8*)&Bs[(1 * 16 + lm) * 32 + quad * 8];
        #pragma unroll
        for (int rt = 0; rt < 4; rt++) {
            short8 a = *(short8*)&As[(w * 64 + rt * 16 + lm) * 32 + quad * 8];
            acc[rt][0] = MFMA16(a, b0, acc[rt][0]);
            acc[rt][1] = MFMA16(a, b1, acc[rt][1]);
        }
        __syncthreads();
    }

    #pragma unroll
    for (int nt = 0; nt < 2; nt++) {
        int col = j0 + nt * 16 + lm;
        if (col >= G_DIM) continue;
        float bv = bias[col];
        #pragma unroll
        for (int rt = 0; rt < 4; rt++) {
            #pragma unroll
            for (int r = 0; r < 4; r++) {
                int grow = rowBase + w * 64 + rt * 16 + quad * 4 + r;
                if (grow >= V_N) continue;
                float v = acc[rt][nt][r] + bv;
                if (EPI == 3) v = elu_f(v);
                Cbf[(long)grow * LDA + col] = __float2bfloat16(v);
            }
        }
    }
}

// ---------------------------------------------------------------------------
// Fused MFMA GRU: out = relu(gru_cell(xc, h))
// ---------------------------------------------------------------------------
__global__ __launch_bounds__(256)
void gru_mfma_kernel(const __hip_bfloat16* __restrict__ xc,
                     const __hip_bfloat16* __restrict__ h,
                     const short* __restrict__ Wp,
                     const float* __restrict__ bih, const float* __restrict__ bhh,
                     __hip_bfloat16* __restrict__ out)
{
    __shared__ short As[256 * 32];
    __shared__ short Bs[3 * 32 * 32];
    const int tid = threadIdx.x;
    const int lane = tid & 63;
    const int w = tid >> 6;
    const int quad = lane >> 4;
    const int lm = lane & 15;
    const int cb = blockIdx.x;
    const int j0 = cb * 32;
    const int rowBase = blockIdx.y * 256;
    const int sRow = tid >> 2;
    const int sChunk = (tid & 3) * 8;

    const short* WpB = Wp + (long)cb * (14 * 3072);

    f32x4 aR[4][2] = {}, aZ[4][2] = {}, aNl[4][2] = {}, aNh[4][2] = {};

    #pragma unroll 1
    for (int st = 0; st < 14; st++) {
        const short* Aptr = (st < 7) ? (const short*)xc : (const short*)h;
        int kl = (st < 7 ? st : st - 7) * 32;
        #pragma unroll
        for (int p = 0; p < 4; p++) {
            int r = sRow + p * 64;
            int gr = rowBase + r;
            short8 v = {};
            if (gr < V_N) v = *(const short8*)(Aptr + (long)gr * LDA + kl + sChunk);
            *(short8*)&As[r * 32 + sChunk] = v;
        }
        {
            const short* bs = WpB + st * 3072;
            *(short8*)&Bs[tid * 8] = *(const short8*)(bs + tid * 8);
            if (tid < 128)
                *(short8*)&Bs[(tid + 256) * 8] = *(const short8*)(bs + (tid + 256) * 8);
        }
        __syncthreads();
        short8 br[2], bz[2], bn[2];
        #pragma unroll
        for (int nt = 0; nt < 2; nt++) {
            br[nt] = *(short8*)&Bs[(0 * 32 + nt * 16 + lm) * 32 + quad * 8];
            bz[nt] = *(short8*)&Bs[(1 * 32 + nt * 16 + lm) * 32 + quad * 8];
            bn[nt] = *(short8*)&Bs[(2 * 32 + nt * 16 + lm) * 32 + quad * 8];
        }
        #pragma unroll
        for (int rt = 0; rt < 4; rt++) {
            short8 a = *(short8*)&As[(w * 64 + rt * 16 + lm) * 32 + quad * 8];
            #pragma unroll
            for (int nt = 0; nt < 2; nt++) {
                aR[rt][nt] = MFMA16(a, br[nt], aR[rt][nt]);
                aZ[rt][nt] = MFMA16(a, bz[nt], aZ[rt][nt]);
                if (st < 7) aNl[rt][nt] = MFMA16(a, bn[nt], aNl[rt][nt]);
                else        aNh[rt][nt] = MFMA16(a, bn[nt], aNh[rt][nt]);
            }
        }
        __syncthreads();
    }

    #pragma unroll
    for (int nt = 0; nt < 2; nt++) {
        int col = j0 + nt * 16 + lm;
        if (col >= G_DIM) continue;
        float b_ir = bih[col], b_iz = bih[G_DIM + col], b_in = bih[2 * G_DIM + col];
        float b_hr = bhh[col], b_hz = bhh[G_DIM + col], b_hn = bhh[2 * G_DIM + col];
        #pragma unroll
        for (int rt = 0; rt < 4; rt++) {
            #pragma unroll
            for (int r = 0; r < 4; r++) {
                int grow = rowBase + w * 64 + rt * 16 + quad * 4 + r;
                if (grow >= V_N) continue;
                float sr = aR[rt][nt][r] + b_ir + b_hr;
                float sz = aZ[rt][nt][r] + b_iz + b_hz;
                float gin = aNl[rt][nt][r] + b_in;
                float ghn = aNh[rt][nt][r] + b_hn;
                float rr = sigmoid_f(sr);
                float zz = sigmoid_f(sz);
                float nn = tanhf(gin + rr * ghn);
                float hval = bf2f(h[(long)grow * LDA + col]);
                float o = (1.f - zz) * nn + zz * hval;
                out[(long)grow * LDA + col] = __float2bfloat16(o > 0.f ? o : 0.f);
            }
        }
    }
}

// ---------------------------------------------------------------------------
// Node dot(s): s1[v] = X[v]·wa (+ s2[v] = X[v]·wb if wb). Wave per node.
// ---------------------------------------------------------------------------
__global__ __launch_bounds__(256)
void node_dot2_kernel(const __hip_bfloat16* __restrict__ X,
                      const float* __restrict__ wa, const float* __restrict__ wb,
                      float* __restrict__ s1, float* __restrict__ s2)
{
    int w = threadIdx.x >> 6, lane = threadIdx.x & 63;
    int v = blockIdx.x * 4 + w;
    if (v >= V_N) return;
    const __hip_bfloat16* row = X + (long)v * LDA;
    float a = 0.f, b = 0.f;
    #pragma unroll
    for (int c = 0; c < 4; c++) {
        int k = c * 64 + lane;
        if (k < G_DIM) {
            float x = bf2f(row[k]);
            a += x * wa[k];
            if (wb) b += x * wb[k];
        }
    }
    for (int off = 32; off > 0; off >>= 1) {
        a += __shfl_down(a, off, 64);
        if (wb) b += __shfl_down(b, off, 64);
    }
    if (lane == 0) {
        s1[v] = a;
        if (wb) s2[v] = b;
    }
}

// logits[e] = lrelu( sd[dst[e]] + (ssn ? ssn[src[e]] : sse[e]) + b )
__global__ __launch_bounds__(256)
void edge_combine_kernel(const float* __restrict__ sd, const int* __restrict__ dst,
                         const float* __restrict__ ssn, const int* __restrict__ src,
                         const float* __restrict__ sse,
                         const float* __restrict__ b, float* __restrict__ out)
{
    int e = blockIdx.x * blockDim.x + threadIdx.x;
    if (e >= E_N) return;
    float v = sd[dst[e]] + (ssn ? ssn[src[e]] : sse[e]) + b[0];
    out[e] = lrelu_f(v);
}

// ---------------------------------------------------------------------------
// Ctx he1-dot: hedot[e] = sum_k lrelu(P[src[e]][k] + Q[e][k]) * pe2W[200+k]
// wave handles 2 edges (ILP), 4 waves/block -> 8 edges/block.
// ---------------------------------------------------------------------------
__global__ __launch_bounds__(256)
void ctx_hedot_kernel(const __hip_bfloat16* __restrict__ P,
                      const float* __restrict__ efeat,
                      const int* __restrict__ src,
                      const float* __restrict__ pe1W,
                      const float* __restrict__ pe2W,
                      float* __restrict__ hedot)
{
    __shared__ float Wef[NEFEAT * G_DIM];
    __shared__ float w2s[G_DIM];
    const int tid = threadIdx.x;
    for (int i = tid; i < NEFEAT * G_DIM; i += 256) {
        int j = i / G_DIM, k = i % G_DIM;
        Wef[i] = pe1W[(long)(NFEAT + j) * G_DIM + k];
    }
    for (int i = tid; i < G_DIM; i += 256) w2s[i] = pe2W[G_DIM + i];
    __syncthreads();
    const int w = tid >> 6, lane = tid & 63;
    const int e0 = (blockIdx.x * 4 + w) * 2;
    #pragma unroll
    for (int u = 0; u < 2; u++) {
        int e = e0 + u;
        if (e >= E_N) break;
        int s = src[e];
        float efj = (lane < NEFEAT) ? efeat[(long)e * NEFEAT + lane] : 0.f;
        float ef[NEFEAT];
        #pragma unroll
        for (int j = 0; j < NEFEAT; j++) ef[j] = __shfl(efj, j, 64);
        float acc = 0.f;
        #pragma unroll
        for (int c = 0; c < 4; c++) {
            int k = c * 64 + lane;
            if (k < G_DIM) {
                float q = 0.f;
                #pragma unroll
                for (int j = 0; j < NEFEAT; j++) q += ef[j] * Wef[j * G_DIM + k];
                acc += lrelu_f(bf2f(P[(long)s * LDA + k]) + q) * w2s[k];
            }
        }
        for (int off = 32; off > 0; off >>= 1) acc += __shfl_down(acc, off, 64);
        if (lane == 0) hedot[e] = acc;
    }
}

// ---------------------------------------------------------------------------
// Ctx aggregation: hbar[v] = sum aw[e]*he1[e] (he1 on the fly), wave per node
// ---------------------------------------------------------------------------
__global__ __launch_bounds__(256)
void ctx_agg_kernel(const __hip_bfloat16* __restrict__ P,
                    const float* __restrict__ efeat,
                    const int* __restrict__ src,
                    const int* __restrict__ rp, const int* __restrict__ perm,
                    const float* __restrict__ aw,
                    const float* __restrict__ pe1W,
                    __hip_bfloat16* __restrict__ hbar)
{
    __shared__ float Wef[NEFEAT * G_DIM];
    const int tid = threadIdx.x;
    for (int i = tid; i < NEFEAT * G_DIM; i += 256) {
        int j = i / G_DIM, k = i % G_DIM;
        Wef[i] = pe1W[(long)(NFEAT + j) * G_DIM + k];
    }
    __syncthreads();
    const int w = tid >> 6, lane = tid & 63;
    int v = blockIdx.x * 4 + w;
    if (v >= V_N) return;
    float a[4] = {};
    int b = rp[v], en = rp[v + 1];
    for (int i = b; i < en; i++) {
        int e = perm[i];
        float we = aw[e];
        int s = src[e];
        float efj = (lane < NEFEAT) ? efeat[(long)e * NEFEAT + lane] : 0.f;
        float ef[NEFEAT];
        #pragma unroll
        for (int j = 0; j < NEFEAT; j++) ef[j] = __shfl(efj, j, 64);
        #pragma unroll
        for (int c = 0; c < 4; c++) {
            int k = c * 64 + lane;
            if (k < G_DIM) {
                float q = 0.f;
                #pragma unroll
                for (int j = 0; j < NEFEAT; j++) q += ef[j] * Wef[j * G_DIM + k];
                a[c] += we * lrelu_f(bf2f(P[(long)s * LDA + k]) + q);
            }
        }
    }
    #pragma unroll
    for (int c = 0; c < 4; c++) {
        int k = c * 64 + lane;
        if (k < G_DIM) hbar[(long)v * LDA + k] = __float2bfloat16(a[c]);
    }
}

// ---------------------------------------------------------------------------
// CSR softmax (thread per node)
// ---------------------------------------------------------------------------
__global__ __launch_bounds__(256)
void softmax_csr_kernel(const float* __restrict__ logits, const int* __restrict__ rp,
                        const int* __restrict__ perm, float* __restrict__ aw)
{
    int v = blockIdx.x * blockDim.x + threadIdx.x;
    if (v >= V_N) return;
    int b = rp[v], en = rp[v + 1];
    if (en == b) return;
    float m = -INFINITY;
    for (int i = b; i < en; i++) m = fmaxf(m, logits[perm[i]]);
    float s = 0.f;
    for (int i = b; i < en; i++) s += expf(logits[perm[i]] - m);
    float inv = 1.f / s;
    for (int i = b; i < en; i++) {
        int e = perm[i];
        aw[e] = expf(logits[e] - m) * inv;
    }
}

// ---------------------------------------------------------------------------
// GNN aggregate: c[v] = elu(sum aw[e]*hvp[src[e]]), wave per node
// ---------------------------------------------------------------------------
__global__ __launch_bounds__(256)
void gnn_agg_kernel(const __hip_bfloat16* __restrict__ X, const int* __restrict__ src,
                    const int* __restrict__ rp, const int* __restrict__ perm,
                    const float* __restrict__ aw, __hip_bfloat16* __restrict__ out)
{
    int w = threadIdx.x >> 6, lane = threadIdx.x & 63;
    int v = blockIdx.x * 4 + w;
    if (v >= V_N) return;
    float a[4] = {};
    int b = rp[v], en = rp[v + 1];
    for (int i = b; i < en; i++) {
        int e = perm[i];
        float we = aw[e];
        long basep = (long)src[e] * LDA;
        a[0] += we * bf2f(X[basep + lane]);
        a[1] += we * bf2f(X[basep + 64 + lane]);
        a[2] += we * bf2f(X[basep + 128 + lane]);
        if (lane < 8) a[3] += we * bf2f(X[basep + 192 + lane]);
    }
    out[(long)v * LDA + lane] = __float2bfloat16(elu_f(a[0]));
    out[(long)v * LDA + 64 + lane] = __float2bfloat16(elu_f(a[1]));
    out[(long)v * LDA + 128 + lane] = __float2bfloat16(elu_f(a[2]));
    if (lane < 8) out[(long)v * LDA + 192 + lane] = __float2bfloat16(elu_f(a[3]));
}

// ---------------------------------------------------------------------------
// readout
// ---------------------------------------------------------------------------
__global__ __launch_bounds__(256)
void mask_kernel(const float* __restrict__ nfeat, float* __restrict__ mask)
{
    int v = blockIdx.x * blockDim.x + threadIdx.x;
    if (v >= V_N) return;
    const float* row = nfeat + (long)v * NFEAT;
    float s = row[NFEAT - 4] + row[NFEAT - 3] + row[NFEAT - 2] + row[NFEAT - 1];
    float m = s * (1.f - row[0]);
    mask[v] = 1.f / m - 1.f;
}

__global__ __launch_bounds__(256)
void readout_kernel(const __hip_bfloat16* __restrict__ nf, const float* __restrict__ predW,
                    const float* __restrict__ predb, const float* __restrict__ mask,
                    const int* __restrict__ gid, float* __restrict__ out_atom,
                    float* __restrict__ gsum)
{
    int gtid = blockIdx.x * blockDim.x + threadIdx.x;
    int v = gtid >> 6, lane = gtid & 63;
    if (v >= V_N) return;
    float acc = 0.f;
    for (int k = lane; k < G_DIM; k += 64)
        acc += bf2f(nf[(long)v * LDA + k]) * predW[k];
    for (int off = 32; off > 0; off >>= 1) acc += __shfl_down(acc, off, 64);
    if (lane == 0) {
        float p = acc + predb[0] + mask[v];
        out_atom[v] = p;
        atomicAdd(&gsum[gid[v]], exp10f(-p));
    }
}

__global__ __launch_bounds__(256)
void graph_out_kernel(const float* __restrict__ gsum, float* __restrict__ out_g)
{
    int g = blockIdx.x * blockDim.x + threadIdx.x;
    if (g >= NG_N) return;
    out_g[g] = -log10f(gsum[g]);
}

// ---------------------------------------------------------------------------
extern "C" void kernel_launch(void* const* d_in, const int* in_sizes, int n_in,
                              void* d_out, int out_size, void* d_ws, size_t ws_size,
                              hipStream_t stream)
{
    const float* node_feats = (const float*)d_in[0];
    const float* edge_feats = (const float*)d_in[1];
    const float* pn_W  = (const float*)d_in[2];
    const float* pn_b  = (const float*)d_in[3];
    const float* pe1_W = (const float*)d_in[4];
    const float* pe1_b = (const float*)d_in[5];
    const float* pe2_W = (const float*)d_in[6];
    const float* pe2_b = (const float*)d_in[7];
    const float* et_W  = (const float*)d_in[8];
    const float* et_b  = (const float*)d_in[9];
    const float* gru0_Wih = (const float*)d_in[10];
    const float* gru0_Whh = (const float*)d_in[11];
    const float* gru0_bih = (const float*)d_in[12];
    const float* gru0_bhh = (const float*)d_in[13];
    const float* gnn_pe_W = (const float*)d_in[14];
    const float* gnn_pe_b = (const float*)d_in[15];
    const float* gnn_pn_W = (const float*)d_in[16];
    const float* gnn_pn_b = (const float*)d_in[17];
    const float* gnn_gru_Wih = (const float*)d_in[18];
    const float* gnn_gru_Whh = (const float*)d_in[19];
    const float* gnn_gru_bih = (const float*)d_in[20];
    const float* gnn_gru_bhh = (const float*)d_in[21];
    const float* pred_W = (const float*)d_in[22];
    const float* pred_b = (const float*)d_in[23];
    const int* src = (const int*)d_in[24];
    const int* dst = (const int*)d_in[25];
    const int* gid = (const int*)d_in[26];

    float* out_g = (float*)d_out;
    float* out_atom = out_g + NG_N;

    char* base = (char*)d_ws;
    size_t off = 0;
    auto take = [&](size_t bytes) -> void* {
        void* p = base + off;
        off += (bytes + 255) & ~(size_t)255;
        return p;
    };
    const size_t VP = (size_t)V_N * LDA;
    const size_t WPL = (size_t)7 * 14 * 3072;
    float* mask   = (float*)take((size_t)V_N * 4);
    float* logits = (float*)take((size_t)E_N * 4);
    float* aw     = (float*)take((size_t)E_N * 4);
    float* hedot  = (float*)take((size_t)E_N * 4);
    float* s1     = (float*)take((size_t)V_N * 4);
    float* s2     = (float*)take((size_t)V_N * 4);
    float* gsum   = (float*)take((size_t)NG_N * 4);
    __hip_bfloat16* c    = (__hip_bfloat16*)take(VP * 2);
    __hip_bfloat16* hv   = (__hip_bfloat16*)take(VP * 2);
    __hip_bfloat16* nf_a = (__hip_bfloat16*)take(VP * 2);
    __hip_bfloat16* nf_b = (__hip_bfloat16*)take(VP * 2);
    short* WpGru = (short*)take(3 * WPL * 2);
    short* Wp_pn0 = (short*)take((size_t)256 * 96 * 2);
    short* Wp_pe1 = (short*)take((size_t)256 * 96 * 2);
    short* Wp_et  = (short*)take((size_t)7 * 7 * 1024 * 2);
    short* Wp_pn1 = (short*)take((size_t)7 * 7 * 1024 * 2);
    short* Wp_pn2 = (short*)take((size_t)7 * 7 * 1024 * 2);
    int* deg  = (int*)take((size_t)V_N * 4);
    int* cnt  = (int*)take((size_t)V_N * 4);
    int* rp   = (int*)take((size_t)(V_N + 1) * 4);
    int* perm = (int*)take((size_t)E_N * 4);
    int* bsum = (int*)take((size_t)512 * 4);
    __hip_bfloat16* P    = nf_a;  // alias: nf_a written only at GRU0
    __hip_bfloat16* hbar = nf_b;  // alias: nf_b first written as layer-0 GRU output
    __hip_bfloat16* hvp  = hv;    // alias: hv dead after GRU0

    if (off > ws_size) {
        fill_kernel<<<cdiv(out_size, 256), 256, 0, stream>>>((float*)d_out, -12345.f, out_size);
        return;
    }

    const int BLK = 256;
    const int nScanBlocks = cdiv(V_N, 256);
    const dim3 gOld(4, cdiv(V_N, 64));
    const dim3 gNew(7, cdiv(V_N, 256));
    const int gAgg = cdiv(V_N, 4);

    // zero-fill padded node matrices (pads must be 0 for GEMM/GRU K-loops)
    {
        int nFloats = (int)(4 * VP * 2 / 4);
        fill_kernel<<<cdiv(nFloats, BLK), BLK, 0, stream>>>((float*)c, 0.f, nFloats);
    }

    // ---- weight prep ----
    gru_wprep_kernel<<<cdiv(7 * 14 * 3072, 256), BLK, 0, stream>>>(gru0_Wih, gru0_Whh, WpGru);
    for (int l = 0; l < L_N; l++)
        gru_wprep_kernel<<<cdiv(7 * 14 * 3072, 256), BLK, 0, stream>>>(
            gnn_gru_Wih + (size_t)l * G_DIM * 3 * G_DIM,
            gnn_gru_Whh + (size_t)l * G_DIM * 3 * G_DIM,
            WpGru + (size_t)(l + 1) * WPL);
    wprep_kernel<<<cdiv(256 * 96, 256), BLK, 0, stream>>>(pn_W, Wp_pn0, NFEAT, 96);
    wprep_kernel<<<cdiv(256 * 96, 256), BLK, 0, stream>>>(pe1_W, Wp_pe1, NFEAT, 96);
    wprep_tiled_kernel<<<cdiv(7 * 7 * 1024, 256), BLK, 0, stream>>>(et_W, Wp_et);
    wprep_tiled_kernel<<<cdiv(7 * 7 * 1024, 256), BLK, 0, stream>>>(gnn_pn_W, Wp_pn1);
    wprep_tiled_kernel<<<cdiv(7 * 7 * 1024, 256), BLK, 0, stream>>>(
        gnn_pn_W + (size_t)G_DIM * G_DIM, Wp_pn2);

    mask_kernel<<<cdiv(V_N, BLK), BLK, 0, stream>>>(node_feats, mask);

    // ---- CSR build (by dst) ----
    fill_int_kernel<<<cdiv(V_N, BLK), BLK, 0, stream>>>(deg, 0, V_N);
    hist_kernel<<<cdiv(E_N, BLK), BLK, 0, stream>>>(dst, deg);
    scan1_kernel<<<nScanBlocks, BLK, 0, stream>>>(deg, rp, bsum);
    scan2_kernel<<<1, 1, 0, stream>>>(bsum, rp, nScanBlocks);
    scan3_kernel<<<nScanBlocks, BLK, 0, stream>>>(rp, bsum);
    fill_int_kernel<<<cdiv(V_N, BLK), BLK, 0, stream>>>(cnt, 0, V_N);
    csr_fill_kernel<<<cdiv(E_N, BLK), BLK, 0, stream>>>(dst, rp, cnt, perm);

    // ---- GetContext ----
    gemm_f32a_kernel<0><<<gOld, BLK, 0, stream>>>(node_feats, Wp_pn0, pn_b, hv);
    gemm_f32a_kernel<1><<<gOld, BLK, 0, stream>>>(node_feats, Wp_pe1, pe1_b, P);
    // t1[v] = hv[v]·pe2W[0:200]  (stored in s1)
    node_dot2_kernel<<<gAgg, BLK, 0, stream>>>(hv, pe2_W, nullptr, s1, nullptr);
    // hedot[e] = he1[e]·pe2W[200:400] (he1 on the fly)
    ctx_hedot_kernel<<<cdiv(E_N, 8), BLK, 0, stream>>>(
        P, edge_feats, src, pe1_W, pe2_W, hedot);
    edge_combine_kernel<<<cdiv(E_N, BLK), BLK, 0, stream>>>(
        s1, dst, nullptr, src, hedot, pe2_b, logits);
    softmax_csr_kernel<<<cdiv(V_N, BLK), BLK, 0, stream>>>(logits, rp, perm, aw);
    ctx_agg_kernel<<<gAgg, BLK, 0, stream>>>(P, edge_feats, src, rp, perm, aw, pe1_W, hbar);
    gemm_bf16a_kernel<3><<<gNew, BLK, 0, stream>>>(hbar, Wp_et, et_b, c);
    gru_mfma_kernel<<<gNew, BLK, 0, stream>>>(c, hv, WpGru, gru0_bih, gru0_bhh, nf_a);

    // ---- GNN layers ----
    __hip_bfloat16* cur = nf_a;
    __hip_bfloat16* nxt = nf_b;
    for (int l = 0; l < L_N; l++) {
        const float* pe_W = gnn_pe_W + (size_t)l * 2 * G_DIM;
        const float* pe_b = gnn_pe_b + l;
        const float* pnB  = gnn_pn_b + (size_t)l * G_DIM;
        const float* bih  = gnn_gru_bih + (size_t)l * 3 * G_DIM;
        const float* bhh  = gnn_gru_bhh + (size_t)l * 3 * G_DIM;
        const short* WpPn = (l == 0) ? Wp_pn1 : Wp_pn2;

        // s1[v]=cur·peW[0:200] (dst part), s2[v]=cur·peW[200:400] (src part)
        node_dot2_kernel<<<gAgg, BLK, 0, stream>>>(cur, pe_W, pe_W + G_DIM, s1, s2);
        edge_combine_kernel<<<cdiv(E_N, BLK), BLK, 0, stream>>>(
            s1, dst, s2, src, nullptr, pe_b, logits);
        softmax_csr_kernel<<<cdiv(V_N, BLK), BLK, 0, stream>>>(logits, rp, perm, aw);

        gemm_bf16a_kernel<1><<<gNew, BLK, 0, stream>>>(cur, WpPn, pnB, hvp);
        gnn_agg_kernel<<<gAgg, BLK, 0, stream>>>(hvp, src, rp, perm, aw, c);
        gru_mfma_kernel<<<gNew, BLK, 0, stream>>>(
            c, cur, WpGru + (size_t)(l + 1) * WPL, bih, bhh, nxt);

        __hip_bfloat16* tmp = cur; cur = nxt; nxt = tmp;
    }

    // ---- readout ----
    fill_kernel<<<cdiv(NG_N, BLK), BLK, 0, stream>>>(gsum, 0.f, NG_N);
    readout_kernel<<<cdiv(V_N * 64, BLK), BLK, 0, stream>>>(
        cur, pred_W, pred_b, mask, gid, out_atom, gsum);
    graph_out_kernel<<<cdiv(NG_N, BLK), BLK, 0, stream>>>(gsum, out_g);
}

// Round 8
// 2048.767 us; speedup vs baseline: 9.4638x; 1.1736x over previous
//
#include <hip/hip_runtime.h>
#include <hip/hip_bf16.h>
#include <math.h>

#define V_N    100000
#define E_N    400000
#define NFEAT  74
#define NEFEAT 12
#define G_DIM  200
#define LDA    224          // padded leading dim for all bf16 node matrices
#define L_N    2
#define NG_N   4000
#define NROWB  391          // cdiv(V_N,256)
#define NROWP  392          // padded to multiple of 8
#define NSWZ   (NROWP / 8 * 56)   // swizzled 1-D grid size = 2744

static inline int cdiv(int a, int b) { return (a + b - 1) / b; }

__device__ __forceinline__ float lrelu_f(float x) { return x > 0.f ? x : 0.01f * x; }
__device__ __forceinline__ float sigmoid_f(float x) { return 1.f / (1.f + expf(-x)); }
__device__ __forceinline__ float elu_f(float x) { return x > 0.f ? x : expm1f(x); }
__device__ __forceinline__ float bf2f(__hip_bfloat16 x) { return __bfloat162float(x); }

__device__ __forceinline__ short f2bf(float f) {
    __hip_bfloat16 b = __float2bfloat16(f);
    short s;
    __builtin_memcpy(&s, &b, 2);
    return s;
}

typedef short short8 __attribute__((ext_vector_type(8)));
typedef float f32x4 __attribute__((ext_vector_type(4)));

#define MFMA16(a, b, c) __builtin_amdgcn_mfma_f32_16x16x32_bf16((a), (b), (c), 0, 0, 0)

// XCD-aware swizzle: 7 cb-blocks of one row-tile land on the same XCD (lin%8)
__device__ __forceinline__ void swz_decode(int lin, int& rowBlk, int& cb)
{
    int grp = lin / 56;
    int rem = lin % 56;
    cb = rem >> 3;            // 0..6
    rowBlk = grp * 8 + (rem & 7);
}

// ---------------------------------------------------------------------------
__global__ __launch_bounds__(256)
void fill_kernel(float* __restrict__ p, float v, int n)
{
    int i = blockIdx.x * blockDim.x + threadIdx.x;
    if (i < n) p[i] = v;
}

__global__ __launch_bounds__(256)
void fill_int_kernel(int* __restrict__ p, int v, int n)
{
    int i = blockIdx.x * blockDim.x + threadIdx.x;
    if (i < n) p[i] = v;
}

// ---------------------------------------------------------------------------
// Weight preps
// ---------------------------------------------------------------------------
__global__ __launch_bounds__(256)
void wprep_kernel(const float* __restrict__ W, short* __restrict__ Wp, int K, int Kpad)
{
    int idx = blockIdx.x * 256 + threadIdx.x;
    if (idx >= 256 * Kpad) return;
    int j = idx / Kpad, k = idx % Kpad;
    float v = (j < G_DIM && k < K) ? W[(long)k * G_DIM + j] : 0.f;
    Wp[idx] = f2bf(v);
}

// Tiled for K=224 GEMM: Wp[cb<7][st<7][cc<32][kk<32]
__global__ __launch_bounds__(256)
void wprep_tiled_kernel(const float* __restrict__ W, short* __restrict__ Wp)
{
    int idx = blockIdx.x * 256 + threadIdx.x;
    if (idx >= 7 * 7 * 1024) return;
    int cb = idx / (7 * 1024);
    int r = idx % (7 * 1024);
    int st = r / 1024;
    int r2 = r % 1024;
    int cc = r2 / 32, kk = r2 % 32;
    int col = cb * 32 + cc, k = st * 32 + kk;
    float v = (col < G_DIM && k < G_DIM) ? W[(long)k * G_DIM + col] : 0.f;
    Wp[idx] = f2bf(v);
}

// GRU tiled: Wp[cb<7][st<14][g<3][cc<32][kk<32]; st<7 -> Wih, st>=7 -> Whh
__global__ __launch_bounds__(256)
void gru_wprep_kernel(const float* __restrict__ Wih, const float* __restrict__ Whh,
                      short* __restrict__ Wp)
{
    int idx = blockIdx.x * 256 + threadIdx.x;
    if (idx >= 7 * 14 * 3072) return;
    int cb = idx / (14 * 3072);
    int r = idx % (14 * 3072);
    int st = r / 3072;
    int r2 = r % 3072;
    int g = r2 / 1024;
    int r3 = r2 % 1024;
    int cc = r3 / 32, kk = r3 % 32;
    int col = cb * 32 + cc;
    float v = 0.f;
    if (col < G_DIM) {
        if (st < 7) {
            int k = st * 32 + kk;
            if (k < G_DIM) v = Wih[(long)k * (3 * G_DIM) + g * G_DIM + col];
        } else {
            int k = (st - 7) * 32 + kk;
            if (k < G_DIM) v = Whh[(long)k * (3 * G_DIM) + g * G_DIM + col];
        }
    }
    Wp[idx] = f2bf(v);
}

// ---------------------------------------------------------------------------
// CSR build
// ---------------------------------------------------------------------------
__global__ __launch_bounds__(256)
void hist_kernel(const int* __restrict__ dst, int* __restrict__ deg)
{
    int e = blockIdx.x * blockDim.x + threadIdx.x;
    if (e >= E_N) return;
    atomicAdd(&deg[dst[e]], 1);
}

__global__ __launch_bounds__(256)
void scan1_kernel(const int* __restrict__ deg, int* __restrict__ rp, int* __restrict__ bsum)
{
    __shared__ int s[256];
    int tid = threadIdx.x;
    int v = blockIdx.x * 256 + tid;
    int x = (v < V_N) ? deg[v] : 0;
    s[tid] = x;
    __syncthreads();
    for (int off = 1; off < 256; off <<= 1) {
        int t = (tid >= off) ? s[tid - off] : 0;
        __syncthreads();
        s[tid] += t;
        __syncthreads();
    }
    if (v < V_N) rp[v] = s[tid] - x;
    if (tid == 255) bsum[blockIdx.x] = s[255];
}

__global__ void scan2_kernel(int* __restrict__ bsum, int* __restrict__ rp, int nb)
{
    if (threadIdx.x != 0 || blockIdx.x != 0) return;
    int acc = 0;
    for (int b = 0; b < nb; b++) { int t = bsum[b]; bsum[b] = acc; acc += t; }
    rp[V_N] = acc;
}

__global__ __launch_bounds__(256)
void scan3_kernel(int* __restrict__ rp, const int* __restrict__ bsum)
{
    int v = blockIdx.x * 256 + threadIdx.x;
    if (v < V_N) rp[v] += bsum[v >> 8];
}

__global__ __launch_bounds__(256)
void csr_fill_kernel(const int* __restrict__ dst, const int* __restrict__ rp,
                     int* __restrict__ cnt, int* __restrict__ perm)
{
    int e = blockIdx.x * blockDim.x + threadIdx.x;
    if (e >= E_N) return;
    int d = dst[e];
    int pos = rp[d] + atomicAdd(&cnt[d], 1);
    perm[pos] = e;
}

// ---------------------------------------------------------------------------
// Dual 64x64 MFMA GEMM for fp32-A (K=74 pad 96): hv AND P in one A pass.
// hv = lrelu(A@W1+b1), P = A@W2+b2
// ---------------------------------------------------------------------------
__global__ __launch_bounds__(256)
void gemm_f32a_dual_kernel(const float* __restrict__ Af32,
                           const short* __restrict__ Wp1, const float* __restrict__ b1,
                           const short* __restrict__ Wp2, const float* __restrict__ b2,
                           __hip_bfloat16* __restrict__ C1,
                           __hip_bfloat16* __restrict__ C2)
{
    __shared__ short As[64 * 40];
    __shared__ short Bs1[64 * 40];
    __shared__ short Bs2[64 * 40];
    const int tid = threadIdx.x;
    const int lane = tid & 63;
    const int w = tid >> 6;
    const int quad = lane >> 4;
    const int lm = lane & 15;
    const int rowBase = blockIdx.y * 64;
    const int j0 = blockIdx.x * 64;
    const int arow = tid >> 2;
    const int akc = (tid & 3) * 8;
    const int agrow = rowBase + arow;

    f32x4 acc1[4] = {}, acc2[4] = {};

    for (int k0 = 0; k0 < 96; k0 += 32) {
        short8 av = {};
        if (agrow < V_N) {
            int gk = k0 + akc;
            #pragma unroll
            for (int i = 0; i < 8; i++) {
                int kg = gk + i;
                av[i] = (kg < NFEAT) ? f2bf(Af32[(long)agrow * NFEAT + kg]) : (short)0;
            }
        }
        *(short8*)&As[arow * 40 + akc] = av;
        {
            int col = tid >> 2;
            *(short8*)&Bs1[col * 40 + akc] =
                *(const short8*)(Wp1 + (long)(j0 + col) * 96 + k0 + akc);
            *(short8*)&Bs2[col * 40 + akc] =
                *(const short8*)(Wp2 + (long)(j0 + col) * 96 + k0 + akc);
        }
        __syncthreads();
        short8 a = *(short8*)&As[(w * 16 + lm) * 40 + quad * 8];
        #pragma unroll
        for (int nt = 0; nt < 4; nt++) {
            short8 bb1 = *(short8*)&Bs1[(nt * 16 + lm) * 40 + quad * 8];
            short8 bb2 = *(short8*)&Bs2[(nt * 16 + lm) * 40 + quad * 8];
            acc1[nt] = MFMA16(a, bb1, acc1[nt]);
            acc2[nt] = MFMA16(a, bb2, acc2[nt]);
        }
        __syncthreads();
    }

    #pragma unroll
    for (int nt = 0; nt < 4; nt++) {
        int col = j0 + nt * 16 + lm;
        if (col >= G_DIM) continue;
        float bv1 = b1[col], bv2 = b2[col];
        #pragma unroll
        for (int r = 0; r < 4; r++) {
            int grow = rowBase + w * 16 + quad * 4 + r;
            if (grow >= V_N) continue;
            C1[(long)grow * LDA + col] = __float2bfloat16(lrelu_f(acc1[nt][r] + bv1));
            C2[(long)grow * LDA + col] = __float2bfloat16(acc2[nt][r] + bv2);
        }
    }
}

// ---------------------------------------------------------------------------
// 256x32 MFMA GEMM, bf16 A [V][LDA], K=224, Wp tiled [7][7][32][32]
// XCD-swizzled 1-D grid (NSWZ blocks)
// ---------------------------------------------------------------------------
template<int EPI>   // 1 = bias only, 3 = elu
__global__ __launch_bounds__(256)
void gemm_bf16a_kernel(const __hip_bfloat16* __restrict__ Abf,
                       const short* __restrict__ Wp,
                       const float* __restrict__ bias,
                       __hip_bfloat16* __restrict__ Cbf)
{
    __shared__ short As[256 * 32];
    __shared__ short Bs[32 * 32];
    int rowBlk, cb;
    swz_decode(blockIdx.x, rowBlk, cb);
    if (rowBlk >= NROWB) return;
    const int tid = threadIdx.x;
    const int lane = tid & 63;
    const int w = tid >> 6;
    const int quad = lane >> 4;
    const int lm = lane & 15;
    const int j0 = cb * 32;
    const int rowBase = rowBlk * 256;
    const int sRow = tid >> 2;
    const int sChunk = (tid & 3) * 8;

    const short* WpB = Wp + (long)cb * (7 * 1024);
    f32x4 acc[4][2] = {};

    #pragma unroll 1
    for (int st = 0; st < 7; st++) {
        int kl = st * 32;
        #pragma unroll
        for (int p = 0; p < 4; p++) {
            int r = sRow + p * 64;
            int gr = rowBase + r;
            short8 v = {};
            if (gr < V_N) v = *(const short8*)((const short*)Abf + (long)gr * LDA + kl + sChunk);
            *(short8*)&As[r * 32 + sChunk] = v;
        }
        if (tid < 128)
            *(short8*)&Bs[tid * 8] = *(const short8*)(WpB + st * 1024 + tid * 8);
        __syncthreads();
        short8 b0 = *(short8*)&Bs[(0 * 16 + lm) * 32 + quad * 8];
        short8 b1 = *(short8*)&Bs[(1 * 16 + lm) * 32 + quad * 8];
        #pragma unroll
        for (int rt = 0; rt < 4; rt++) {
            short8 a = *(short8*)&As[(w * 64 + rt * 16 + lm) * 32 + quad * 8];
            acc[rt][0] = MFMA16(a, b0, acc[rt][0]);
            acc[rt][1] = MFMA16(a, b1, acc[rt][1]);
        }
        __syncthreads();
    }

    #pragma unroll
    for (int nt = 0; nt < 2; nt++) {
        int col = j0 + nt * 16 + lm;
        if (col >= G_DIM) continue;
        float bv = bias[col];
        #pragma unroll
        for (int rt = 0; rt < 4; rt++) {
            #pragma unroll
            for (int r = 0; r < 4; r++) {
                int grow = rowBase + w * 64 + rt * 16 + quad * 4 + r;
                if (grow >= V_N) continue;
                float v = acc[rt][nt][r] + bv;
                if (EPI == 3) v = elu_f(v);
                Cbf[(long)grow * LDA + col] = __float2bfloat16(v);
            }
        }
    }
}

// ---------------------------------------------------------------------------
// Fused MFMA GRU: out = relu(gru_cell(xc, h)); XCD-swizzled 1-D grid
// ---------------------------------------------------------------------------
__global__ __launch_bounds__(256)
void gru_mfma_kernel(const __hip_bfloat16* __restrict__ xc,
                     const __hip_bfloat16* __restrict__ h,
                     const short* __restrict__ Wp,
                     const float* __restrict__ bih, const float* __restrict__ bhh,
                     __hip_bfloat16* __restrict__ out)
{
    __shared__ short As[256 * 32];
    __shared__ short Bs[3 * 32 * 32];
    int rowBlk, cb;
    swz_decode(blockIdx.x, rowBlk, cb);
    if (rowBlk >= NROWB) return;
    const int tid = threadIdx.x;
    const int lane = tid & 63;
    const int w = tid >> 6;
    const int quad = lane >> 4;
    const int lm = lane & 15;
    const int j0 = cb * 32;
    const int rowBase = rowBlk * 256;
    const int sRow = tid >> 2;
    const int sChunk = (tid & 3) * 8;

    const short* WpB = Wp + (long)cb * (14 * 3072);

    f32x4 aR[4][2] = {}, aZ[4][2] = {}, aNl[4][2] = {}, aNh[4][2] = {};

    #pragma unroll 1
    for (int st = 0; st < 14; st++) {
        const short* Aptr = (st < 7) ? (const short*)xc : (const short*)h;
        int kl = (st < 7 ? st : st - 7) * 32;
        #pragma unroll
        for (int p = 0; p < 4; p++) {
            int r = sRow + p * 64;
            int gr = rowBase + r;
            short8 v = {};
            if (gr < V_N) v = *(const short8*)(Aptr + (long)gr * LDA + kl + sChunk);
            *(short8*)&As[r * 32 + sChunk] = v;
        }
        {
            const short* bs = WpB + st * 3072;
            *(short8*)&Bs[tid * 8] = *(const short8*)(bs + tid * 8);
            if (tid < 128)
                *(short8*)&Bs[(tid + 256) * 8] = *(const short8*)(bs + (tid + 256) * 8);
        }
        __syncthreads();
        short8 br[2], bz[2], bn[2];
        #pragma unroll
        for (int nt = 0; nt < 2; nt++) {
            br[nt] = *(short8*)&Bs[(0 * 32 + nt * 16 + lm) * 32 + quad * 8];
            bz[nt] = *(short8*)&Bs[(1 * 32 + nt * 16 + lm) * 32 + quad * 8];
            bn[nt] = *(short8*)&Bs[(2 * 32 + nt * 16 + lm) * 32 + quad * 8];
        }
        #pragma unroll
        for (int rt = 0; rt < 4; rt++) {
            short8 a = *(short8*)&As[(w * 64 + rt * 16 + lm) * 32 + quad * 8];
            #pragma unroll
            for (int nt = 0; nt < 2; nt++) {
                aR[rt][nt] = MFMA16(a, br[nt], aR[rt][nt]);
                aZ[rt][nt] = MFMA16(a, bz[nt], aZ[rt][nt]);
                if (st < 7) aNl[rt][nt] = MFMA16(a, bn[nt], aNl[rt][nt]);
                else        aNh[rt][nt] = MFMA16(a, bn[nt], aNh[rt][nt]);
            }
        }
        __syncthreads();
    }

    #pragma unroll
    for (int nt = 0; nt < 2; nt++) {
        int col = j0 + nt * 16 + lm;
        if (col >= G_DIM) continue;
        float b_ir = bih[col], b_iz = bih[G_DIM + col], b_in = bih[2 * G_DIM + col];
        float b_hr = bhh[col], b_hz = bhh[G_DIM + col], b_hn = bhh[2 * G_DIM + col];
        #pragma unroll
        for (int rt = 0; rt < 4; rt++) {
            #pragma unroll
            for (int r = 0; r < 4; r++) {
                int grow = rowBase + w * 64 + rt * 16 + quad * 4 + r;
                if (grow >= V_N) continue;
                float sr = aR[rt][nt][r] + b_ir + b_hr;
                float sz = aZ[rt][nt][r] + b_iz + b_hz;
                float gin = aNl[rt][nt][r] + b_in;
                float ghn = aNh[rt][nt][r] + b_hn;
                float rr = sigmoid_f(sr);
                float zz = sigmoid_f(sz);
                float nn = tanhf(gin + rr * ghn);
                float hval = bf2f(h[(long)grow * LDA + col]);
                float o = (1.f - zz) * nn + zz * hval;
                out[(long)grow * LDA + col] = __float2bfloat16(o > 0.f ? o : 0.f);
            }
        }
    }
}

// ---------------------------------------------------------------------------
// Node dot(s): s1[v] = X[v]·wa (+ s2[v] = X[v]·wb if wb). Wave per node.
// ---------------------------------------------------------------------------
__global__ __launch_bounds__(256)
void node_dot2_kernel(const __hip_bfloat16* __restrict__ X,
                      const float* __restrict__ wa, const float* __restrict__ wb,
                      float* __restrict__ s1, float* __restrict__ s2)
{
    int w = threadIdx.x >> 6, lane = threadIdx.x & 63;
    int v = blockIdx.x * 4 + w;
    if (v >= V_N) return;
    const __hip_bfloat16* row = X + (long)v * LDA;
    float a = 0.f, b = 0.f;
    #pragma unroll
    for (int c = 0; c < 4; c++) {
        int k = c * 64 + lane;
        if (k < G_DIM) {
            float x = bf2f(row[k]);
            a += x * wa[k];
            if (wb) b += x * wb[k];
        }
    }
    for (int off = 32; off > 0; off >>= 1) {
        a += __shfl_down(a, off, 64);
        if (wb) b += __shfl_down(b, off, 64);
    }
    if (lane == 0) {
        s1[v] = a;
        if (wb) s2[v] = b;
    }
}

// logits[e] = lrelu( sd[dst[e]] + (ssn ? ssn[src[e]] : sse[e]) + b )
__global__ __launch_bounds__(256)
void edge_combine_kernel(const float* __restrict__ sd, const int* __restrict__ dst,
                         const float* __restrict__ ssn, const int* __restrict__ src,
                         const float* __restrict__ sse,
                         const float* __restrict__ b, float* __restrict__ out)
{
    int e = blockIdx.x * blockDim.x + threadIdx.x;
    if (e >= E_N) return;
    float v = sd[dst[e]] + (ssn ? ssn[src[e]] : sse[e]) + b[0];
    out[e] = lrelu_f(v);
}

// ---------------------------------------------------------------------------
// Ctx he1-dot: hedot[e] = sum_k lrelu(P[src[e]][k] + Q[e][k]) * pe2W[200+k]
// ---------------------------------------------------------------------------
__global__ __launch_bounds__(256)
void ctx_hedot_kernel(const __hip_bfloat16* __restrict__ P,
                      const float* __restrict__ efeat,
                      const int* __restrict__ src,
                      const float* __restrict__ pe1W,
                      const float* __restrict__ pe2W,
                      float* __restrict__ hedot)
{
    __shared__ float Wef[NEFEAT * G_DIM];
    __shared__ float w2s[G_DIM];
    const int tid = threadIdx.x;
    for (int i = tid; i < NEFEAT * G_DIM; i += 256) {
        int j = i / G_DIM, k = i % G_DIM;
        Wef[i] = pe1W[(long)(NFEAT + j) * G_DIM + k];
    }
    for (int i = tid; i < G_DIM; i += 256) w2s[i] = pe2W[G_DIM + i];
    __syncthreads();
    const int w = tid >> 6, lane = tid & 63;
    const int e0 = (blockIdx.x * 4 + w) * 2;
    #pragma unroll
    for (int u = 0; u < 2; u++) {
        int e = e0 + u;
        if (e >= E_N) break;
        int s = src[e];
        float efj = (lane < NEFEAT) ? efeat[(long)e * NEFEAT + lane] : 0.f;
        float ef[NEFEAT];
        #pragma unroll
        for (int j = 0; j < NEFEAT; j++) ef[j] = __shfl(efj, j, 64);
        float acc = 0.f;
        #pragma unroll
        for (int c = 0; c < 4; c++) {
            int k = c * 64 + lane;
            if (k < G_DIM) {
                float q = 0.f;
                #pragma unroll
                for (int j = 0; j < NEFEAT; j++) q += ef[j] * Wef[j * G_DIM + k];
                acc += lrelu_f(bf2f(P[(long)s * LDA + k]) + q) * w2s[k];
            }
        }
        for (int off = 32; off > 0; off >>= 1) acc += __shfl_down(acc, off, 64);
        if (lane == 0) hedot[e] = acc;
    }
}

// ---------------------------------------------------------------------------
// Ctx aggregation: hbar[v] = sum aw[e]*he1[e] (he1 on the fly), wave per node
// ---------------------------------------------------------------------------
__global__ __launch_bounds__(256)
void ctx_agg_kernel(const __hip_bfloat16* __restrict__ P,
                    const float* __restrict__ efeat,
                    const int* __restrict__ src,
                    const int* __restrict__ rp, const int* __restrict__ perm,
                    const float* __restrict__ aw,
                    const float* __restrict__ pe1W,
                    __hip_bfloat16* __restrict__ hbar)
{
    __shared__ float Wef[NEFEAT * G_DIM];
    const int tid = threadIdx.x;
    for (int i = tid; i < NEFEAT * G_DIM; i += 256) {
        int j = i / G_DIM, k = i % G_DIM;
        Wef[i] = pe1W[(long)(NFEAT + j) * G_DIM + k];
    }
    __syncthreads();
    const int w = tid >> 6, lane = tid & 63;
    int v = blockIdx.x * 4 + w;
    if (v >= V_N) return;
    float a[4] = {};
    int b = rp[v], en = rp[v + 1];
    for (int i = b; i < en; i++) {
        int e = perm[i];
        float we = aw[e];
        int s = src[e];
        float efj = (lane < NEFEAT) ? efeat[(long)e * NEFEAT + lane] : 0.f;
        float ef[NEFEAT];
        #pragma unroll
        for (int j = 0; j < NEFEAT; j++) ef[j] = __shfl(efj, j, 64);
        #pragma unroll
        for (int c = 0; c < 4; c++) {
            int k = c * 64 + lane;
            if (k < G_DIM) {
                float q = 0.f;
                #pragma unroll
                for (int j = 0; j < NEFEAT; j++) q += ef[j] * Wef[j * G_DIM + k];
                a[c] += we * lrelu_f(bf2f(P[(long)s * LDA + k]) + q);
            }
        }
    }
    #pragma unroll
    for (int c = 0; c < 4; c++) {
        int k = c * 64 + lane;
        if (k < G_DIM) hbar[(long)v * LDA + k] = __float2bfloat16(a[c]);
    }
}

// ---------------------------------------------------------------------------
// CSR softmax (thread per node)
// ---------------------------------------------------------------------------
__global__ __launch_bounds__(256)
void softmax_csr_kernel(const float* __restrict__ logits, const int* __restrict__ rp,
                        const int* __restrict__ perm, float* __restrict__ aw)
{
    int v = blockIdx.x * blockDim.x + threadIdx.x;
    if (v >= V_N) return;
    int b = rp[v], en = rp[v + 1];
    if (en == b) return;
    float m = -INFINITY;
    for (int i = b; i < en; i++) m = fmaxf(m, logits[perm[i]]);
    float s = 0.f;
    for (int i = b; i < en; i++) s += expf(logits[perm[i]] - m);
    float inv = 1.f / s;
    for (int i = b; i < en; i++) {
        int e = perm[i];
        aw[e] = expf(logits[e] - m) * inv;
    }
}

// ---------------------------------------------------------------------------
// GNN aggregate: c[v] = elu(sum aw[e]*hvp[src[e]]), wave per node
// ---------------------------------------------------------------------------
__global__ __launch_bounds__(256)
void gnn_agg_kernel(const __hip_bfloat16* __restrict__ X, const int* __restrict__ src,
                    const int* __restrict__ rp, const int* __restrict__ perm,
                    const float* __restrict__ aw, __hip_bfloat16* __restrict__ out)
{
    int w = threadIdx.x >> 6, lane = threadIdx.x & 63;
    int v = blockIdx.x * 4 + w;
    if (v >= V_N) return;
    float a[4] = {};
    int b = rp[v], en = rp[v + 1];
    for (int i = b; i < en; i++) {
        int e = perm[i];
        float we = aw[e];
        long basep = (long)src[e] * LDA;
        a[0] += we * bf2f(X[basep + lane]);
        a[1] += we * bf2f(X[basep + 64 + lane]);
        a[2] += we * bf2f(X[basep + 128 + lane]);
        if (lane < 8) a[3] += we * bf2f(X[basep + 192 + lane]);
    }
    out[(long)v * LDA + lane] = __float2bfloat16(elu_f(a[0]));
    out[(long)v * LDA + 64 + lane] = __float2bfloat16(elu_f(a[1]));
    out[(long)v * LDA + 128 + lane] = __float2bfloat16(elu_f(a[2]));
    if (lane < 8) out[(long)v * LDA + 192 + lane] = __float2bfloat16(elu_f(a[3]));
}

// ---------------------------------------------------------------------------
// readout
// ---------------------------------------------------------------------------
__global__ __launch_bounds__(256)
void mask_kernel(const float* __restrict__ nfeat, float* __restrict__ mask)
{
    int v = blockIdx.x * blockDim.x + threadIdx.x;
    if (v >= V_N) return;
    const float* row = nfeat + (long)v * NFEAT;
    float s = row[NFEAT - 4] + row[NFEAT - 3] + row[NFEAT - 2] + row[NFEAT - 1];
    float m = s * (1.f - row[0]);
    mask[v] = 1.f / m - 1.f;
}

__global__ __launch_bounds__(256)
void readout_kernel(const __hip_bfloat16* __restrict__ nf, const float* __restrict__ predW,
                    const float* __restrict__ predb, const float* __restrict__ mask,
                    const int* __restrict__ gid, float* __restrict__ out_atom,
                    float* __restrict__ gsum)
{
    int gtid = blockIdx.x * blockDim.x + threadIdx.x;
    int v = gtid >> 6, lane = gtid & 63;
    if (v >= V_N) return;
    float acc = 0.f;
    for (int k = lane; k < G_DIM; k += 64)
        acc += bf2f(nf[(long)v * LDA + k]) * predW[k];
    for (int off = 32; off > 0; off >>= 1) acc += __shfl_down(acc, off, 64);
    if (lane == 0) {
        float p = acc + predb[0] + mask[v];
        out_atom[v] = p;
        atomicAdd(&gsum[gid[v]], exp10f(-p));
    }
}

__global__ __launch_bounds__(256)
void graph_out_kernel(const float* __restrict__ gsum, float* __restrict__ out_g)
{
    int g = blockIdx.x * blockDim.x + threadIdx.x;
    if (g >= NG_N) return;
    out_g[g] = -log10f(gsum[g]);
}

// ---------------------------------------------------------------------------
extern "C" void kernel_launch(void* const* d_in, const int* in_sizes, int n_in,
                              void* d_out, int out_size, void* d_ws, size_t ws_size,
                              hipStream_t stream)
{
    const float* node_feats = (const float*)d_in[0];
    const float* edge_feats = (const float*)d_in[1];
    const float* pn_W  = (const float*)d_in[2];
    const float* pn_b  = (const float*)d_in[3];
    const float* pe1_W = (const float*)d_in[4];
    const float* pe1_b = (const float*)d_in[5];
    const float* pe2_W = (const float*)d_in[6];
    const float* pe2_b = (const float*)d_in[7];
    const float* et_W  = (const float*)d_in[8];
    const float* et_b  = (const float*)d_in[9];
    const float* gru0_Wih = (const float*)d_in[10];
    const float* gru0_Whh = (const float*)d_in[11];
    const float* gru0_bih = (const float*)d_in[12];
    const float* gru0_bhh = (const float*)d_in[13];
    const float* gnn_pe_W = (const float*)d_in[14];
    const float* gnn_pe_b = (const float*)d_in[15];
    const float* gnn_pn_W = (const float*)d_in[16];
    const float* gnn_pn_b = (const float*)d_in[17];
    const float* gnn_gru_Wih = (const float*)d_in[18];
    const float* gnn_gru_Whh = (const float*)d_in[19];
    const float* gnn_gru_bih = (const float*)d_in[20];
    const float* gnn_gru_bhh = (const float*)d_in[21];
    const float* pred_W = (const float*)d_in[22];
    const float* pred_b = (const float*)d_in[23];
    const int* src = (const int*)d_in[24];
    const int* dst = (const int*)d_in[25];
    const int* gid = (const int*)d_in[26];

    float* out_g = (float*)d_out;
    float* out_atom = out_g + NG_N;

    char* base = (char*)d_ws;
    size_t off = 0;
    auto take = [&](size_t bytes) -> void* {
        void* p = base + off;
        off += (bytes + 255) & ~(size_t)255;
        return p;
    };
    const size_t VP = (size_t)V_N * LDA;
    const size_t WPL = (size_t)7 * 14 * 3072;
    float* mask   = (float*)take((size_t)V_N * 4);
    float* logits = (float*)take((size_t)E_N * 4);
    float* aw     = (float*)take((size_t)E_N * 4);
    float* hedot  = (float*)take((size_t)E_N * 4);
    float* s1     = (float*)take((size_t)V_N * 4);
    float* s2     = (float*)take((size_t)V_N * 4);
    float* gsum   = (float*)take((size_t)NG_N * 4);
    __hip_bfloat16* c    = (__hip_bfloat16*)take(VP * 2);
    __hip_bfloat16* hv   = (__hip_bfloat16*)take(VP * 2);
    __hip_bfloat16* nf_a = (__hip_bfloat16*)take(VP * 2);
    __hip_bfloat16* nf_b = (__hip_bfloat16*)take(VP * 2);
    short* WpGru = (short*)take(3 * WPL * 2);
    short* Wp_pn0 = (short*)take((size_t)256 * 96 * 2);
    short* Wp_pe1 = (short*)take((size_t)256 * 96 * 2);
    short* Wp_et  = (short*)take((size_t)7 * 7 * 1024 * 2);
    short* Wp_pn1 = (short*)take((size_t)7 * 7 * 1024 * 2);
    short* Wp_pn2 = (short*)take((size_t)7 * 7 * 1024 * 2);
    int* deg  = (int*)take((size_t)V_N * 4);
    int* cnt  = (int*)take((size_t)V_N * 4);
    int* rp   = (int*)take((size_t)(V_N + 1) * 4);
    int* perm = (int*)take((size_t)E_N * 4);
    int* bsum = (int*)take((size_t)512 * 4);
    __hip_bfloat16* P    = nf_a;  // alias: nf_a written only at GRU0
    __hip_bfloat16* hbar = nf_b;  // alias: nf_b first written as layer-0 GRU output
    __hip_bfloat16* hvp  = hv;    // alias: hv dead after GRU0

    if (off > ws_size) {
        fill_kernel<<<cdiv(out_size, 256), 256, 0, stream>>>((float*)d_out, -12345.f, out_size);
        return;
    }

    const int BLK = 256;
    const int nScanBlocks = cdiv(V_N, 256);
    const dim3 gOld(4, cdiv(V_N, 64));
    const int gAgg = cdiv(V_N, 4);

    // zero-fill padded node matrices (pads must be 0 for GEMM/GRU K-loops)
    {
        int nFloats = (int)(4 * VP * 2 / 4);
        fill_kernel<<<cdiv(nFloats, BLK), BLK, 0, stream>>>((float*)c, 0.f, nFloats);
    }

    // ---- weight prep ----
    gru_wprep_kernel<<<cdiv(7 * 14 * 3072, 256), BLK, 0, stream>>>(gru0_Wih, gru0_Whh, WpGru);
    for (int l = 0; l < L_N; l++)
        gru_wprep_kernel<<<cdiv(7 * 14 * 3072, 256), BLK, 0, stream>>>(
            gnn_gru_Wih + (size_t)l * G_DIM * 3 * G_DIM,
            gnn_gru_Whh + (size_t)l * G_DIM * 3 * G_DIM,
            WpGru + (size_t)(l + 1) * WPL);
    wprep_kernel<<<cdiv(256 * 96, 256), BLK, 0, stream>>>(pn_W, Wp_pn0, NFEAT, 96);
    wprep_kernel<<<cdiv(256 * 96, 256), BLK, 0, stream>>>(pe1_W, Wp_pe1, NFEAT, 96);
    wprep_tiled_kernel<<<cdiv(7 * 7 * 1024, 256), BLK, 0, stream>>>(et_W, Wp_et);
    wprep_tiled_kernel<<<cdiv(7 * 7 * 1024, 256), BLK, 0, stream>>>(gnn_pn_W, Wp_pn1);
    wprep_tiled_kernel<<<cdiv(7 * 7 * 1024, 256), BLK, 0, stream>>>(
        gnn_pn_W + (size_t)G_DIM * G_DIM, Wp_pn2);

    mask_kernel<<<cdiv(V_N, BLK), BLK, 0, stream>>>(node_feats, mask);

    // ---- CSR build (by dst) ----
    fill_int_kernel<<<cdiv(V_N, BLK), BLK, 0, stream>>>(deg, 0, V_N);
    hist_kernel<<<cdiv(E_N, BLK), BLK, 0, stream>>>(dst, deg);
    scan1_kernel<<<nScanBlocks, BLK, 0, stream>>>(deg, rp, bsum);
    scan2_kernel<<<1, 1, 0, stream>>>(bsum, rp, nScanBlocks);
    scan3_kernel<<<nScanBlocks, BLK, 0, stream>>>(rp, bsum);
    fill_int_kernel<<<cdiv(V_N, BLK), BLK, 0, stream>>>(cnt, 0, V_N);
    csr_fill_kernel<<<cdiv(E_N, BLK), BLK, 0, stream>>>(dst, rp, cnt, perm);

    // ---- GetContext ----
    // hv + P in one node_feats pass
    gemm_f32a_dual_kernel<<<gOld, BLK, 0, stream>>>(
        node_feats, Wp_pn0, pn_b, Wp_pe1, pe1_b, hv, P);
    node_dot2_kernel<<<gAgg, BLK, 0, stream>>>(hv, pe2_W, nullptr, s1, nullptr);
    ctx_hedot_kernel<<<cdiv(E_N, 8), BLK, 0, stream>>>(
        P, edge_feats, src, pe1_W, pe2_W, hedot);
    edge_combine_kernel<<<cdiv(E_N, BLK), BLK, 0, stream>>>(
        s1, dst, nullptr, src, hedot, pe2_b, logits);
    softmax_csr_kernel<<<cdiv(V_N, BLK), BLK, 0, stream>>>(logits, rp, perm, aw);
    ctx_agg_kernel<<<gAgg, BLK, 0, stream>>>(P, edge_feats, src, rp, perm, aw, pe1_W, hbar);
    gemm_bf16a_kernel<3><<<NSWZ, BLK, 0, stream>>>(hbar, Wp_et, et_b, c);
    gru_mfma_kernel<<<NSWZ, BLK, 0, stream>>>(c, hv, WpGru, gru0_bih, gru0_bhh, nf_a);

    // ---- GNN layers ----
    __hip_bfloat16* cur = nf_a;
    __hip_bfloat16* nxt = nf_b;
    for (int l = 0; l < L_N; l++) {
        const float* pe_W = gnn_pe_W + (size_t)l * 2 * G_DIM;
        const float* pe_b = gnn_pe_b + l;
        const float* pnB  = gnn_pn_b + (size_t)l * G_DIM;
        const float* bih  = gnn_gru_bih + (size_t)l * 3 * G_DIM;
        const float* bhh  = gnn_gru_bhh + (size_t)l * 3 * G_DIM;
        const short* WpPn = (l == 0) ? Wp_pn1 : Wp_pn2;

        node_dot2_kernel<<<gAgg, BLK, 0, stream>>>(cur, pe_W, pe_W + G_DIM, s1, s2);
        edge_combine_kernel<<<cdiv(E_N, BLK), BLK, 0, stream>>>(
            s1, dst, s2, src, nullptr, pe_b, logits);
        softmax_csr_kernel<<<cdiv(V_N, BLK), BLK, 0, stream>>>(logits, rp, perm, aw);

        gemm_bf16a_kernel<1><<<NSWZ, BLK, 0, stream>>>(cur, WpPn, pnB, hvp);
        gnn_agg_kernel<<<gAgg, BLK, 0, stream>>>(hvp, src, rp, perm, aw, c);
        gru_mfma_kernel<<<NSWZ, BLK, 0, stream>>>(
            c, cur, WpGru + (size_t)(l + 1) * WPL, bih, bhh, nxt);

        __hip_bfloat16* tmp = cur; cur = nxt; nxt = tmp;
    }

    // ---- readout ----
    fill_kernel<<<cdiv(NG_N, BLK), BLK, 0, stream>>>(gsum, 0.f, NG_N);
    readout_kernel<<<cdiv(V_N * 64, BLK), BLK, 0, stream>>>(
        cur, pred_W, pred_b, mask, gid, out_atom, gsum);
    graph_out_kernel<<<cdiv(NG_N, BLK), BLK, 0, stream>>>(gsum, out_g);
}

// Round 9
// 1773.967 us; speedup vs baseline: 10.9298x; 1.1549x over previous
//
#include <hip/hip_runtime.h>
#include <hip/hip_bf16.h>
#include <math.h>

#define V_N    100000
#define E_N    400000
#define NFEAT  74
#define NEFEAT 12
#define G_DIM  200
#define LDA    224          // padded leading dim for all bf16 node matrices
#define L_N    2
#define NG_N   4000
#define NROWB  391          // cdiv(V_N,256)
#define NROWP  392          // padded to multiple of 8
#define NSWZ   (NROWP / 8 * 56)   // swizzled 1-D grid = 2744

static inline int cdiv(int a, int b) { return (a + b - 1) / b; }

__device__ __forceinline__ float lrelu_f(float x) { return x > 0.f ? x : 0.01f * x; }
__device__ __forceinline__ float sigmoid_f(float x) { return 1.f / (1.f + expf(-x)); }
__device__ __forceinline__ float elu_f(float x) { return x > 0.f ? x : expm1f(x); }
__device__ __forceinline__ float bf2f(__hip_bfloat16 x) { return __bfloat162float(x); }
__device__ __forceinline__ float bfbits2f(short s) {
    return __uint_as_float(((unsigned)(unsigned short)s) << 16);
}

__device__ __forceinline__ short f2bf(float f) {
    __hip_bfloat16 b = __float2bfloat16(f);
    short s;
    __builtin_memcpy(&s, &b, 2);
    return s;
}

typedef short short8 __attribute__((ext_vector_type(8)));
typedef short short4v __attribute__((ext_vector_type(4)));
typedef float f32x4 __attribute__((ext_vector_type(4)));

#define MFMA16(a, b, c) __builtin_amdgcn_mfma_f32_16x16x32_bf16((a), (b), (c), 0, 0, 0)

// XCD-aware swizzle: 7 cb-blocks of one row-tile land on the same XCD (lin%8)
__device__ __forceinline__ void swz_decode(int lin, int& rowBlk, int& cb)
{
    int grp = lin / 56;
    int rem = lin % 56;
    cb = rem >> 3;
    rowBlk = grp * 8 + (rem & 7);
}

// ---------------------------------------------------------------------------
__global__ __launch_bounds__(256)
void fill_kernel(float* __restrict__ p, float v, int n)
{
    int i = blockIdx.x * blockDim.x + threadIdx.x;
    if (i < n) p[i] = v;
}

__global__ __launch_bounds__(256)
void fill_int_kernel(int* __restrict__ p, int v, int n)
{
    int i = blockIdx.x * blockDim.x + threadIdx.x;
    if (i < n) p[i] = v;
}

// zero only the pad columns (k in [200,224)) of the 4 contiguous node matrices
__global__ __launch_bounds__(256)
void pad_zero_kernel(short* __restrict__ base, size_t VP)
{
    int idx = blockIdx.x * blockDim.x + threadIdx.x;
    if (idx >= 4 * V_N) return;
    int mat = idx / V_N, row = idx % V_N;
    short* p = base + (size_t)mat * VP + (long)row * LDA + G_DIM;
    short8 z = {};
    *(short8*)(p) = z;
    *(short8*)(p + 8) = z;
    *(short8*)(p + 16) = z;
}

// ---------------------------------------------------------------------------
// Weight preps
// ---------------------------------------------------------------------------
__global__ __launch_bounds__(256)
void wprep_kernel(const float* __restrict__ W, short* __restrict__ Wp, int K, int Kpad)
{
    int idx = blockIdx.x * 256 + threadIdx.x;
    if (idx >= 256 * Kpad) return;
    int j = idx / Kpad, k = idx % Kpad;
    float v = (j < G_DIM && k < K) ? W[(long)k * G_DIM + j] : 0.f;
    Wp[idx] = f2bf(v);
}

__global__ __launch_bounds__(256)
void wprep_tiled_kernel(const float* __restrict__ W, short* __restrict__ Wp)
{
    int idx = blockIdx.x * 256 + threadIdx.x;
    if (idx >= 7 * 7 * 1024) return;
    int cb = idx / (7 * 1024);
    int r = idx % (7 * 1024);
    int st = r / 1024;
    int r2 = r % 1024;
    int cc = r2 / 32, kk = r2 % 32;
    int col = cb * 32 + cc, k = st * 32 + kk;
    float v = (col < G_DIM && k < G_DIM) ? W[(long)k * G_DIM + col] : 0.f;
    Wp[idx] = f2bf(v);
}

__global__ __launch_bounds__(256)
void gru_wprep_kernel(const float* __restrict__ Wih, const float* __restrict__ Whh,
                      short* __restrict__ Wp)
{
    int idx = blockIdx.x * 256 + threadIdx.x;
    if (idx >= 7 * 14 * 3072) return;
    int cb = idx / (14 * 3072);
    int r = idx % (14 * 3072);
    int st = r / 3072;
    int r2 = r % 3072;
    int g = r2 / 1024;
    int r3 = r2 % 1024;
    int cc = r3 / 32, kk = r3 % 32;
    int col = cb * 32 + cc;
    float v = 0.f;
    if (col < G_DIM) {
        if (st < 7) {
            int k = st * 32 + kk;
            if (k < G_DIM) v = Wih[(long)k * (3 * G_DIM) + g * G_DIM + col];
        } else {
            int k = (st - 7) * 32 + kk;
            if (k < G_DIM) v = Whh[(long)k * (3 * G_DIM) + g * G_DIM + col];
        }
    }
    Wp[idx] = f2bf(v);
}

// ---------------------------------------------------------------------------
// CSR build
// ---------------------------------------------------------------------------
__global__ __launch_bounds__(256)
void hist_kernel(const int* __restrict__ dst, int* __restrict__ deg)
{
    int e = blockIdx.x * blockDim.x + threadIdx.x;
    if (e >= E_N) return;
    atomicAdd(&deg[dst[e]], 1);
}

__global__ __launch_bounds__(256)
void scan1_kernel(const int* __restrict__ deg, int* __restrict__ rp, int* __restrict__ bsum)
{
    __shared__ int s[256];
    int tid = threadIdx.x;
    int v = blockIdx.x * 256 + tid;
    int x = (v < V_N) ? deg[v] : 0;
    s[tid] = x;
    __syncthreads();
    for (int off = 1; off < 256; off <<= 1) {
        int t = (tid >= off) ? s[tid - off] : 0;
        __syncthreads();
        s[tid] += t;
        __syncthreads();
    }
    if (v < V_N) rp[v] = s[tid] - x;
    if (tid == 255) bsum[blockIdx.x] = s[255];
}

__global__ void scan2_kernel(int* __restrict__ bsum, int* __restrict__ rp, int nb)
{
    if (threadIdx.x != 0 || blockIdx.x != 0) return;
    int acc = 0;
    for (int b = 0; b < nb; b++) { int t = bsum[b]; bsum[b] = acc; acc += t; }
    rp[V_N] = acc;
}

__global__ __launch_bounds__(256)
void scan3_kernel(int* __restrict__ rp, const int* __restrict__ bsum)
{
    int v = blockIdx.x * 256 + threadIdx.x;
    if (v < V_N) rp[v] += bsum[v >> 8];
}

__global__ __launch_bounds__(256)
void csr_fill_kernel(const int* __restrict__ dst, const int* __restrict__ rp,
                     int* __restrict__ cnt, int* __restrict__ perm)
{
    int e = blockIdx.x * blockDim.x + threadIdx.x;
    if (e >= E_N) return;
    int d = dst[e];
    int pos = rp[d] + atomicAdd(&cnt[d], 1);
    perm[pos] = e;
}

// ---------------------------------------------------------------------------
// Dual 64x64 MFMA GEMM for fp32-A (K=74 pad 96): hv AND P in one A pass
// ---------------------------------------------------------------------------
__global__ __launch_bounds__(256)
void gemm_f32a_dual_kernel(const float* __restrict__ Af32,
                           const short* __restrict__ Wp1, const float* __restrict__ b1,
                           const short* __restrict__ Wp2, const float* __restrict__ b2,
                           __hip_bfloat16* __restrict__ C1,
                           __hip_bfloat16* __restrict__ C2)
{
    __shared__ short As[64 * 40];
    __shared__ short Bs1[64 * 40];
    __shared__ short Bs2[64 * 40];
    const int tid = threadIdx.x;
    const int lane = tid & 63;
    const int w = tid >> 6;
    const int quad = lane >> 4;
    const int lm = lane & 15;
    const int rowBase = blockIdx.y * 64;
    const int j0 = blockIdx.x * 64;
    const int arow = tid >> 2;
    const int akc = (tid & 3) * 8;
    const int agrow = rowBase + arow;

    f32x4 acc1[4] = {}, acc2[4] = {};

    for (int k0 = 0; k0 < 96; k0 += 32) {
        short8 av = {};
        if (agrow < V_N) {
            int gk = k0 + akc;
            #pragma unroll
            for (int i = 0; i < 8; i++) {
                int kg = gk + i;
                av[i] = (kg < NFEAT) ? f2bf(Af32[(long)agrow * NFEAT + kg]) : (short)0;
            }
        }
        *(short8*)&As[arow * 40 + akc] = av;
        {
            int col = tid >> 2;
            *(short8*)&Bs1[col * 40 + akc] =
                *(const short8*)(Wp1 + (long)(j0 + col) * 96 + k0 + akc);
            *(short8*)&Bs2[col * 40 + akc] =
                *(const short8*)(Wp2 + (long)(j0 + col) * 96 + k0 + akc);
        }
        __syncthreads();
        short8 a = *(short8*)&As[(w * 16 + lm) * 40 + quad * 8];
        #pragma unroll
        for (int nt = 0; nt < 4; nt++) {
            short8 bb1 = *(short8*)&Bs1[(nt * 16 + lm) * 40 + quad * 8];
            short8 bb2 = *(short8*)&Bs2[(nt * 16 + lm) * 40 + quad * 8];
            acc1[nt] = MFMA16(a, bb1, acc1[nt]);
            acc2[nt] = MFMA16(a, bb2, acc2[nt]);
        }
        __syncthreads();
    }

    #pragma unroll
    for (int nt = 0; nt < 4; nt++) {
        int col = j0 + nt * 16 + lm;
        if (col >= G_DIM) continue;
        float bv1 = b1[col], bv2 = b2[col];
        #pragma unroll
        for (int r = 0; r < 4; r++) {
            int grow = rowBase + w * 16 + quad * 4 + r;
            if (grow >= V_N) continue;
            C1[(long)grow * LDA + col] = __float2bfloat16(lrelu_f(acc1[nt][r] + bv1));
            C2[(long)grow * LDA + col] = __float2bfloat16(acc2[nt][r] + bv2);
        }
    }
}

// ---------------------------------------------------------------------------
// 256x32 MFMA GEMM, bf16 A [V][LDA], K=224, Wp tiled; XCD-swizzled grid
// ---------------------------------------------------------------------------
template<int EPI>   // 1 = bias only, 3 = elu
__global__ __launch_bounds__(256)
void gemm_bf16a_kernel(const __hip_bfloat16* __restrict__ Abf,
                       const short* __restrict__ Wp,
                       const float* __restrict__ bias,
                       __hip_bfloat16* __restrict__ Cbf)
{
    __shared__ short As[256 * 32];
    __shared__ short Bs[32 * 32];
    int rowBlk, cb;
    swz_decode(blockIdx.x, rowBlk, cb);
    if (rowBlk >= NROWB) return;
    const int tid = threadIdx.x;
    const int lane = tid & 63;
    const int w = tid >> 6;
    const int quad = lane >> 4;
    const int lm = lane & 15;
    const int j0 = cb * 32;
    const int rowBase = rowBlk * 256;
    const int sRow = tid >> 2;
    const int sChunk = (tid & 3) * 8;

    const short* WpB = Wp + (long)cb * (7 * 1024);
    f32x4 acc[4][2] = {};

    #pragma unroll 1
    for (int st = 0; st < 7; st++) {
        int kl = st * 32;
        #pragma unroll
        for (int p = 0; p < 4; p++) {
            int r = sRow + p * 64;
            int gr = rowBase + r;
            short8 v = {};
            if (gr < V_N) v = *(const short8*)((const short*)Abf + (long)gr * LDA + kl + sChunk);
            *(short8*)&As[r * 32 + sChunk] = v;
        }
        if (tid < 128)
            *(short8*)&Bs[tid * 8] = *(const short8*)(WpB + st * 1024 + tid * 8);
        __syncthreads();
        short8 b0 = *(short8*)&Bs[(0 * 16 + lm) * 32 + quad * 8];
        short8 b1 = *(short8*)&Bs[(1 * 16 + lm) * 32 + quad * 8];
        #pragma unroll
        for (int rt = 0; rt < 4; rt++) {
            short8 a = *(short8*)&As[(w * 64 + rt * 16 + lm) * 32 + quad * 8];
            acc[rt][0] = MFMA16(a, b0, acc[rt][0]);
            acc[rt][1] = MFMA16(a, b1, acc[rt][1]);
        }
        __syncthreads();
    }

    #pragma unroll
    for (int nt = 0; nt < 2; nt++) {
        int col = j0 + nt * 16 + lm;
        if (col >= G_DIM) continue;
        float bv = bias[col];
        #pragma unroll
        for (int rt = 0; rt < 4; rt++) {
            #pragma unroll
            for (int r = 0; r < 4; r++) {
                int grow = rowBase + w * 64 + rt * 16 + quad * 4 + r;
                if (grow >= V_N) continue;
                float v = acc[rt][nt][r] + bv;
                if (EPI == 3) v = elu_f(v);
                Cbf[(long)grow * LDA + col] = __float2bfloat16(v);
            }
        }
    }
}

// ---------------------------------------------------------------------------
// Fused MFMA GRU; XCD-swizzled grid
// ---------------------------------------------------------------------------
__global__ __launch_bounds__(256)
void gru_mfma_kernel(const __hip_bfloat16* __restrict__ xc,
                     const __hip_bfloat16* __restrict__ h,
                     const short* __restrict__ Wp,
                     const float* __restrict__ bih, const float* __restrict__ bhh,
                     __hip_bfloat16* __restrict__ out)
{
    __shared__ short As[256 * 32];
    __shared__ short Bs[3 * 32 * 32];
    int rowBlk, cb;
    swz_decode(blockIdx.x, rowBlk, cb);
    if (rowBlk >= NROWB) return;
    const int tid = threadIdx.x;
    const int lane = tid & 63;
    const int w = tid >> 6;
    const int quad = lane >> 4;
    const int lm = lane & 15;
    const int j0 = cb * 32;
    const int rowBase = rowBlk * 256;
    const int sRow = tid >> 2;
    const int sChunk = (tid & 3) * 8;

    const short* WpB = Wp + (long)cb * (14 * 3072);

    f32x4 aR[4][2] = {}, aZ[4][2] = {}, aNl[4][2] = {}, aNh[4][2] = {};

    #pragma unroll 1
    for (int st = 0; st < 14; st++) {
        const short* Aptr = (st < 7) ? (const short*)xc : (const short*)h;
        int kl = (st < 7 ? st : st - 7) * 32;
        #pragma unroll
        for (int p = 0; p < 4; p++) {
            int r = sRow + p * 64;
            int gr = rowBase + r;
            short8 v = {};
            if (gr < V_N) v = *(const short8*)(Aptr + (long)gr * LDA + kl + sChunk);
            *(short8*)&As[r * 32 + sChunk] = v;
        }
        {
            const short* bs = WpB + st * 3072;
            *(short8*)&Bs[tid * 8] = *(const short8*)(bs + tid * 8);
            if (tid < 128)
                *(short8*)&Bs[(tid + 256) * 8] = *(const short8*)(bs + (tid + 256) * 8);
        }
        __syncthreads();
        short8 br[2], bz[2], bn[2];
        #pragma unroll
        for (int nt = 0; nt < 2; nt++) {
            br[nt] = *(short8*)&Bs[(0 * 32 + nt * 16 + lm) * 32 + quad * 8];
            bz[nt] = *(short8*)&Bs[(1 * 32 + nt * 16 + lm) * 32 + quad * 8];
            bn[nt] = *(short8*)&Bs[(2 * 32 + nt * 16 + lm) * 32 + quad * 8];
        }
        #pragma unroll
        for (int rt = 0; rt < 4; rt++) {
            short8 a = *(short8*)&As[(w * 64 + rt * 16 + lm) * 32 + quad * 8];
            #pragma unroll
            for (int nt = 0; nt < 2; nt++) {
                aR[rt][nt] = MFMA16(a, br[nt], aR[rt][nt]);
                aZ[rt][nt] = MFMA16(a, bz[nt], aZ[rt][nt]);
                if (st < 7) aNl[rt][nt] = MFMA16(a, bn[nt], aNl[rt][nt]);
                else        aNh[rt][nt] = MFMA16(a, bn[nt], aNh[rt][nt]);
            }
        }
        __syncthreads();
    }

    #pragma unroll
    for (int nt = 0; nt < 2; nt++) {
        int col = j0 + nt * 16 + lm;
        if (col >= G_DIM) continue;
        float b_ir = bih[col], b_iz = bih[G_DIM + col], b_in = bih[2 * G_DIM + col];
        float b_hr = bhh[col], b_hz = bhh[G_DIM + col], b_hn = bhh[2 * G_DIM + col];
        #pragma unroll
        for (int rt = 0; rt < 4; rt++) {
            #pragma unroll
            for (int r = 0; r < 4; r++) {
                int grow = rowBase + w * 64 + rt * 16 + quad * 4 + r;
                if (grow >= V_N) continue;
                float sr = aR[rt][nt][r] + b_ir + b_hr;
                float sz = aZ[rt][nt][r] + b_iz + b_hz;
                float gin = aNl[rt][nt][r] + b_in;
                float ghn = aNh[rt][nt][r] + b_hn;
                float rr = sigmoid_f(sr);
                float zz = sigmoid_f(sz);
                float nn = tanhf(gin + rr * ghn);
                float hval = bf2f(h[(long)grow * LDA + col]);
                float o = (1.f - zz) * nn + zz * hval;
                out[(long)grow * LDA + col] = __float2bfloat16(o > 0.f ? o : 0.f);
            }
        }
    }
}

// ---------------------------------------------------------------------------
// Node dot(s): s1[v] = X[v]·wa (+ s2[v] = X[v]·wb). Wave per node, vectorized.
// ---------------------------------------------------------------------------
__global__ __launch_bounds__(256)
void node_dot2_kernel(const __hip_bfloat16* __restrict__ X,
                      const float* __restrict__ wa, const float* __restrict__ wb,
                      float* __restrict__ s1, float* __restrict__ s2)
{
    int w = threadIdx.x >> 6, lane = threadIdx.x & 63;
    int v = blockIdx.x * 4 + w;
    if (v >= V_N) return;
    int vlane = (lane < 50) ? lane : 0;
    short4v pv = *(const short4v*)((const short*)X + (long)v * LDA + vlane * 4);
    f32x4 wav = *(const f32x4*)(wa + vlane * 4);
    float a = 0.f, b = 0.f;
    #pragma unroll
    for (int u = 0; u < 4; u++) a += bfbits2f(pv[u]) * wav[u];
    if (wb) {
        f32x4 wbv = *(const f32x4*)(wb + vlane * 4);
        #pragma unroll
        for (int u = 0; u < 4; u++) b += bfbits2f(pv[u]) * wbv[u];
    }
    if (lane >= 50) { a = 0.f; b = 0.f; }
    for (int off = 32; off > 0; off >>= 1) {
        a += __shfl_down(a, off, 64);
        if (wb) b += __shfl_down(b, off, 64);
    }
    if (lane == 0) {
        s1[v] = a;
        if (wb) s2[v] = b;
    }
}

// ---------------------------------------------------------------------------
// Ctx logits (he1 on the fly, vectorized): 2 edges per wave, 8 per block.
// logits[e] = lrelu( s1[dst] + sum_k lrelu(P[src][k]+Q[e][k])*pe2W[200+k] + b )
// ---------------------------------------------------------------------------
__global__ __launch_bounds__(256)
void ctx_logits_kernel(const __hip_bfloat16* __restrict__ P,
                       const float* __restrict__ efeat,
                       const int* __restrict__ src, const int* __restrict__ dst,
                       const float* __restrict__ s1,
                       const float* __restrict__ pe1W,
                       const float* __restrict__ pe2W, const float* __restrict__ pe2b,
                       float* __restrict__ logits)
{
    __shared__ float Wef[NEFEAT * G_DIM];
    __shared__ float w2s[G_DIM];
    const int tid = threadIdx.x;
    for (int i = tid; i < NEFEAT * G_DIM; i += 256) {
        int j = i / G_DIM, k = i % G_DIM;
        Wef[i] = pe1W[(long)(NFEAT + j) * G_DIM + k];
    }
    for (int i = tid; i < G_DIM; i += 256) w2s[i] = pe2W[G_DIM + i];
    __syncthreads();
    const f32x4* Wef4 = (const f32x4*)Wef;
    const f32x4* w2s4 = (const f32x4*)w2s;
    const int w = tid >> 6, lane = tid & 63;
    const int vlane = (lane < 50) ? lane : 0;
    const int e0 = (blockIdx.x * 4 + w) * 2;
    #pragma unroll
    for (int u = 0; u < 2; u++) {
        int e = e0 + u;
        if (e >= E_N) break;
        int s = src[e];
        float efv = (lane < NEFEAT) ? efeat[(long)e * NEFEAT + lane] : 0.f;
        f32x4 q = {};
        #pragma unroll
        for (int j = 0; j < NEFEAT; j++) {
            float ej = __shfl(efv, j, 64);
            f32x4 wv = Wef4[j * 50 + vlane];
            q += ej * wv;
        }
        short4v pv = *(const short4v*)((const short*)P + (long)s * LDA + vlane * 4);
        f32x4 wv2 = w2s4[vlane];
        float acc = 0.f;
        #pragma unroll
        for (int c = 0; c < 4; c++)
            acc += lrelu_f(bfbits2f(pv[c]) + q[c]) * wv2[c];
        if (lane >= 50) acc = 0.f;
        for (int off = 32; off > 0; off >>= 1) acc += __shfl_down(acc, off, 64);
        if (lane == 0) logits[e] = lrelu_f(acc + s1[dst[e]] + pe2b[0]);
    }
}

// ---------------------------------------------------------------------------
// Ctx fused softmax+agg: hbar[v] = softmax-weighted sum of he1 (on the fly).
// Online softmax; wave per node; vectorized gathers.
// ---------------------------------------------------------------------------
__global__ __launch_bounds__(256)
void ctx_fused_agg_kernel(const __hip_bfloat16* __restrict__ P,
                          const float* __restrict__ efeat,
                          const int* __restrict__ src,
                          const int* __restrict__ rp, const int* __restrict__ perm,
                          const float* __restrict__ logits,
                          const float* __restrict__ pe1W,
                          __hip_bfloat16* __restrict__ hbar)
{
    __shared__ float Wef[NEFEAT * G_DIM];
    const int tid = threadIdx.x;
    for (int i = tid; i < NEFEAT * G_DIM; i += 256) {
        int j = i / G_DIM, k = i % G_DIM;
        Wef[i] = pe1W[(long)(NFEAT + j) * G_DIM + k];
    }
    __syncthreads();
    const f32x4* Wef4 = (const f32x4*)Wef;
    const int w = tid >> 6, lane = tid & 63;
    const int vlane = (lane < 50) ? lane : 0;
    int v = blockIdx.x * 4 + w;
    if (v >= V_N) return;
    int b = rp[v], en = rp[v + 1];
    f32x4 a = {};
    float m = -INFINITY, s = 0.f;
    for (int cb0 = b; cb0 < en; cb0 += 64) {
        int i = cb0 + lane;
        int e = 0, sE = 0;
        float l = -INFINITY;
        if (i < en) { e = perm[i]; sE = src[e]; l = logits[e]; }
        float lmax = l;
        for (int off = 32; off > 0; off >>= 1) lmax = fmaxf(lmax, __shfl_xor(lmax, off, 64));
        float m_new = fmaxf(m, lmax);
        float scale = expf(m - m_new);
        s *= scale; a *= scale;
        float wgt = (i < en) ? expf(l - m_new) : 0.f;
        float wsum = wgt;
        for (int off = 32; off > 0; off >>= 1) wsum += __shfl_xor(wsum, off, 64);
        s += wsum;
        int cnt = min(64, en - cb0);
        for (int t = 0; t < cnt; t++) {
            int eT = __shfl(e, t, 64);
            int sT = __shfl(sE, t, 64);
            float wT = __shfl(wgt, t, 64);
            float efv = (lane < NEFEAT) ? efeat[(long)eT * NEFEAT + lane] : 0.f;
            f32x4 q = {};
            #pragma unroll
            for (int j = 0; j < NEFEAT; j++) {
                float ej = __shfl(efv, j, 64);
                f32x4 wv = Wef4[j * 50 + vlane];
                q += ej * wv;
            }
            short4v pv = *(const short4v*)((const short*)P + (long)sT * LDA + vlane * 4);
            #pragma unroll
            for (int u = 0; u < 4; u++)
                a[u] += wT * lrelu_f(bfbits2f(pv[u]) + q[u]);
        }
        m = m_new;
    }
    float inv = (s > 0.f) ? 1.f / s : 0.f;
    if (lane < 50) {
        short4v o;
        #pragma unroll
        for (int u = 0; u < 4; u++) o[u] = f2bf(a[u] * inv);
        *(short4v*)((short*)hbar + (long)v * LDA + lane * 4) = o;
    }
}

// ---------------------------------------------------------------------------
// GNN fused softmax+agg: c[v] = elu(softmax-weighted sum of hvp[src]).
// logits computed inline from s1/s2. Online softmax; wave per node.
// ---------------------------------------------------------------------------
__global__ __launch_bounds__(256)
void gnn_fused_agg_kernel(const __hip_bfloat16* __restrict__ X,
                          const int* __restrict__ src,
                          const int* __restrict__ rp, const int* __restrict__ perm,
                          const float* __restrict__ s1, const float* __restrict__ s2,
                          const float* __restrict__ bias,
                          __hip_bfloat16* __restrict__ out)
{
    const int tid = threadIdx.x;
    const int w = tid >> 6, lane = tid & 63;
    const int vlane = (lane < 50) ? lane : 0;
    int v = blockIdx.x * 4 + w;
    if (v >= V_N) return;
    int b = rp[v], en = rp[v + 1];
    float s1v = s1[v] + bias[0];
    f32x4 a = {};
    float m = -INFINITY, s = 0.f;
    for (int cb0 = b; cb0 < en; cb0 += 64) {
        int i = cb0 + lane;
        int sE = 0;
        float l = -INFINITY;
        if (i < en) { int e = perm[i]; sE = src[e]; l = lrelu_f(s1v + s2[sE]); }
        float lmax = l;
        for (int off = 32; off > 0; off >>= 1) lmax = fmaxf(lmax, __shfl_xor(lmax, off, 64));
        float m_new = fmaxf(m, lmax);
        float scale = expf(m - m_new);
        s *= scale; a *= scale;
        float wgt = (i < en) ? expf(l - m_new) : 0.f;
        float wsum = wgt;
        for (int off = 32; off > 0; off >>= 1) wsum += __shfl_xor(wsum, off, 64);
        s += wsum;
        int cnt = min(64, en - cb0);
        for (int t = 0; t < cnt; t++) {
            int sT = __shfl(sE, t, 64);
            float wT = __shfl(wgt, t, 64);
            short4v pv = *(const short4v*)((const short*)X + (long)sT * LDA + vlane * 4);
            #pragma unroll
            for (int u = 0; u < 4; u++)
                a[u] += wT * bfbits2f(pv[u]);
        }
        m = m_new;
    }
    float inv = (s > 0.f) ? 1.f / s : 0.f;
    if (lane < 50) {
        short4v o;
        #pragma unroll
        for (int u = 0; u < 4; u++) o[u] = f2bf(elu_f(a[u] * inv));
        *(short4v*)((short*)out + (long)v * LDA + lane * 4) = o;
    }
}

// ---------------------------------------------------------------------------
// readout
// ---------------------------------------------------------------------------
__global__ __launch_bounds__(256)
void mask_kernel(const float* __restrict__ nfeat, float* __restrict__ mask)
{
    int v = blockIdx.x * blockDim.x + threadIdx.x;
    if (v >= V_N) return;
    const float* row = nfeat + (long)v * NFEAT;
    float s = row[NFEAT - 4] + row[NFEAT - 3] + row[NFEAT - 2] + row[NFEAT - 1];
    float m = s * (1.f - row[0]);
    mask[v] = 1.f / m - 1.f;
}

__global__ __launch_bounds__(256)
void readout_kernel(const __hip_bfloat16* __restrict__ nf, const float* __restrict__ predW,
                    const float* __restrict__ predb, const float* __restrict__ mask,
                    const int* __restrict__ gid, float* __restrict__ out_atom,
                    float* __restrict__ gsum)
{
    int gtid = blockIdx.x * blockDim.x + threadIdx.x;
    int v = gtid >> 6, lane = gtid & 63;
    if (v >= V_N) return;
    int vlane = (lane < 50) ? lane : 0;
    short4v pv = *(const short4v*)((const short*)nf + (long)v * LDA + vlane * 4);
    f32x4 wv = *(const f32x4*)(predW + vlane * 4);
    float acc = 0.f;
    #pragma unroll
    for (int u = 0; u < 4; u++) acc += bfbits2f(pv[u]) * wv[u];
    if (lane >= 50) acc = 0.f;
    for (int off = 32; off > 0; off >>= 1) acc += __shfl_down(acc, off, 64);
    if (lane == 0) {
        float p = acc + predb[0] + mask[v];
        out_atom[v] = p;
        atomicAdd(&gsum[gid[v]], exp10f(-p));
    }
}

__global__ __launch_bounds__(256)
void graph_out_kernel(const float* __restrict__ gsum, float* __restrict__ out_g)
{
    int g = blockIdx.x * blockDim.x + threadIdx.x;
    if (g >= NG_N) return;
    out_g[g] = -log10f(gsum[g]);
}

// ---------------------------------------------------------------------------
extern "C" void kernel_launch(void* const* d_in, const int* in_sizes, int n_in,
                              void* d_out, int out_size, void* d_ws, size_t ws_size,
                              hipStream_t stream)
{
    const float* node_feats = (const float*)d_in[0];
    const float* edge_feats = (const float*)d_in[1];
    const float* pn_W  = (const float*)d_in[2];
    const float* pn_b  = (const float*)d_in[3];
    const float* pe1_W = (const float*)d_in[4];
    const float* pe1_b = (const float*)d_in[5];
    const float* pe2_W = (const float*)d_in[6];
    const float* pe2_b = (const float*)d_in[7];
    const float* et_W  = (const float*)d_in[8];
    const float* et_b  = (const float*)d_in[9];
    const float* gru0_Wih = (const float*)d_in[10];
    const float* gru0_Whh = (const float*)d_in[11];
    const float* gru0_bih = (const float*)d_in[12];
    const float* gru0_bhh = (const float*)d_in[13];
    const float* gnn_pe_W = (const float*)d_in[14];
    const float* gnn_pe_b = (const float*)d_in[15];
    const float* gnn_pn_W = (const float*)d_in[16];
    const float* gnn_pn_b = (const float*)d_in[17];
    const float* gnn_gru_Wih = (const float*)d_in[18];
    const float* gnn_gru_Whh = (const float*)d_in[19];
    const float* gnn_gru_bih = (const float*)d_in[20];
    const float* gnn_gru_bhh = (const float*)d_in[21];
    const float* pred_W = (const float*)d_in[22];
    const float* pred_b = (const float*)d_in[23];
    const int* src = (const int*)d_in[24];
    const int* dst = (const int*)d_in[25];
    const int* gid = (const int*)d_in[26];

    float* out_g = (float*)d_out;
    float* out_atom = out_g + NG_N;

    char* base = (char*)d_ws;
    size_t off = 0;
    auto take = [&](size_t bytes) -> void* {
        void* p = base + off;
        off += (bytes + 255) & ~(size_t)255;
        return p;
    };
    const size_t VP = (size_t)V_N * LDA;
    const size_t WPL = (size_t)7 * 14 * 3072;
    float* mask   = (float*)take((size_t)V_N * 4);
    float* logits = (float*)take((size_t)E_N * 4);
    float* s1     = (float*)take((size_t)V_N * 4);
    float* s2     = (float*)take((size_t)V_N * 4);
    float* gsum   = (float*)take((size_t)NG_N * 4);
    __hip_bfloat16* c    = (__hip_bfloat16*)take(VP * 2);
    __hip_bfloat16* hv   = (__hip_bfloat16*)take(VP * 2);
    __hip_bfloat16* nf_a = (__hip_bfloat16*)take(VP * 2);
    __hip_bfloat16* nf_b = (__hip_bfloat16*)take(VP * 2);
    short* WpGru = (short*)take(3 * WPL * 2);
    short* Wp_pn0 = (short*)take((size_t)256 * 96 * 2);
    short* Wp_pe1 = (short*)take((size_t)256 * 96 * 2);
    short* Wp_et  = (short*)take((size_t)7 * 7 * 1024 * 2);
    short* Wp_pn1 = (short*)take((size_t)7 * 7 * 1024 * 2);
    short* Wp_pn2 = (short*)take((size_t)7 * 7 * 1024 * 2);
    int* deg  = (int*)take((size_t)V_N * 4);
    int* cnt  = (int*)take((size_t)V_N * 4);
    int* rp   = (int*)take((size_t)(V_N + 1) * 4);
    int* perm = (int*)take((size_t)E_N * 4);
    int* bsum = (int*)take((size_t)512 * 4);
    __hip_bfloat16* P    = nf_a;  // alias: nf_a written only at GRU0
    __hip_bfloat16* hbar = nf_b;  // alias: nf_b first written as layer-0 GRU output
    __hip_bfloat16* hvp  = hv;    // alias: hv dead after GRU0

    if (off > ws_size) {
        fill_kernel<<<cdiv(out_size, 256), 256, 0, stream>>>((float*)d_out, -12345.f, out_size);
        return;
    }

    const int BLK = 256;
    const int nScanBlocks = cdiv(V_N, 256);
    const dim3 gOld(4, cdiv(V_N, 64));
    const int gAgg = cdiv(V_N, 4);

    // zero only the pad columns of the 4 contiguous node matrices
    pad_zero_kernel<<<cdiv(4 * V_N, BLK), BLK, 0, stream>>>((short*)c, VP);

    // ---- weight prep ----
    gru_wprep_kernel<<<cdiv(7 * 14 * 3072, 256), BLK, 0, stream>>>(gru0_Wih, gru0_Whh, WpGru);
    for (int l = 0; l < L_N; l++)
        gru_wprep_kernel<<<cdiv(7 * 14 * 3072, 256), BLK, 0, stream>>>(
            gnn_gru_Wih + (size_t)l * G_DIM * 3 * G_DIM,
            gnn_gru_Whh + (size_t)l * G_DIM * 3 * G_DIM,
            WpGru + (size_t)(l + 1) * WPL);
    wprep_kernel<<<cdiv(256 * 96, 256), BLK, 0, stream>>>(pn_W, Wp_pn0, NFEAT, 96);
    wprep_kernel<<<cdiv(256 * 96, 256), BLK, 0, stream>>>(pe1_W, Wp_pe1, NFEAT, 96);
    wprep_tiled_kernel<<<cdiv(7 * 7 * 1024, 256), BLK, 0, stream>>>(et_W, Wp_et);
    wprep_tiled_kernel<<<cdiv(7 * 7 * 1024, 256), BLK, 0, stream>>>(gnn_pn_W, Wp_pn1);
    wprep_tiled_kernel<<<cdiv(7 * 7 * 1024, 256), BLK, 0, stream>>>(
        gnn_pn_W + (size_t)G_DIM * G_DIM, Wp_pn2);

    mask_kernel<<<cdiv(V_N, BLK), BLK, 0, stream>>>(node_feats, mask);

    // ---- CSR build (by dst) ----
    fill_int_kernel<<<cdiv(V_N, BLK), BLK, 0, stream>>>(deg, 0, V_N);
    hist_kernel<<<cdiv(E_N, BLK), BLK, 0, stream>>>(dst, deg);
    scan1_kernel<<<nScanBlocks, BLK, 0, stream>>>(deg, rp, bsum);
    scan2_kernel<<<1, 1, 0, stream>>>(bsum, rp, nScanBlocks);
    scan3_kernel<<<nScanBlocks, BLK, 0, stream>>>(rp, bsum);
    fill_int_kernel<<<cdiv(V_N, BLK), BLK, 0, stream>>>(cnt, 0, V_N);
    csr_fill_kernel<<<cdiv(E_N, BLK), BLK, 0, stream>>>(dst, rp, cnt, perm);

    // ---- GetContext ----
    gemm_f32a_dual_kernel<<<gOld, BLK, 0, stream>>>(
        node_feats, Wp_pn0, pn_b, Wp_pe1, pe1_b, hv, P);
    node_dot2_kernel<<<gAgg, BLK, 0, stream>>>(hv, pe2_W, nullptr, s1, nullptr);
    ctx_logits_kernel<<<cdiv(E_N, 8), BLK, 0, stream>>>(
        P, edge_feats, src, dst, s1, pe1_W, pe2_W, pe2_b, logits);
    ctx_fused_agg_kernel<<<gAgg, BLK, 0, stream>>>(
        P, edge_feats, src, rp, perm, logits, pe1_W, hbar);
    gemm_bf16a_kernel<3><<<NSWZ, BLK, 0, stream>>>(hbar, Wp_et, et_b, c);
    gru_mfma_kernel<<<NSWZ, BLK, 0, stream>>>(c, hv, WpGru, gru0_bih, gru0_bhh, nf_a);

    // ---- GNN layers ----
    __hip_bfloat16* cur = nf_a;
    __hip_bfloat16* nxt = nf_b;
    for (int l = 0; l < L_N; l++) {
        const float* pe_W = gnn_pe_W + (size_t)l * 2 * G_DIM;
        const float* pe_b = gnn_pe_b + l;
        const float* pnB  = gnn_pn_b + (size_t)l * G_DIM;
        const float* bih  = gnn_gru_bih + (size_t)l * 3 * G_DIM;
        const float* bhh  = gnn_gru_bhh + (size_t)l * 3 * G_DIM;
        const short* WpPn = (l == 0) ? Wp_pn1 : Wp_pn2;

        node_dot2_kernel<<<gAgg, BLK, 0, stream>>>(cur, pe_W, pe_W + G_DIM, s1, s2);
        gemm_bf16a_kernel<1><<<NSWZ, BLK, 0, stream>>>(cur, WpPn, pnB, hvp);
        gnn_fused_agg_kernel<<<gAgg, BLK, 0, stream>>>(
            hvp, src, rp, perm, s1, s2, pe_b, c);
        gru_mfma_kernel<<<NSWZ, BLK, 0, stream>>>(
            c, cur, WpGru + (size_t)(l + 1) * WPL, bih, bhh, nxt);

        __hip_bfloat16* tmp = cur; cur = nxt; nxt = tmp;
    }

    // ---- readout ----
    fill_kernel<<<cdiv(NG_N, BLK), BLK, 0, stream>>>(gsum, 0.f, NG_N);
    readout_kernel<<<cdiv(V_N * 64, BLK), BLK, 0, stream>>>(
        cur, pred_W, pred_b, mask, gid, out_atom, gsum);
    graph_out_kernel<<<cdiv(NG_N, BLK), BLK, 0, stream>>>(gsum, out_g);
}